// Round 2
// baseline (597.270 us; speedup 1.0000x reference)
//
#include <hip/hip_runtime.h>

#define NN 100000   // nodes
#define NE 500000   // edges
#define FD 128      // input features
#define HD 64       // hidden
#define RR 16       // relations
#define NBASE 30    // bases
#define GG 1000     // graphs
#define CC 10       // classes

// ---------------- init: zero counts + histogram ----------------
__global__ void k_init(float* c, int* hist) {
  int idx = blockIdx.x * 256 + threadIdx.x;
  if (idx < NN * RR) c[idx] = 0.0f;
  if (idx < RR) hist[idx] = 0;
}

// ---------------- W[r] = sum_b comp[r,b] * bases[b] ----------------
__global__ void k_basis(const float* comp, const float* bases, float* W) {
  int idx = blockIdx.x * 256 + threadIdx.x;  // r*4096 + kj
  int r = idx >> 12, kj = idx & 4095;
  float acc = 0.0f;
  for (int b = 0; b < NBASE; ++b)
    acc += comp[r * NBASE + b] * bases[b * 4096 + kj];
  W[idx] = acc;
}

// ---------------- h = x@w1_root + b1 ; xw = x@w1_rel ----------------
__global__ __launch_bounds__(256) void k_proj(const float* x, const float* w_rel,
                                              const float* w_root, const float* b1,
                                              float* h, float* xw) {
  __shared__ float xs[4][4][FD];
  int w = threadIdx.x >> 6, j = threadIdx.x & 63;
  int i0 = blockIdx.x * 16 + w * 4;  // 4 nodes per wave, 16 per block (NN%16==0)
  // stage 4 rows (512 floats = 2KB) per wave, coalesced float4
  const float4* xr = reinterpret_cast<const float4*>(x + (size_t)i0 * FD);
  float4 va = xr[j], vb = xr[64 + j];
  reinterpret_cast<float4*>(&xs[w][0][0])[j] = va;
  reinterpret_cast<float4*>(&xs[w][0][0])[64 + j] = vb;
  __syncthreads();
  float ah[4] = {0, 0, 0, 0}, aw[4] = {0, 0, 0, 0};
  for (int k = 0; k < FD; ++k) {
    float wr = w_rel[k * 64 + j];
    float wo = w_root[k * 64 + j];
#pragma unroll
    for (int m = 0; m < 4; ++m) {
      float xv = xs[w][m][k];
      ah[m] += xv * wo;
      aw[m] += xv * wr;
    }
  }
  float bb = b1[j];
#pragma unroll
  for (int m = 0; m < 4; ++m) {
    h[(size_t)(i0 + m) * 64 + j] = ah[m] + bb;
    xw[(size_t)(i0 + m) * 64 + j] = aw[m];
  }
}

// ---------------- histogram of edge types ----------------
__global__ void k_hist(const int* etype, int* hist) {
  __shared__ int lh[RR];
  if (threadIdx.x < RR) lh[threadIdx.x] = 0;
  __syncthreads();
  for (int e = blockIdx.x * 256 + threadIdx.x; e < NE; e += gridDim.x * 256)
    atomicAdd(&lh[etype[e]], 1);
  __syncthreads();
  if (threadIdx.x < RR) atomicAdd(&hist[threadIdx.x], lh[threadIdx.x]);
}

// ---------------- exclusive scan (16 elems) ----------------
__global__ void k_scan(const int* hist, int* offsets, int* ctr) {
  if (threadIdx.x == 0) {
    int s = 0;
    for (int r = 0; r < RR; ++r) { offsets[r] = s; ctr[r] = s; s += hist[r]; }
    offsets[RR] = s;
  }
}

// ---------------- counting-sort scatter: perm sorted by type ----------------
__global__ void k_perm(const int* etype, int* ctr, int* perm) {
  __shared__ int lcnt[RR], lbase[RR];
  if (threadIdx.x < RR) lcnt[threadIdx.x] = 0;
  __syncthreads();
  int e = blockIdx.x * 256 + threadIdx.x;
  int t = 0, rank = 0;
  bool valid = e < NE;
  if (valid) { t = etype[e]; rank = atomicAdd(&lcnt[t], 1); }
  __syncthreads();
  if (threadIdx.x < RR) {
    int n = lcnt[threadIdx.x];
    lbase[threadIdx.x] = n ? atomicAdd(&ctr[threadIdx.x], n) : 0;
  }
  __syncthreads();
  if (valid) perm[lbase[t] + rank] = e;
}

// ---------------- GraphConv scatter: h[dst] += xw[src]*norm ; count c ----------------
__global__ void k_gconv(const int* ei, const float* enorm, const int* etype,
                        const float* xw, float* h, float* c) {
  int idx = blockIdx.x * 256 + threadIdx.x;
  int e = idx >> 6, j = idx & 63;
  if (e >= NE) return;
  int src = ei[e], dst = ei[NE + e];
  float nrm = enorm[e];
  atomicAdd(&h[(size_t)dst * 64 + j], xw[(size_t)src * 64 + j] * nrm);
  if (j == 0) atomicAdd(&c[dst * RR + etype[e]], 1.0f);
}

// ---------------- out = h @ w2_root + b2 ----------------
__global__ __launch_bounds__(256) void k_root2(const float* h, const float* w2,
                                               const float* b2, float* out) {
  __shared__ float hs[4][4][HD];
  int w = threadIdx.x >> 6, j = threadIdx.x & 63;
  int i0 = blockIdx.x * 16 + w * 4;
  float4 v = reinterpret_cast<const float4*>(h + (size_t)i0 * 64)[j];
  reinterpret_cast<float4*>(&hs[w][0][0])[j] = v;
  __syncthreads();
  float acc[4] = {0, 0, 0, 0};
  for (int k = 0; k < HD; ++k) {
    float wv = w2[k * 64 + j];
#pragma unroll
    for (int m = 0; m < 4; ++m) acc[m] += hs[w][m][k] * wv;
  }
  float bb = b2[j];
#pragma unroll
  for (int m = 0; m < 4; ++m) out[(size_t)(i0 + m) * 64 + j] = acc[m] + bb;
}

// ---------------- RGCN edges (sorted by type): out[dst] += (h[src]@W[r]) / c ----------------
#define EG 16
__global__ __launch_bounds__(256) void k_rgcn(const int* perm, const int* ei,
    const int* offsets, const float* h, const float* W, const float* c, float* out) {
  __shared__ float hs[4][EG][HD];
  int r = blockIdx.x;
  int lo = offsets[r], hi = offsets[r + 1];
  int cnt = hi - lo;
  int w = threadIdx.x >> 6, j = threadIdx.x & 63;
  int ngroups = (cnt + EG - 1) / EG;
  const float* Wr = W + r * 4096;
  for (int g = blockIdx.y * 4 + w; g < ngroups; g += gridDim.y * 4) {
    int base = lo + g * EG;
    int ne = min(EG, hi - base);
    int dste[EG];
#pragma unroll
    for (int e = 0; e < EG; ++e) {
      int p = (e < ne) ? (base + e) : base;  // clamp tail to a valid edge
      int ed = perm[p];
      dste[e] = ei[NE + ed];
      int s = ei[ed];
      hs[w][e][j] = h[(size_t)s * 64 + j];   // coalesced 256B row gather
    }
    float acc[EG];
#pragma unroll
    for (int e = 0; e < EG; ++e) acc[e] = 0.0f;
    for (int k = 0; k < HD; ++k) {
      float wv = Wr[k * 64 + j];             // L1-resident (16KB, single type/block)
#pragma unroll
      for (int e = 0; e < EG; ++e) acc[e] += hs[w][e][k] * wv;  // LDS broadcast
    }
#pragma unroll
    for (int e = 0; e < EG; ++e) {
      if (e < ne) {
        float cc = fmaxf(c[dste[e] * RR + r], 1.0f);
        atomicAdd(&out[(size_t)dste[e] * 64 + j], acc[e] / cc);
      }
    }
  }
}

// ---------------- graph bounds from seq_lengths ----------------
__global__ void k_bounds(const int* seq, int* bounds) {
  __shared__ int s[GG];
  for (int i = threadIdx.x; i < GG; i += 256) s[i] = seq[i];
  __syncthreads();
  if (threadIdx.x == 0) {
    int acc = 0;
    for (int g = 0; g < GG; ++g) { acc += s[g]; bounds[g] = acc; }
  }
}

// ---------------- fused pool (sum+max) + MLP head + log_softmax ----------------
__global__ __launch_bounds__(256) void k_head(const float* x, const float* outn,
    const int* bounds, const float* lin_w, const float* lin_b,
    const float* fc_w, const float* fc_b, float* dout) {
  __shared__ float gsum[192], gmax[192], hid[HD], lg[CC], mred[2];
  int g = blockIdx.x, t = threadIdx.x;
  int lo = (g == 0) ? 0 : bounds[g - 1];
  int hi = bounds[g];
  if (t < 192) {
    float s = 0.0f, mx = -3.4e38f;
    for (int n = lo; n < hi; ++n) {
      float v = (t < FD) ? x[(size_t)n * FD + t]
                         : outn[(size_t)n * 64 + (t - FD)];
      s += v;
      mx = fmaxf(mx, v);
    }
    gsum[t] = s;
    gmax[t] = mx;
  }
  __syncthreads();
  if (t < HD) {
    float a = lin_b[t];
    for (int k = 0; k < 192; ++k) a += gsum[k] * lin_w[k * 64 + t];
    for (int k = 0; k < 192; ++k) a += gmax[k] * lin_w[(192 + k) * 64 + t];
    hid[t] = fmaxf(a, 0.0f);
  }
  __syncthreads();
  if (t < CC) {
    float a = fc_b[t];
    for (int k = 0; k < HD; ++k) a += hid[k] * fc_w[k * CC + t];
    lg[t] = a;
  }
  __syncthreads();
  if (t == 0) {
    float m = lg[0];
#pragma unroll
    for (int i = 1; i < CC; ++i) m = fmaxf(m, lg[i]);
    float se = 0.0f;
#pragma unroll
    for (int i = 0; i < CC; ++i) se += __expf(lg[i] - m);
    mred[0] = m;
    mred[1] = __logf(se);
  }
  __syncthreads();
  if (t < CC) dout[g * CC + t] = lg[t] - mred[0] - mred[1];
}

extern "C" void kernel_launch(void* const* d_in, const int* in_sizes, int n_in,
                              void* d_out, int out_size, void* d_ws, size_t ws_size,
                              hipStream_t stream) {
  const float* x     = (const float*)d_in[0];
  const int* ei      = (const int*)d_in[1];
  const float* enorm = (const float*)d_in[2];
  const int* etype   = (const int*)d_in[3];
  const int* seq     = (const int*)d_in[4];
  // d_in[5] = avec (scalar 0, log_softmax branch)
  const float* w1_rel  = (const float*)d_in[6];
  const float* w1_root = (const float*)d_in[7];
  const float* b1      = (const float*)d_in[8];
  const float* bases   = (const float*)d_in[9];
  const float* comp    = (const float*)d_in[10];
  const float* w2      = (const float*)d_in[11];
  const float* b2      = (const float*)d_in[12];
  const float* lin_w   = (const float*)d_in[13];
  const float* lin_b   = (const float*)d_in[14];
  const float* fc_w    = (const float*)d_in[15];
  const float* fc_b    = (const float*)d_in[16];
  float* dout = (float*)d_out;

  char* p = (char*)d_ws;
  float* h    = (float*)p; p += (size_t)NN * 64 * 4;
  float* xw   = (float*)p; p += (size_t)NN * 64 * 4;
  float* out  = (float*)p; p += (size_t)NN * 64 * 4;
  float* c    = (float*)p; p += (size_t)NN * RR * 4;
  float* W    = (float*)p; p += (size_t)RR * 64 * 64 * 4;
  int* perm   = (int*)p; p += (size_t)NE * 4;
  int* bounds = (int*)p; p += (size_t)GG * 4;
  int* hist   = (int*)p; p += 64;
  int* offs   = (int*)p; p += 68;
  int* ctr    = (int*)p; p += 64;

  hipLaunchKernelGGL(k_init, dim3((NN * RR + 255) / 256), dim3(256), 0, stream, c, hist);
  hipLaunchKernelGGL(k_basis, dim3(RR * 64 * 64 / 256), dim3(256), 0, stream, comp, bases, W);
  hipLaunchKernelGGL(k_proj, dim3(NN / 16), dim3(256), 0, stream, x, w1_rel, w1_root, b1, h, xw);
  hipLaunchKernelGGL(k_hist, dim3(512), dim3(256), 0, stream, etype, hist);
  hipLaunchKernelGGL(k_scan, dim3(1), dim3(64), 0, stream, hist, offs, ctr);
  hipLaunchKernelGGL(k_perm, dim3((NE + 255) / 256), dim3(256), 0, stream, etype, ctr, perm);
  hipLaunchKernelGGL(k_gconv, dim3(NE / 4), dim3(256), 0, stream, ei, enorm, etype, xw, h, c);
  hipLaunchKernelGGL(k_root2, dim3(NN / 16), dim3(256), 0, stream, h, w2, b2, out);
  hipLaunchKernelGGL(k_rgcn, dim3(RR, 512), dim3(256), 0, stream, perm, ei, offs, h, W, c, out);
  hipLaunchKernelGGL(k_bounds, dim3(1), dim3(256), 0, stream, seq, bounds);
  hipLaunchKernelGGL(k_head, dim3(GG), dim3(256), 0, stream, x, out, bounds,
                     lin_w, lin_b, fc_w, fc_b, dout);
}

// Round 3
// 530.844 us; speedup vs baseline: 1.1251x; 1.1251x over previous
//
#include <hip/hip_runtime.h>
#include <hip/hip_bf16.h>

#define NN 100000   // nodes
#define NE 500000   // edges
#define FD 128      // input features
#define HD 64       // hidden
#define RR 16       // relations
#define NBASE 30    // bases
#define GG 1000     // graphs
#define CC 10       // classes

typedef __attribute__((ext_vector_type(8))) short bf16x8;
typedef __attribute__((ext_vector_type(4))) float f32x4;

__device__ inline unsigned short f2b(float x) {
  __hip_bfloat16 b = __float2bfloat16(x);
  return *reinterpret_cast<unsigned short*>(&b);
}

// ---------------- init: zero counts + histogram ----------------
__global__ void k_init(float* c, int* hist) {
  int idx = blockIdx.x * 256 + threadIdx.x;
  if (idx < NN * RR) c[idx] = 0.0f;
  if (idx < RR) hist[idx] = 0;
}

// ---------------- Wt[r][n][k] = sum_b comp[r,b] * bases[b][k][n]  (bf16, transposed) ----------------
__global__ void k_basis(const float* comp, const float* bases, unsigned short* Wt) {
  int idx = blockIdx.x * 256 + threadIdx.x;  // r*4096 + k*64 + n
  int r = idx >> 12, kj = idx & 4095;
  int k = kj >> 6, n = kj & 63;
  float acc = 0.0f;
  for (int b = 0; b < NBASE; ++b)
    acc += comp[r * NBASE + b] * bases[b * 4096 + kj];
  Wt[(r << 12) + n * 64 + k] = f2b(acc);
}

// ---------------- h = x@w1_root + b1 ; xw = x@w1_rel ----------------
__global__ __launch_bounds__(256) void k_proj(const float* x, const float* w_rel,
                                              const float* w_root, const float* b1,
                                              float* h, float* xw) {
  __shared__ float xs[4][4][FD];
  int w = threadIdx.x >> 6, j = threadIdx.x & 63;
  int i0 = blockIdx.x * 16 + w * 4;  // 4 nodes per wave, 16 per block (NN%16==0)
  const float4* xr = reinterpret_cast<const float4*>(x + (size_t)i0 * FD);
  float4 va = xr[j], vb = xr[64 + j];
  reinterpret_cast<float4*>(&xs[w][0][0])[j] = va;
  reinterpret_cast<float4*>(&xs[w][0][0])[64 + j] = vb;
  __syncthreads();
  float ah[4] = {0, 0, 0, 0}, aw[4] = {0, 0, 0, 0};
  for (int k = 0; k < FD; ++k) {
    float wr = w_rel[k * 64 + j];
    float wo = w_root[k * 64 + j];
#pragma unroll
    for (int m = 0; m < 4; ++m) {
      float xv = xs[w][m][k];
      ah[m] += xv * wo;
      aw[m] += xv * wr;
    }
  }
  float bb = b1[j];
#pragma unroll
  for (int m = 0; m < 4; ++m) {
    h[(size_t)(i0 + m) * 64 + j] = ah[m] + bb;
    xw[(size_t)(i0 + m) * 64 + j] = aw[m];
  }
}

// ---------------- histogram of edge types ----------------
__global__ void k_hist(const int* etype, int* hist) {
  __shared__ int lh[RR];
  if (threadIdx.x < RR) lh[threadIdx.x] = 0;
  __syncthreads();
  for (int e = blockIdx.x * 256 + threadIdx.x; e < NE; e += gridDim.x * 256)
    atomicAdd(&lh[etype[e]], 1);
  __syncthreads();
  if (threadIdx.x < RR) atomicAdd(&hist[threadIdx.x], lh[threadIdx.x]);
}

// ---------------- exclusive scan (16 elems) ----------------
__global__ void k_scan(const int* hist, int* offsets, int* ctr) {
  if (threadIdx.x == 0) {
    int s = 0;
    for (int r = 0; r < RR; ++r) { offsets[r] = s; ctr[r] = s; s += hist[r]; }
    offsets[RR] = s;
  }
}

// ---------------- counting-sort scatter: perm sorted by type ----------------
__global__ void k_perm(const int* etype, int* ctr, int* perm) {
  __shared__ int lcnt[RR], lbase[RR];
  if (threadIdx.x < RR) lcnt[threadIdx.x] = 0;
  __syncthreads();
  int e = blockIdx.x * 256 + threadIdx.x;
  int t = 0, rank = 0;
  bool valid = e < NE;
  if (valid) { t = etype[e]; rank = atomicAdd(&lcnt[t], 1); }
  __syncthreads();
  if (threadIdx.x < RR) {
    int n = lcnt[threadIdx.x];
    lbase[threadIdx.x] = n ? atomicAdd(&ctr[threadIdx.x], n) : 0;
  }
  __syncthreads();
  if (valid) perm[lbase[t] + rank] = e;
}

// ---------------- GraphConv scatter: h[dst] += xw[src]*norm ; count c ----------------
__global__ void k_gconv(const int* ei, const float* enorm, const int* etype,
                        const float* xw, float* h, float* c) {
  int idx = blockIdx.x * 256 + threadIdx.x;
  int e = idx >> 6, j = idx & 63;
  if (e >= NE) return;
  int src = ei[e], dst = ei[NE + e];
  float nrm = enorm[e];
  atomicAdd(&h[(size_t)dst * 64 + j], xw[(size_t)src * 64 + j] * nrm);
  if (j == 0) atomicAdd(&c[dst * RR + etype[e]], 1.0f);
}

// ---------------- out = h @ w2_root + b2 ; also emit h_bf (bf16 copy of h) ----------------
__global__ __launch_bounds__(256) void k_root2(const float* h, const float* w2,
                                               const float* b2, float* out,
                                               unsigned short* h_bf) {
  __shared__ float hs[4][4][HD];
  int w = threadIdx.x >> 6, j = threadIdx.x & 63;
  int i0 = blockIdx.x * 16 + w * 4;
  float4 v = reinterpret_cast<const float4*>(h + (size_t)i0 * 64)[j];
  reinterpret_cast<float4*>(&hs[w][0][0])[j] = v;
  ushort4 hb;
  hb.x = f2b(v.x); hb.y = f2b(v.y); hb.z = f2b(v.z); hb.w = f2b(v.w);
  reinterpret_cast<ushort4*>(h_bf)[(size_t)i0 * 16 + j] = hb;
  __syncthreads();
  float acc[4] = {0, 0, 0, 0};
  for (int k = 0; k < HD; ++k) {
    float wv = w2[k * 64 + j];
#pragma unroll
    for (int m = 0; m < 4; ++m) acc[m] += hs[w][m][k] * wv;
  }
  float bb = b2[j];
#pragma unroll
  for (int m = 0; m < 4; ++m) out[(size_t)(i0 + m) * 64 + j] = acc[m] + bb;
}

// ---------------- RGCN via MFMA: out[dst] += (h[src] @ W[r]) / c  (edges type-sorted) ----------------
// A-tile: 16 edges x 64(k) bf16; B: Wt[r] (stored [n][k]); D: 16x64 fp32.
__global__ __launch_bounds__(256) void k_rgcn(const int* perm, const int* ei,
    const int* offsets, const unsigned short* h_bf, const unsigned short* Wt,
    const float* c, float* out) {
  int r = blockIdx.x;
  int lo = offsets[r], hi = offsets[r + 1];
  int cnt = hi - lo;
  int wv = threadIdx.x >> 6;
  int l = threadIdx.x & 63;
  int m = l & 15;   // A row (edge in group) / D col
  int q = l >> 4;   // quad: A k-chunk / D row-group
  int ngroups = (cnt + 15) / 16;
  // hoist B fragments: 2 ksteps x 4 ntiles, lane holds Wt[nt*16+m][s*32+q*8 .. +8]
  const unsigned short* Wr = Wt + (r << 12);
  bf16x8 bfr[2][4];
#pragma unroll
  for (int s = 0; s < 2; ++s)
#pragma unroll
    for (int nt = 0; nt < 4; ++nt)
      bfr[s][nt] = *reinterpret_cast<const bf16x8*>(Wr + (nt * 16 + m) * 64 + s * 32 + q * 8);

  for (int g = blockIdx.y * 4 + wv; g < ngroups; g += gridDim.y * 4) {
    int base = lo + g * 16;
    int ne = min(16, hi - base);
    int p = base + ((m < ne) ? m : 0);  // clamp tail
    int ed = perm[p];
    int src = ei[ed];
    int dst = ei[NE + ed];
    float inv = 1.0f / fmaxf(c[dst * RR + r], 1.0f);
    f32x4 acc[4] = {{0, 0, 0, 0}, {0, 0, 0, 0}, {0, 0, 0, 0}, {0, 0, 0, 0}};
    const unsigned short* hrow = h_bf + (size_t)src * 64 + q * 8;
#pragma unroll
    for (int s = 0; s < 2; ++s) {
      bf16x8 afr = *reinterpret_cast<const bf16x8*>(hrow + s * 32);
#pragma unroll
      for (int nt = 0; nt < 4; ++nt)
        acc[nt] = __builtin_amdgcn_mfma_f32_16x16x32_bf16(afr, bfr[s][nt], acc[nt], 0, 0, 0);
    }
#pragma unroll
    for (int i = 0; i < 4; ++i) {
      int row = q * 4 + i;                 // D row = edge index in group
      int dr = __shfl(dst, row);           // lane `row` owns edge `row`'s dst
      float ir = __shfl(inv, row);
      if (row < ne) {
#pragma unroll
        for (int nt = 0; nt < 4; ++nt)
          atomicAdd(&out[(size_t)dr * 64 + nt * 16 + m], acc[nt][i] * ir);
      }
    }
  }
}

// ---------------- graph bounds from seq_lengths ----------------
__global__ void k_bounds(const int* seq, int* bounds) {
  __shared__ int s[GG];
  for (int i = threadIdx.x; i < GG; i += 256) s[i] = seq[i];
  __syncthreads();
  if (threadIdx.x == 0) {
    int acc = 0;
    for (int g = 0; g < GG; ++g) { acc += s[g]; bounds[g] = acc; }
  }
}

// ---------------- fused pool (sum+max) + MLP head + log_softmax ----------------
__global__ __launch_bounds__(256) void k_head(const float* x, const float* outn,
    const int* bounds, const float* lin_w, const float* lin_b,
    const float* fc_w, const float* fc_b, float* dout) {
  __shared__ float gsum[192], gmax[192], hid[HD], lg[CC], mred[2];
  int g = blockIdx.x, t = threadIdx.x;
  int lo = (g == 0) ? 0 : bounds[g - 1];
  int hi = bounds[g];
  if (t < 192) {
    float s = 0.0f, mx = -3.4e38f;
    for (int n = lo; n < hi; ++n) {
      float v = (t < FD) ? x[(size_t)n * FD + t]
                         : outn[(size_t)n * 64 + (t - FD)];
      s += v;
      mx = fmaxf(mx, v);
    }
    gsum[t] = s;
    gmax[t] = mx;
  }
  __syncthreads();
  if (t < HD) {
    float a = lin_b[t];
    for (int k = 0; k < 192; ++k) a += gsum[k] * lin_w[k * 64 + t];
    for (int k = 0; k < 192; ++k) a += gmax[k] * lin_w[(192 + k) * 64 + t];
    hid[t] = fmaxf(a, 0.0f);
  }
  __syncthreads();
  if (t < CC) {
    float a = fc_b[t];
    for (int k = 0; k < HD; ++k) a += hid[k] * fc_w[k * CC + t];
    lg[t] = a;
  }
  __syncthreads();
  if (t == 0) {
    float mm = lg[0];
#pragma unroll
    for (int i = 1; i < CC; ++i) mm = fmaxf(mm, lg[i]);
    float se = 0.0f;
#pragma unroll
    for (int i = 0; i < CC; ++i) se += __expf(lg[i] - mm);
    mred[0] = mm;
    mred[1] = __logf(se);
  }
  __syncthreads();
  if (t < CC) dout[g * CC + t] = lg[t] - mred[0] - mred[1];
}

extern "C" void kernel_launch(void* const* d_in, const int* in_sizes, int n_in,
                              void* d_out, int out_size, void* d_ws, size_t ws_size,
                              hipStream_t stream) {
  const float* x     = (const float*)d_in[0];
  const int* ei      = (const int*)d_in[1];
  const float* enorm = (const float*)d_in[2];
  const int* etype   = (const int*)d_in[3];
  const int* seq     = (const int*)d_in[4];
  // d_in[5] = avec (scalar 0, log_softmax branch)
  const float* w1_rel  = (const float*)d_in[6];
  const float* w1_root = (const float*)d_in[7];
  const float* b1      = (const float*)d_in[8];
  const float* bases   = (const float*)d_in[9];
  const float* comp    = (const float*)d_in[10];
  const float* w2      = (const float*)d_in[11];
  const float* b2      = (const float*)d_in[12];
  const float* lin_w   = (const float*)d_in[13];
  const float* lin_b   = (const float*)d_in[14];
  const float* fc_w    = (const float*)d_in[15];
  const float* fc_b    = (const float*)d_in[16];
  float* dout = (float*)d_out;

  char* p = (char*)d_ws;
  float* h    = (float*)p; p += (size_t)NN * 64 * 4;
  float* xw   = (float*)p; p += (size_t)NN * 64 * 4;   // h_bf aliases this after k_gconv
  float* out  = (float*)p; p += (size_t)NN * 64 * 4;
  float* c    = (float*)p; p += (size_t)NN * RR * 4;
  unsigned short* Wt = (unsigned short*)p; p += (size_t)RR * 64 * 64 * 2;
  int* perm   = (int*)p; p += (size_t)NE * 4;
  int* bounds = (int*)p; p += (size_t)GG * 4;
  int* hist   = (int*)p; p += 64;
  int* offs   = (int*)p; p += 68;
  int* ctr    = (int*)p; p += 64;
  unsigned short* h_bf = (unsigned short*)xw;  // xw dead after k_gconv

  hipLaunchKernelGGL(k_init, dim3((NN * RR + 255) / 256), dim3(256), 0, stream, c, hist);
  hipLaunchKernelGGL(k_basis, dim3(RR * 64 * 64 / 256), dim3(256), 0, stream, comp, bases, Wt);
  hipLaunchKernelGGL(k_proj, dim3(NN / 16), dim3(256), 0, stream, x, w1_rel, w1_root, b1, h, xw);
  hipLaunchKernelGGL(k_hist, dim3(512), dim3(256), 0, stream, etype, hist);
  hipLaunchKernelGGL(k_scan, dim3(1), dim3(64), 0, stream, hist, offs, ctr);
  hipLaunchKernelGGL(k_perm, dim3((NE + 255) / 256), dim3(256), 0, stream, etype, ctr, perm);
  hipLaunchKernelGGL(k_gconv, dim3(NE / 4), dim3(256), 0, stream, ei, enorm, etype, xw, h, c);
  hipLaunchKernelGGL(k_root2, dim3(NN / 16), dim3(256), 0, stream, h, w2, b2, out, h_bf);
  hipLaunchKernelGGL(k_rgcn, dim3(RR, 128), dim3(256), 0, stream, perm, ei, offs, h_bf, Wt, c, out);
  hipLaunchKernelGGL(k_bounds, dim3(1), dim3(256), 0, stream, seq, bounds);
  hipLaunchKernelGGL(k_head, dim3(GG), dim3(256), 0, stream, x, out, bounds,
                     lin_w, lin_b, fc_w, fc_b, dout);
}

// Round 4
// 463.560 us; speedup vs baseline: 1.2884x; 1.1451x over previous
//
#include <hip/hip_runtime.h>
#include <hip/hip_bf16.h>

#define NN 100000   // nodes
#define NE 500000   // edges
#define FD 128      // input features
#define HD 64       // hidden
#define RR 16       // relations
#define NBASE 30    // bases
#define GG 1000     // graphs
#define CC 10       // classes
#define NGROUP 6250 // NN/16

typedef __attribute__((ext_vector_type(8))) short bf16x8;
typedef __attribute__((ext_vector_type(4))) float f32x4;

__device__ inline unsigned short f2b(float x) {
  __hip_bfloat16 b = __float2bfloat16(x);
  return *reinterpret_cast<unsigned short*>(&b);
}
__device__ inline float b2f(unsigned short u) {
  return __uint_as_float(((unsigned)u) << 16);
}

// ---------------- Wt[r][n][k] = sum_b comp[r,b]*bases[b][k][n] (bf16, B-layout) ----------------
__global__ void k_basis(const float* comp, const float* bases, unsigned short* Wt) {
  int idx = blockIdx.x * 256 + threadIdx.x;  // r*4096 + k*64 + n
  int r = idx >> 12, kj = idx & 4095;
  int k = kj >> 6, n = kj & 63;
  float acc = 0.0f;
  for (int b = 0; b < NBASE; ++b)
    acc += comp[r * NBASE + b] * bases[b * 4096 + kj];
  Wt[(r << 12) + n * 64 + k] = f2b(acc);
}

// ---------------- weight conversions: wcat[n<64:root|n>=64:rel][k], w2t[n][k] ----------------
__global__ void k_wcvt(const float* w_root, const float* w_rel, const float* w2,
                       unsigned short* wcat, unsigned short* w2t) {
  int idx = blockIdx.x * 256 + threadIdx.x;
  if (idx < 16384) {
    int n = idx >> 7, k = idx & 127;
    float v = (n < 64) ? w_root[k * 64 + n] : w_rel[k * 64 + (n - 64)];
    wcat[n * 128 + k] = f2b(v);
  } else if (idx < 16384 + 4096) {
    int i2 = idx - 16384;
    int n = i2 >> 6, k = i2 & 63;
    w2t[n * 64 + k] = f2b(w2[k * 64 + n]);
  }
}

// ---------------- h = x@w_root + b1 ; xw = x@w_rel  (MFMA, 16 nodes/wave) ----------------
__global__ __launch_bounds__(256) void k_proj_mfma(const float* x, const unsigned short* wcat,
                                                   const float* b1, float* h, float* xw) {
  int wv = threadIdx.x >> 6, l = threadIdx.x & 63, m = l & 15, q = l >> 4;
  int g = blockIdx.x * 4 + wv;
  if (g >= NGROUP) return;
  int n0 = g * 16;
  const float* xr = x + (size_t)(n0 + m) * FD;
  bf16x8 afr[4];
#pragma unroll
  for (int s = 0; s < 4; ++s) {
    float4 xa = *reinterpret_cast<const float4*>(xr + s * 32 + q * 8);
    float4 xb = *reinterpret_cast<const float4*>(xr + s * 32 + q * 8 + 4);
    bf16x8 a;
    a[0] = (short)f2b(xa.x); a[1] = (short)f2b(xa.y);
    a[2] = (short)f2b(xa.z); a[3] = (short)f2b(xa.w);
    a[4] = (short)f2b(xb.x); a[5] = (short)f2b(xb.y);
    a[6] = (short)f2b(xb.z); a[7] = (short)f2b(xb.w);
    afr[s] = a;
  }
  f32x4 acc[8];
#pragma unroll
  for (int nt = 0; nt < 8; ++nt) acc[nt] = (f32x4){0, 0, 0, 0};
#pragma unroll
  for (int s = 0; s < 4; ++s) {
#pragma unroll
    for (int nt = 0; nt < 8; ++nt) {
      bf16x8 b = *reinterpret_cast<const bf16x8*>(wcat + (nt * 16 + m) * 128 + s * 32 + q * 8);
      acc[nt] = __builtin_amdgcn_mfma_f32_16x16x32_bf16(afr[s], b, acc[nt], 0, 0, 0);
    }
  }
  float b1v[4];
#pragma unroll
  for (int nt = 0; nt < 4; ++nt) b1v[nt] = b1[nt * 16 + m];
#pragma unroll
  for (int i = 0; i < 4; ++i) {
    size_t row = n0 + q * 4 + i;
#pragma unroll
    for (int nt = 0; nt < 4; ++nt) {
      h[row * 64 + nt * 16 + m] = acc[nt][i] + b1v[nt];
      xw[row * 64 + nt * 16 + m] = acc[nt + 4][i];
    }
  }
}

// ---------------- histograms: hist1[type] (LDS-priv), hist2[dst*16+type] ----------------
__global__ void k_hists(const int* ei, const int* etype, int* hist1, int* hist2) {
  __shared__ int lh[RR];
  if (threadIdx.x < RR) lh[threadIdx.x] = 0;
  __syncthreads();
  for (int e = blockIdx.x * 256 + threadIdx.x; e < NE; e += gridDim.x * 256) {
    int t = etype[e];
    atomicAdd(&lh[t], 1);
    atomicAdd(&hist2[ei[NE + e] * RR + t], 1);
  }
  __syncthreads();
  if (threadIdx.x < RR) atomicAdd(&hist1[threadIdx.x], lh[threadIdx.x]);
}

// ---------------- 16-bin scan ----------------
__global__ void k_scan1(const int* hist1, int* offs, int* ctr1) {
  if (threadIdx.x == 0) {
    int s = 0;
    for (int r = 0; r < RR; ++r) { offs[r] = s; ctr1[r] = s; s += hist1[r]; }
    offs[RR] = s;
  }
}

// ---------------- type-sort scatter -> perm1 ----------------
__global__ void k_perm1(const int* etype, int* ctr1, int* perm1) {
  __shared__ int lcnt[RR], lbase[RR];
  if (threadIdx.x < RR) lcnt[threadIdx.x] = 0;
  __syncthreads();
  int e = blockIdx.x * 256 + threadIdx.x;
  int t = 0, rank = 0;
  bool valid = e < NE;
  if (valid) { t = etype[e]; rank = atomicAdd(&lcnt[t], 1); }
  __syncthreads();
  if (threadIdx.x < RR) {
    int n = lcnt[threadIdx.x];
    lbase[threadIdx.x] = n ? atomicAdd(&ctr1[threadIdx.x], n) : 0;
  }
  __syncthreads();
  if (valid) perm1[lbase[t] + rank] = e;
}

// ---------------- hierarchical scan of hist2 (1.6M) -> rowptr2 ----------------
__device__ inline int block_scan_incl(int v, int* ps, int t) {
  ps[t] = v;
  __syncthreads();
  for (int off = 1; off < 256; off <<= 1) {
    int u = (t >= off) ? ps[t - off] : 0;
    __syncthreads();
    ps[t] += u;
    __syncthreads();
  }
  return ps[t];
}

__global__ void k_scanA(const int* hist2, int* bsum) {
  __shared__ int red[256];
  int t = threadIdx.x;
  red[t] = hist2[blockIdx.x * 256 + t];
  __syncthreads();
  for (int s = 128; s; s >>= 1) {
    if (t < s) red[t] += red[t + s];
    __syncthreads();
  }
  if (t == 0) bsum[blockIdx.x] = red[0];
}

__global__ void k_scanB(int* bsum) {  // 6250 = 250*25, in-place exclusive scan
  int t = threadIdx.x;
  int loc[25];
  int s = 0;
  if (t < 250) {
    for (int i = 0; i < 25; ++i) { loc[i] = bsum[t * 25 + i]; s += loc[i]; }
  }
  __shared__ int ps[256];
  int incl = block_scan_incl(s, ps, t);
  int base = incl - s;
  if (t < 250) {
    int run = base;
    for (int i = 0; i < 25; ++i) { int tmp = loc[i]; bsum[t * 25 + i] = run; run += tmp; }
  }
}

__global__ void k_scanC(const int* hist2, const int* bsum, int* rowptr2) {
  int t = threadIdx.x;
  int gid = blockIdx.x * 256 + t;
  int v = hist2[gid];
  __shared__ int ps[256];
  int incl = block_scan_incl(v, ps, t);
  rowptr2[gid] = bsum[blockIdx.x] + incl - v;
}

// ---------------- dst-sort scatter: perm2b (type-order positions), es, en ----------------
__global__ void k_perm2(const int* perm1, const int* ei, const int* etype, const float* enorm,
                        int* ctr2, int* perm2b, int* es, float* en) {
  int p = blockIdx.x * 256 + threadIdx.x;
  if (p >= NE) return;
  int e = perm1[p];
  int key = ei[NE + e] * RR + etype[e];
  int pos = atomicAdd(&ctr2[key], 1);
  perm2b[pos] = p;
  es[pos] = ei[e];
  en[pos] = enorm[e];
}

// ---------------- GraphConv segment-sum: h_bf[dst] = bf16(h_root + sum xw[src]*norm) ----------------
__global__ __launch_bounds__(256) void k_gconv_seg(const int* rowptr2, const int* es,
    const float* en, const float* xw, const float* h, unsigned short* h_bf) {
  int wv = threadIdx.x >> 6, j = threadIdx.x & 63;
  int dst = blockIdx.x * 4 + wv;
  int lo = rowptr2[dst * RR];
  int hi = (dst == NN - 1) ? NE : rowptr2[(dst + 1) * RR];
  float acc = h[(size_t)dst * 64 + j];
  for (int base = lo; base < hi; base += 64) {
    int n = min(64, hi - base);
    int sv = 0;
    float nv = 0.0f;
    if (j < n) { sv = es[base + j]; nv = en[base + j]; }
    for (int k = 0; k < n; ++k) {
      int s = __shfl(sv, k);
      float w = __shfl(nv, k);
      acc += xw[(size_t)s * 64 + j] * w;
    }
  }
  h_bf[(size_t)dst * 64 + j] = f2b(acc);
}

// ---------------- out = h_bf @ w2t + b2  (MFMA) ----------------
__global__ __launch_bounds__(256) void k_root2_mfma(const unsigned short* h_bf,
    const unsigned short* w2t, const float* b2, float* out) {
  int wv = threadIdx.x >> 6, l = threadIdx.x & 63, m = l & 15, q = l >> 4;
  int g = blockIdx.x * 4 + wv;
  if (g >= NGROUP) return;
  int n0 = g * 16;
  f32x4 acc[4];
#pragma unroll
  for (int nt = 0; nt < 4; ++nt) acc[nt] = (f32x4){0, 0, 0, 0};
#pragma unroll
  for (int s = 0; s < 2; ++s) {
    bf16x8 a = *reinterpret_cast<const bf16x8*>(h_bf + (size_t)(n0 + m) * 64 + s * 32 + q * 8);
#pragma unroll
    for (int nt = 0; nt < 4; ++nt) {
      bf16x8 b = *reinterpret_cast<const bf16x8*>(w2t + (nt * 16 + m) * 64 + s * 32 + q * 8);
      acc[nt] = __builtin_amdgcn_mfma_f32_16x16x32_bf16(a, b, acc[nt], 0, 0, 0);
    }
  }
  float b2v[4];
#pragma unroll
  for (int nt = 0; nt < 4; ++nt) b2v[nt] = b2[nt * 16 + m];
#pragma unroll
  for (int i = 0; i < 4; ++i) {
    size_t row = n0 + q * 4 + i;
#pragma unroll
    for (int nt = 0; nt < 4; ++nt)
      out[row * 64 + nt * 16 + m] = acc[nt][i] + b2v[nt];
  }
}

// ---------------- RGCN via MFMA, streamed y rows (type-sorted) ----------------
__global__ __launch_bounds__(256) void k_rgcn_y(const int* perm1, const int* ei,
    const int* offs, const unsigned short* h_bf, const unsigned short* Wt,
    const int* hist2, unsigned short* y_bf) {
  int r = blockIdx.x;
  int lo = offs[r], hi = offs[r + 1];
  int cnt = hi - lo;
  int wv = threadIdx.x >> 6;
  int l = threadIdx.x & 63;
  int m = l & 15, q = l >> 4;
  int ngroups = (cnt + 15) / 16;
  const unsigned short* Wr = Wt + (r << 12);
  bf16x8 bfr[2][4];
#pragma unroll
  for (int s = 0; s < 2; ++s)
#pragma unroll
    for (int nt = 0; nt < 4; ++nt)
      bfr[s][nt] = *reinterpret_cast<const bf16x8*>(Wr + (nt * 16 + m) * 64 + s * 32 + q * 8);

  for (int g = blockIdx.y * 4 + wv; g < ngroups; g += gridDim.y * 4) {
    int base = lo + g * 16;
    int ne = min(16, hi - base);
    int p = base + ((m < ne) ? m : 0);
    int ed = perm1[p];
    int src = ei[ed];
    int dst = ei[NE + ed];
    float inv = 1.0f / (float)max(hist2[dst * RR + r], 1);
    f32x4 acc[4];
#pragma unroll
    for (int nt = 0; nt < 4; ++nt) acc[nt] = (f32x4){0, 0, 0, 0};
    const unsigned short* hrow = h_bf + (size_t)src * 64 + q * 8;
#pragma unroll
    for (int s = 0; s < 2; ++s) {
      bf16x8 afr = *reinterpret_cast<const bf16x8*>(hrow + s * 32);
#pragma unroll
      for (int nt = 0; nt < 4; ++nt)
        acc[nt] = __builtin_amdgcn_mfma_f32_16x16x32_bf16(afr, bfr[s][nt], acc[nt], 0, 0, 0);
    }
#pragma unroll
    for (int i = 0; i < 4; ++i) {
      int row = q * 4 + i;
      float ir = __shfl(inv, row);
      if (row < ne) {
#pragma unroll
        for (int nt = 0; nt < 4; ++nt)
          y_bf[(size_t)(base + row) * 64 + nt * 16 + m] = f2b(acc[nt][i] * ir);
      }
    }
  }
}

// ---------------- per-dst y-row gather-sum: out[dst] += sum y ----------------
__global__ __launch_bounds__(256) void k_ysum(const int* rowptr2, const int* perm2b,
    const unsigned short* y_bf, float* out) {
  int wv = threadIdx.x >> 6, j = threadIdx.x & 63;
  int dst = blockIdx.x * 4 + wv;
  int lo = rowptr2[dst * RR];
  int hi = (dst == NN - 1) ? NE : rowptr2[(dst + 1) * RR];
  float acc = out[(size_t)dst * 64 + j];
  for (int base = lo; base < hi; base += 64) {
    int n = min(64, hi - base);
    int p = 0;
    if (j < n) p = perm2b[base + j];
    for (int k = 0; k < n; ++k) {
      int pp = __shfl(p, k);
      acc += b2f(y_bf[(size_t)pp * 64 + j]);
    }
  }
  out[(size_t)dst * 64 + j] = acc;
}

// ---------------- graph bounds ----------------
__global__ void k_bounds(const int* seq, int* bounds) {
  __shared__ int s[GG];
  for (int i = threadIdx.x; i < GG; i += 256) s[i] = seq[i];
  __syncthreads();
  if (threadIdx.x == 0) {
    int acc = 0;
    for (int g = 0; g < GG; ++g) { acc += s[g]; bounds[g] = acc; }
  }
}

// ---------------- fused pool + MLP head + log_softmax ----------------
__global__ __launch_bounds__(256) void k_head(const float* x, const float* outn,
    const int* bounds, const float* lin_w, const float* lin_b,
    const float* fc_w, const float* fc_b, float* dout) {
  __shared__ float gsum[192], gmax[192], hid[HD], lg[CC], mred[2];
  int g = blockIdx.x, t = threadIdx.x;
  int lo = (g == 0) ? 0 : bounds[g - 1];
  int hi = bounds[g];
  if (t < 192) {
    float s = 0.0f, mx = -3.4e38f;
    for (int n = lo; n < hi; ++n) {
      float v = (t < FD) ? x[(size_t)n * FD + t] : outn[(size_t)n * 64 + (t - FD)];
      s += v;
      mx = fmaxf(mx, v);
    }
    gsum[t] = s;
    gmax[t] = mx;
  }
  __syncthreads();
  if (t < HD) {
    float a = lin_b[t];
    for (int k = 0; k < 192; ++k) a += gsum[k] * lin_w[k * 64 + t];
    for (int k = 0; k < 192; ++k) a += gmax[k] * lin_w[(192 + k) * 64 + t];
    hid[t] = fmaxf(a, 0.0f);
  }
  __syncthreads();
  if (t < CC) {
    float a = fc_b[t];
    for (int k = 0; k < HD; ++k) a += hid[k] * fc_w[k * CC + t];
    lg[t] = a;
  }
  __syncthreads();
  if (t == 0) {
    float mm = lg[0];
#pragma unroll
    for (int i = 1; i < CC; ++i) mm = fmaxf(mm, lg[i]);
    float se = 0.0f;
#pragma unroll
    for (int i = 0; i < CC; ++i) se += __expf(lg[i] - mm);
    mred[0] = mm;
    mred[1] = __logf(se);
  }
  __syncthreads();
  if (t < CC) dout[g * CC + t] = lg[t] - mred[0] - mred[1];
}

extern "C" void kernel_launch(void* const* d_in, const int* in_sizes, int n_in,
                              void* d_out, int out_size, void* d_ws, size_t ws_size,
                              hipStream_t stream) {
  const float* x     = (const float*)d_in[0];
  const int* ei      = (const int*)d_in[1];
  const float* enorm = (const float*)d_in[2];
  const int* etype   = (const int*)d_in[3];
  const int* seq     = (const int*)d_in[4];
  const float* w1_rel  = (const float*)d_in[6];
  const float* w1_root = (const float*)d_in[7];
  const float* b1      = (const float*)d_in[8];
  const float* bases   = (const float*)d_in[9];
  const float* comp    = (const float*)d_in[10];
  const float* w2      = (const float*)d_in[11];
  const float* b2      = (const float*)d_in[12];
  const float* lin_w   = (const float*)d_in[13];
  const float* lin_b   = (const float*)d_in[14];
  const float* fc_w    = (const float*)d_in[15];
  const float* fc_b    = (const float*)d_in[16];
  float* dout = (float*)d_out;

  char* p = (char*)d_ws;
  float* h    = (float*)p;  p += (size_t)NN * 64 * 4;   // 25.6 MB (fp32 root part)
  float* xw   = (float*)p;  p += (size_t)NN * 64 * 4;   // 25.6 MB
  float* out  = (float*)p;  p += (size_t)NN * 64 * 4;   // 25.6 MB (ctr2 aliases pre-root2)
  unsigned short* y_bf = (unsigned short*)p; p += (size_t)NE * 64 * 2;  // 64 MB
  unsigned short* h_bf = (unsigned short*)p; p += (size_t)NN * 64 * 2;  // 12.8 MB
  unsigned short* Wt   = (unsigned short*)p; p += (size_t)RR * 4096 * 2;
  unsigned short* wcat = (unsigned short*)p; p += (size_t)128 * 128 * 2;
  unsigned short* w2t  = (unsigned short*)p; p += (size_t)64 * 64 * 2;
  int* perm1   = (int*)p; p += (size_t)NE * 4;
  int* perm2b  = (int*)p; p += (size_t)NE * 4;
  int* es      = (int*)p; p += (size_t)NE * 4;
  float* en    = (float*)p; p += (size_t)NE * 4;
  int* hist2   = (int*)p; p += (size_t)NN * RR * 4;     // 6.4 MB (= per-(dst,r) counts)
  int* rowptr2 = (int*)p; p += (size_t)NN * RR * 4;     // 6.4 MB
  int* bsum    = (int*)p; p += (size_t)NGROUP * 4;
  int* hist1   = (int*)p; p += 64;
  int* ctr1    = (int*)p; p += 64;
  int* offs    = (int*)p; p += 68;
  int* bounds  = (int*)p; p += (size_t)GG * 4;
  int* ctr2    = (int*)out;  // safe: out first written by k_root2_mfma, after k_perm2

  hipMemsetAsync(hist2, 0, (size_t)NN * RR * 4, stream);
  hipMemsetAsync(hist1, 0, 128, stream);  // hist1 + ctr1

  hipLaunchKernelGGL(k_basis, dim3(256), dim3(256), 0, stream, comp, bases, Wt);
  hipLaunchKernelGGL(k_wcvt, dim3(80), dim3(256), 0, stream, w1_root, w1_rel, w2, wcat, w2t);
  hipLaunchKernelGGL(k_proj_mfma, dim3((NGROUP + 3) / 4), dim3(256), 0, stream,
                     x, wcat, b1, h, xw);
  hipLaunchKernelGGL(k_hists, dim3(512), dim3(256), 0, stream, ei, etype, hist1, hist2);
  hipLaunchKernelGGL(k_scan1, dim3(1), dim3(64), 0, stream, hist1, offs, ctr1);
  hipLaunchKernelGGL(k_perm1, dim3((NE + 255) / 256), dim3(256), 0, stream, etype, ctr1, perm1);
  hipLaunchKernelGGL(k_scanA, dim3(NGROUP), dim3(256), 0, stream, hist2, bsum);
  hipLaunchKernelGGL(k_scanB, dim3(1), dim3(256), 0, stream, bsum);
  hipLaunchKernelGGL(k_scanC, dim3(NGROUP), dim3(256), 0, stream, hist2, bsum, rowptr2);
  hipMemcpyAsync(ctr2, rowptr2, (size_t)NN * RR * 4, hipMemcpyDeviceToDevice, stream);
  hipLaunchKernelGGL(k_perm2, dim3((NE + 255) / 256), dim3(256), 0, stream,
                     perm1, ei, etype, enorm, ctr2, perm2b, es, en);
  hipLaunchKernelGGL(k_gconv_seg, dim3(NN / 4), dim3(256), 0, stream,
                     rowptr2, es, en, xw, h, h_bf);
  hipLaunchKernelGGL(k_root2_mfma, dim3((NGROUP + 3) / 4), dim3(256), 0, stream,
                     h_bf, w2t, b2, out);
  hipLaunchKernelGGL(k_rgcn_y, dim3(RR, 128), dim3(256), 0, stream,
                     perm1, ei, offs, h_bf, Wt, hist2, y_bf);
  hipLaunchKernelGGL(k_ysum, dim3(NN / 4), dim3(256), 0, stream, rowptr2, perm2b, y_bf, out);
  hipLaunchKernelGGL(k_bounds, dim3(1), dim3(256), 0, stream, seq, bounds);
  hipLaunchKernelGGL(k_head, dim3(GG), dim3(256), 0, stream, x, out, bounds,
                     lin_w, lin_b, fc_w, fc_b, dout);
}

// Round 5
// 456.034 us; speedup vs baseline: 1.3097x; 1.0165x over previous
//
#include <hip/hip_runtime.h>
#include <hip/hip_bf16.h>

#define NN 100000   // nodes
#define NE 500000   // edges
#define FD 128      // input features
#define HD 64       // hidden
#define RR 16       // relations
#define NBASE 30    // bases
#define GG 1000     // graphs
#define CC 10       // classes
#define NGROUP 6250 // NN/16

typedef __attribute__((ext_vector_type(8))) short bf16x8;
typedef __attribute__((ext_vector_type(4))) float f32x4;

__device__ inline unsigned short f2b(float x) {
  __hip_bfloat16 b = __float2bfloat16(x);
  return *reinterpret_cast<unsigned short*>(&b);
}
__device__ inline float b2f(unsigned short u) {
  return __uint_as_float(((unsigned)u) << 16);
}

// ---------------- Wt[r][n][k] = sum_b comp[r,b]*bases[b][k][n] (bf16, B-layout) ----------------
__global__ void k_basis(const float* comp, const float* bases, unsigned short* Wt) {
  int idx = blockIdx.x * 256 + threadIdx.x;  // r*4096 + k*64 + n
  int r = idx >> 12, kj = idx & 4095;
  int k = kj >> 6, n = kj & 63;
  float acc = 0.0f;
  for (int b = 0; b < NBASE; ++b)
    acc += comp[r * NBASE + b] * bases[b * 4096 + kj];
  Wt[(r << 12) + n * 64 + k] = f2b(acc);
}

// ---------------- weight conversions: wcat[n<64:root|n>=64:rel][k], w2t[n][k] ----------------
__global__ void k_wcvt(const float* w_root, const float* w_rel, const float* w2,
                       unsigned short* wcat, unsigned short* w2t) {
  int idx = blockIdx.x * 256 + threadIdx.x;
  if (idx < 16384) {
    int n = idx >> 7, k = idx & 127;
    float v = (n < 64) ? w_root[k * 64 + n] : w_rel[k * 64 + (n - 64)];
    wcat[n * 128 + k] = f2b(v);
  } else if (idx < 16384 + 4096) {
    int i2 = idx - 16384;
    int n = i2 >> 6, k = i2 & 63;
    w2t[n * 64 + k] = f2b(w2[k * 64 + n]);
  }
}

// ---------------- h = x@w_root + b1 (fp32) ; xw_bf = bf16(x@w_rel)  (MFMA, K-split) ----------------
// Block = 1 group of 16 nodes; 4 waves each own K-chunk of 32; LDS reduce + coalesced store.
__global__ __launch_bounds__(256) void k_proj_mfma(const float* x, const unsigned short* wcat,
                                                   const float* b1, float* h,
                                                   unsigned short* xw_bf) {
  __shared__ float red[4][64][33];          // +1 pad: lanes stride 33 -> 2-way max
  __shared__ float ldsH[16][68];            // 68: 16B-aligned rows, conflict-lite
  __shared__ unsigned short ldsX[16][72];   // 72: 16B-aligned rows
  int wv = threadIdx.x >> 6, l = threadIdx.x & 63, m = l & 15, q = l >> 4;
  int n0 = blockIdx.x * 16;
  const float* xr = x + (size_t)(n0 + m) * FD + wv * 32 + q * 8;
  float4 xa = *reinterpret_cast<const float4*>(xr);
  float4 xb = *reinterpret_cast<const float4*>(xr + 4);
  bf16x8 a;
  a[0] = (short)f2b(xa.x); a[1] = (short)f2b(xa.y);
  a[2] = (short)f2b(xa.z); a[3] = (short)f2b(xa.w);
  a[4] = (short)f2b(xb.x); a[5] = (short)f2b(xb.y);
  a[6] = (short)f2b(xb.z); a[7] = (short)f2b(xb.w);
  f32x4 zero = {0.0f, 0.0f, 0.0f, 0.0f};
#pragma unroll
  for (int nt = 0; nt < 8; ++nt) {
    bf16x8 b = *reinterpret_cast<const bf16x8*>(wcat + (nt * 16 + m) * 128 + wv * 32 + q * 8);
    f32x4 acc = __builtin_amdgcn_mfma_f32_16x16x32_bf16(a, b, zero, 0, 0, 0);
#pragma unroll
    for (int i = 0; i < 4; ++i) red[wv][l][nt * 4 + i] = acc[i];
  }
  __syncthreads();
#pragma unroll
  for (int t2 = 0; t2 < 2; ++t2) {
    int nt = wv * 2 + t2;   // waves 0,1 -> h tiles 0..3; waves 2,3 -> xw tiles 4..7
    float s0 = 0, s1 = 0, s2 = 0, s3 = 0;
#pragma unroll
    for (int w = 0; w < 4; ++w) {
      s0 += red[w][l][nt * 4 + 0];
      s1 += red[w][l][nt * 4 + 1];
      s2 += red[w][l][nt * 4 + 2];
      s3 += red[w][l][nt * 4 + 3];
    }
    if (nt < 4) {
      float bb = b1[nt * 16 + m];
      ldsH[q * 4 + 0][nt * 16 + m] = s0 + bb;
      ldsH[q * 4 + 1][nt * 16 + m] = s1 + bb;
      ldsH[q * 4 + 2][nt * 16 + m] = s2 + bb;
      ldsH[q * 4 + 3][nt * 16 + m] = s3 + bb;
    } else {
      int cc = (nt - 4) * 16 + m;
      ldsX[q * 4 + 0][cc] = f2b(s0);
      ldsX[q * 4 + 1][cc] = f2b(s1);
      ldsX[q * 4 + 2][cc] = f2b(s2);
      ldsX[q * 4 + 3][cc] = f2b(s3);
    }
  }
  __syncthreads();
  int t = threadIdx.x;
  {  // h: 16 rows x 256B, 256 threads x float4
    int row = t >> 4, c4 = (t & 15) * 4;
    float4 v = *reinterpret_cast<const float4*>(&ldsH[row][c4]);
    *reinterpret_cast<float4*>(&h[(size_t)(n0 + row) * 64 + c4]) = v;
  }
  if (t < 128) {  // xw_bf: 16 rows x 128B, 128 threads x 16B
    int row = t >> 3, c8 = (t & 7) * 8;
    uint4 v = *reinterpret_cast<const uint4*>(&ldsX[row][c8]);
    *reinterpret_cast<uint4*>(&xw_bf[(size_t)(n0 + row) * 64 + c8]) = v;
  }
}

// ---------------- histograms: hist1[type] (LDS-priv), hist2[dst*16+type] ----------------
__global__ void k_hists(const int* ei, const int* etype, int* hist1, int* hist2) {
  __shared__ int lh[RR];
  if (threadIdx.x < RR) lh[threadIdx.x] = 0;
  __syncthreads();
  for (int e = blockIdx.x * 256 + threadIdx.x; e < NE; e += gridDim.x * 256) {
    int t = etype[e];
    atomicAdd(&lh[t], 1);
    atomicAdd(&hist2[ei[NE + e] * RR + t], 1);
  }
  __syncthreads();
  if (threadIdx.x < RR) atomicAdd(&hist1[threadIdx.x], lh[threadIdx.x]);
}

// ---------------- 16-bin scan ----------------
__global__ void k_scan1(const int* hist1, int* offs, int* ctr1) {
  if (threadIdx.x == 0) {
    int s = 0;
    for (int r = 0; r < RR; ++r) { offs[r] = s; ctr1[r] = s; s += hist1[r]; }
    offs[RR] = s;
  }
}

// ---------------- type-sort scatter -> perm1 ----------------
__global__ void k_perm1(const int* etype, int* ctr1, int* perm1) {
  __shared__ int lcnt[RR], lbase[RR];
  if (threadIdx.x < RR) lcnt[threadIdx.x] = 0;
  __syncthreads();
  int e = blockIdx.x * 256 + threadIdx.x;
  int t = 0, rank = 0;
  bool valid = e < NE;
  if (valid) { t = etype[e]; rank = atomicAdd(&lcnt[t], 1); }
  __syncthreads();
  if (threadIdx.x < RR) {
    int n = lcnt[threadIdx.x];
    lbase[threadIdx.x] = n ? atomicAdd(&ctr1[threadIdx.x], n) : 0;
  }
  __syncthreads();
  if (valid) perm1[lbase[t] + rank] = e;
}

// ---------------- hierarchical scan of hist2 (1.6M) -> rowptr2 (+ctr2 copy) ----------------
__device__ inline int block_scan_incl(int v, int* ps, int t) {
  ps[t] = v;
  __syncthreads();
  for (int off = 1; off < 256; off <<= 1) {
    int u = (t >= off) ? ps[t - off] : 0;
    __syncthreads();
    ps[t] += u;
    __syncthreads();
  }
  return ps[t];
}

__global__ void k_scanA(const int* hist2, int* bsum) {
  __shared__ int red[256];
  int t = threadIdx.x;
  red[t] = hist2[blockIdx.x * 256 + t];
  __syncthreads();
  for (int s = 128; s; s >>= 1) {
    if (t < s) red[t] += red[t + s];
    __syncthreads();
  }
  if (t == 0) bsum[blockIdx.x] = red[0];
}

__global__ void k_scanB(int* bsum) {  // 6250 = 250*25, in-place exclusive scan
  int t = threadIdx.x;
  int loc[25];
  int s = 0;
  if (t < 250) {
    for (int i = 0; i < 25; ++i) { loc[i] = bsum[t * 25 + i]; s += loc[i]; }
  }
  __shared__ int ps[256];
  int incl = block_scan_incl(s, ps, t);
  int base = incl - s;
  if (t < 250) {
    int run = base;
    for (int i = 0; i < 25; ++i) { int tmp = loc[i]; bsum[t * 25 + i] = run; run += tmp; }
  }
}

__global__ void k_scanC(const int* hist2, const int* bsum, int* rowptr2, int* ctr2) {
  int t = threadIdx.x;
  int gid = blockIdx.x * 256 + t;
  int v = hist2[gid];
  __shared__ int ps[256];
  int incl = block_scan_incl(v, ps, t);
  int ex = bsum[blockIdx.x] + incl - v;
  rowptr2[gid] = ex;
  ctr2[gid] = ex;
}

// ---------------- dst-sort scatter: es/en at dst-pos; pos2[type_pos] = dst_pos ----------------
__global__ void k_perm2(const int* perm1, const int* ei, const int* etype, const float* enorm,
                        int* ctr2, int* pos2, int* es, float* en) {
  int p = blockIdx.x * 256 + threadIdx.x;
  if (p >= NE) return;
  int e = perm1[p];
  int key = ei[NE + e] * RR + etype[e];
  int pos = atomicAdd(&ctr2[key], 1);
  pos2[p] = pos;
  es[pos] = ei[e];
  en[pos] = enorm[e];
}

// ---------------- GraphConv segment-sum: h_bf[dst] = bf16(h_root + sum xw[src]*norm) ----------------
__global__ __launch_bounds__(256) void k_gconv_seg(const int* rowptr2, const int* es,
    const float* en, const unsigned short* xw_bf, const float* h, unsigned short* h_bf) {
  int wv = threadIdx.x >> 6, j = threadIdx.x & 63;
  int dst = blockIdx.x * 4 + wv;
  int lo = rowptr2[dst * RR];
  int hi = (dst == NN - 1) ? NE : rowptr2[(dst + 1) * RR];
  float acc = h[(size_t)dst * 64 + j];
  for (int base = lo; base < hi; base += 64) {
    int n = min(64, hi - base);
    int sv = 0;
    float nv = 0.0f;
    if (j < n) { sv = es[base + j]; nv = en[base + j]; }
    for (int k = 0; k < n; ++k) {
      int s = __shfl(sv, k);
      float w = __shfl(nv, k);
      acc += b2f(xw_bf[(size_t)s * 64 + j]) * w;
    }
  }
  h_bf[(size_t)dst * 64 + j] = f2b(acc);
}

// ---------------- out = h_bf @ w2t + b2  (MFMA) ----------------
__global__ __launch_bounds__(256) void k_root2_mfma(const unsigned short* h_bf,
    const unsigned short* w2t, const float* b2, float* out) {
  int wv = threadIdx.x >> 6, l = threadIdx.x & 63, m = l & 15, q = l >> 4;
  int g = blockIdx.x * 4 + wv;
  if (g >= NGROUP) return;
  int n0 = g * 16;
  f32x4 acc[4];
#pragma unroll
  for (int nt = 0; nt < 4; ++nt) acc[nt] = (f32x4){0, 0, 0, 0};
#pragma unroll
  for (int s = 0; s < 2; ++s) {
    bf16x8 a = *reinterpret_cast<const bf16x8*>(h_bf + (size_t)(n0 + m) * 64 + s * 32 + q * 8);
#pragma unroll
    for (int nt = 0; nt < 4; ++nt) {
      bf16x8 b = *reinterpret_cast<const bf16x8*>(w2t + (nt * 16 + m) * 64 + s * 32 + q * 8);
      acc[nt] = __builtin_amdgcn_mfma_f32_16x16x32_bf16(a, b, acc[nt], 0, 0, 0);
    }
  }
  float b2v[4];
#pragma unroll
  for (int nt = 0; nt < 4; ++nt) b2v[nt] = b2[nt * 16 + m];
#pragma unroll
  for (int i = 0; i < 4; ++i) {
    size_t row = n0 + q * 4 + i;
#pragma unroll
    for (int nt = 0; nt < 4; ++nt)
      out[row * 64 + nt * 16 + m] = acc[nt][i] + b2v[nt];
  }
}

// ---------------- RGCN via MFMA; y rows written at dst-ordered slots (scatter-write) ----------------
__global__ __launch_bounds__(256) void k_rgcn_y(const int* perm1, const int* ei,
    const int* offs, const int* pos2, const unsigned short* h_bf, const unsigned short* Wt,
    const int* hist2, unsigned short* y_bf) {
  int r = blockIdx.x;
  int lo = offs[r], hi = offs[r + 1];
  int cnt = hi - lo;
  int wv = threadIdx.x >> 6;
  int l = threadIdx.x & 63;
  int m = l & 15, q = l >> 4;
  int ngroups = (cnt + 15) / 16;
  const unsigned short* Wr = Wt + (r << 12);
  bf16x8 bfr[2][4];
#pragma unroll
  for (int s = 0; s < 2; ++s)
#pragma unroll
    for (int nt = 0; nt < 4; ++nt)
      bfr[s][nt] = *reinterpret_cast<const bf16x8*>(Wr + (nt * 16 + m) * 64 + s * 32 + q * 8);

  for (int g = blockIdx.y * 4 + wv; g < ngroups; g += gridDim.y * 4) {
    int base = lo + g * 16;
    int ne = min(16, hi - base);
    int p = base + ((m < ne) ? m : 0);
    int ed = perm1[p];
    int src = ei[ed];
    int dst = ei[NE + ed];
    int pos = pos2[p];
    float inv = 1.0f / (float)max(hist2[dst * RR + r], 1);
    f32x4 acc[4];
#pragma unroll
    for (int nt = 0; nt < 4; ++nt) acc[nt] = (f32x4){0, 0, 0, 0};
    const unsigned short* hrow = h_bf + (size_t)src * 64 + q * 8;
#pragma unroll
    for (int s = 0; s < 2; ++s) {
      bf16x8 afr = *reinterpret_cast<const bf16x8*>(hrow + s * 32);
#pragma unroll
      for (int nt = 0; nt < 4; ++nt)
        acc[nt] = __builtin_amdgcn_mfma_f32_16x16x32_bf16(afr, bfr[s][nt], acc[nt], 0, 0, 0);
    }
#pragma unroll
    for (int i = 0; i < 4; ++i) {
      int row = q * 4 + i;
      float ir = __shfl(inv, row);
      int pr = __shfl(pos, row);
      if (row < ne) {
#pragma unroll
        for (int nt = 0; nt < 4; ++nt)
          y_bf[(size_t)pr * 64 + nt * 16 + m] = f2b(acc[nt][i] * ir);
      }
    }
  }
}

// ---------------- per-dst y-row streaming sum (coalesced): out[dst] += sum y ----------------
__global__ __launch_bounds__(256) void k_ysum(const int* rowptr2, const unsigned short* y_bf,
                                              float* out) {
  int wv = threadIdx.x >> 6, j = threadIdx.x & 63;
  int dst = blockIdx.x * 4 + wv;
  int lo = rowptr2[dst * RR];
  int hi = (dst == NN - 1) ? NE : rowptr2[(dst + 1) * RR];
  float acc = out[(size_t)dst * 64 + j];
  for (int k = lo; k < hi; ++k)
    acc += b2f(y_bf[(size_t)k * 64 + j]);
  out[(size_t)dst * 64 + j] = acc;
}

// ---------------- graph bounds ----------------
__global__ void k_bounds(const int* seq, int* bounds) {
  __shared__ int s[GG];
  for (int i = threadIdx.x; i < GG; i += 256) s[i] = seq[i];
  __syncthreads();
  if (threadIdx.x == 0) {
    int acc = 0;
    for (int g = 0; g < GG; ++g) { acc += s[g]; bounds[g] = acc; }
  }
}

// ---------------- fused pool + MLP head + log_softmax (1024 thr, 5-way node parallel) ----------------
__global__ __launch_bounds__(1024) void k_head(const float* x, const float* outn,
    const int* bounds, const float* lin_w, const float* lin_b,
    const float* fc_w, const float* fc_b, float* dout) {
  __shared__ float psum[5][192], pmax[5][192];
  __shared__ float gsum[192], gmax[192], hid[HD], lg[CC], mred[2];
  int g = blockIdx.x, t = threadIdx.x;
  int lo = (g == 0) ? 0 : bounds[g - 1];
  int hi = bounds[g];
  int nn = hi - lo;
  if (t < 960) {
    int col = t % 192, ch = t / 192;
    int a = lo + (nn * ch) / 5, b = lo + (nn * (ch + 1)) / 5;
    float s = 0.0f, mx = -3.4e38f;
    for (int n = a; n < b; ++n) {
      float v = (col < FD) ? x[(size_t)n * FD + col] : outn[(size_t)n * 64 + (col - FD)];
      s += v;
      mx = fmaxf(mx, v);
    }
    psum[ch][col] = s;
    pmax[ch][col] = mx;
  }
  __syncthreads();
  if (t < 192) {
    float s = 0.0f, mx = -3.4e38f;
#pragma unroll
    for (int ch = 0; ch < 5; ++ch) {
      s += psum[ch][t];
      mx = fmaxf(mx, pmax[ch][t]);
    }
    gsum[t] = s;
    gmax[t] = mx;
  }
  __syncthreads();
  if (t < HD) {
    float a = lin_b[t];
    for (int k = 0; k < 192; ++k) a += gsum[k] * lin_w[k * 64 + t];
    for (int k = 0; k < 192; ++k) a += gmax[k] * lin_w[(192 + k) * 64 + t];
    hid[t] = fmaxf(a, 0.0f);
  }
  __syncthreads();
  if (t < CC) {
    float a = fc_b[t];
    for (int k = 0; k < HD; ++k) a += hid[k] * fc_w[k * CC + t];
    lg[t] = a;
  }
  __syncthreads();
  if (t == 0) {
    float mm = lg[0];
#pragma unroll
    for (int i = 1; i < CC; ++i) mm = fmaxf(mm, lg[i]);
    float se = 0.0f;
#pragma unroll
    for (int i = 0; i < CC; ++i) se += __expf(lg[i] - mm);
    mred[0] = mm;
    mred[1] = __logf(se);
  }
  __syncthreads();
  if (t < CC) dout[g * CC + t] = lg[t] - mred[0] - mred[1];
}

extern "C" void kernel_launch(void* const* d_in, const int* in_sizes, int n_in,
                              void* d_out, int out_size, void* d_ws, size_t ws_size,
                              hipStream_t stream) {
  const float* x     = (const float*)d_in[0];
  const int* ei      = (const int*)d_in[1];
  const float* enorm = (const float*)d_in[2];
  const int* etype   = (const int*)d_in[3];
  const int* seq     = (const int*)d_in[4];
  const float* w1_rel  = (const float*)d_in[6];
  const float* w1_root = (const float*)d_in[7];
  const float* b1      = (const float*)d_in[8];
  const float* bases   = (const float*)d_in[9];
  const float* comp    = (const float*)d_in[10];
  const float* w2      = (const float*)d_in[11];
  const float* b2      = (const float*)d_in[12];
  const float* lin_w   = (const float*)d_in[13];
  const float* lin_b   = (const float*)d_in[14];
  const float* fc_w    = (const float*)d_in[15];
  const float* fc_b    = (const float*)d_in[16];
  float* dout = (float*)d_out;

  char* p = (char*)d_ws;
  float* h    = (float*)p;  p += (size_t)NN * 64 * 4;                    // 25.6 MB
  unsigned short* xw_bf = (unsigned short*)p; p += (size_t)NN * 64 * 2;  // 12.8 MB
  float* out  = (float*)p;  p += (size_t)NN * 64 * 4;                    // 25.6 MB (ctr2 aliases)
  unsigned short* y_bf = (unsigned short*)p; p += (size_t)NE * 64 * 2;   // 64 MB
  unsigned short* h_bf = (unsigned short*)p; p += (size_t)NN * 64 * 2;   // 12.8 MB
  unsigned short* Wt   = (unsigned short*)p; p += (size_t)RR * 4096 * 2;
  unsigned short* wcat = (unsigned short*)p; p += (size_t)128 * 128 * 2;
  unsigned short* w2t  = (unsigned short*)p; p += (size_t)64 * 64 * 2;
  int* perm1   = (int*)p; p += (size_t)NE * 4;
  int* pos2    = (int*)p; p += (size_t)NE * 4;
  int* es      = (int*)p; p += (size_t)NE * 4;
  float* en    = (float*)p; p += (size_t)NE * 4;
  int* hist2   = (int*)p; p += (size_t)NN * RR * 4;     // 6.4 MB (= per-(dst,r) counts)
  int* rowptr2 = (int*)p; p += (size_t)NN * RR * 4;     // 6.4 MB
  int* bsum    = (int*)p; p += (size_t)NGROUP * 4;
  int* hist1   = (int*)p; p += 64;
  int* ctr1    = (int*)p; p += 64;
  int* offs    = (int*)p; p += 68;
  int* bounds  = (int*)p; p += (size_t)GG * 4;
  int* ctr2    = (int*)out;  // safe: out first written by k_root2_mfma (after k_perm2)

  hipMemsetAsync(hist2, 0, (size_t)NN * RR * 4, stream);
  hipMemsetAsync(hist1, 0, 128, stream);  // hist1 + ctr1

  hipLaunchKernelGGL(k_basis, dim3(256), dim3(256), 0, stream, comp, bases, Wt);
  hipLaunchKernelGGL(k_wcvt, dim3(80), dim3(256), 0, stream, w1_root, w1_rel, w2, wcat, w2t);
  hipLaunchKernelGGL(k_proj_mfma, dim3(NGROUP), dim3(256), 0, stream, x, wcat, b1, h, xw_bf);
  hipLaunchKernelGGL(k_hists, dim3(512), dim3(256), 0, stream, ei, etype, hist1, hist2);
  hipLaunchKernelGGL(k_scan1, dim3(1), dim3(64), 0, stream, hist1, offs, ctr1);
  hipLaunchKernelGGL(k_perm1, dim3((NE + 255) / 256), dim3(256), 0, stream, etype, ctr1, perm1);
  hipLaunchKernelGGL(k_scanA, dim3(NGROUP), dim3(256), 0, stream, hist2, bsum);
  hipLaunchKernelGGL(k_scanB, dim3(1), dim3(256), 0, stream, bsum);
  hipLaunchKernelGGL(k_scanC, dim3(NGROUP), dim3(256), 0, stream, hist2, bsum, rowptr2, ctr2);
  hipLaunchKernelGGL(k_perm2, dim3((NE + 255) / 256), dim3(256), 0, stream,
                     perm1, ei, etype, enorm, ctr2, pos2, es, en);
  hipLaunchKernelGGL(k_gconv_seg, dim3(NN / 4), dim3(256), 0, stream,
                     rowptr2, es, en, xw_bf, h, h_bf);
  hipLaunchKernelGGL(k_root2_mfma, dim3((NGROUP + 3) / 4), dim3(256), 0, stream,
                     h_bf, w2t, b2, out);
  hipLaunchKernelGGL(k_rgcn_y, dim3(RR, 128), dim3(256), 0, stream,
                     perm1, ei, offs, pos2, h_bf, Wt, hist2, y_bf);
  hipLaunchKernelGGL(k_ysum, dim3(NN / 4), dim3(256), 0, stream, rowptr2, y_bf, out);
  hipLaunchKernelGGL(k_bounds, dim3(1), dim3(256), 0, stream, seq, bounds);
  hipLaunchKernelGGL(k_head, dim3(GG), dim3(1024), 0, stream, x, out, bounds,
                     lin_w, lin_b, fc_w, fc_b, dout);
}

// Round 6
// 420.179 us; speedup vs baseline: 1.4215x; 1.0853x over previous
//
#include <hip/hip_runtime.h>
#include <hip/hip_bf16.h>

#define NN 100000   // nodes
#define NE 500000   // edges
#define FD 128      // input features
#define HD 64       // hidden
#define RR 16       // relations
#define NBASE 30    // bases
#define GG 1000     // graphs
#define CC 10       // classes
#define NGROUP 6250 // NN/16

typedef __attribute__((ext_vector_type(8))) short bf16x8;
typedef __attribute__((ext_vector_type(4))) float f32x4;

__device__ inline unsigned short f2b(float x) {
  __hip_bfloat16 b = __float2bfloat16(x);
  return *reinterpret_cast<unsigned short*>(&b);
}
__device__ inline float b2f(unsigned short u) {
  return __uint_as_float(((unsigned)u) << 16);
}

// ---------------- Wt[r][n][k] = sum_b comp[r,b]*bases[b][k][n] (bf16, B-layout) ----------------
__global__ void k_basis(const float* comp, const float* bases, unsigned short* Wt) {
  int idx = blockIdx.x * 256 + threadIdx.x;  // r*4096 + k*64 + n
  int r = idx >> 12, kj = idx & 4095;
  int k = kj >> 6, n = kj & 63;
  float acc = 0.0f;
  for (int b = 0; b < NBASE; ++b)
    acc += comp[r * NBASE + b] * bases[b * 4096 + kj];
  Wt[(r << 12) + n * 64 + k] = f2b(acc);
}

// ---------------- weight conversions: wcat[n<64:root|n>=64:rel][k], w2t[n][k] ----------------
__global__ void k_wcvt(const float* w_root, const float* w_rel, const float* w2,
                       unsigned short* wcat, unsigned short* w2t) {
  int idx = blockIdx.x * 256 + threadIdx.x;
  if (idx < 16384) {
    int n = idx >> 7, k = idx & 127;
    float v = (n < 64) ? w_root[k * 64 + n] : w_rel[k * 64 + (n - 64)];
    wcat[n * 128 + k] = f2b(v);
  } else if (idx < 16384 + 4096) {
    int i2 = idx - 16384;
    int n = i2 >> 6, k = i2 & 63;
    w2t[n * 64 + k] = f2b(w2[k * 64 + n]);
  }
}

// ---------------- h = x@w_root + b1 (fp32) ; xw_bf = bf16(x@w_rel)  (MFMA, K-split) ----------------
__global__ __launch_bounds__(256) void k_proj_mfma(const float* x, const unsigned short* wcat,
                                                   const float* b1, float* h,
                                                   unsigned short* xw_bf) {
  __shared__ float red[4][64][33];
  __shared__ float ldsH[16][68];
  __shared__ unsigned short ldsX[16][72];
  int wv = threadIdx.x >> 6, l = threadIdx.x & 63, m = l & 15, q = l >> 4;
  int n0 = blockIdx.x * 16;
  const float* xr = x + (size_t)(n0 + m) * FD + wv * 32 + q * 8;
  float4 xa = *reinterpret_cast<const float4*>(xr);
  float4 xb = *reinterpret_cast<const float4*>(xr + 4);
  bf16x8 a;
  a[0] = (short)f2b(xa.x); a[1] = (short)f2b(xa.y);
  a[2] = (short)f2b(xa.z); a[3] = (short)f2b(xa.w);
  a[4] = (short)f2b(xb.x); a[5] = (short)f2b(xb.y);
  a[6] = (short)f2b(xb.z); a[7] = (short)f2b(xb.w);
  f32x4 zero = {0.0f, 0.0f, 0.0f, 0.0f};
#pragma unroll
  for (int nt = 0; nt < 8; ++nt) {
    bf16x8 b = *reinterpret_cast<const bf16x8*>(wcat + (nt * 16 + m) * 128 + wv * 32 + q * 8);
    f32x4 acc = __builtin_amdgcn_mfma_f32_16x16x32_bf16(a, b, zero, 0, 0, 0);
#pragma unroll
    for (int i = 0; i < 4; ++i) red[wv][l][nt * 4 + i] = acc[i];
  }
  __syncthreads();
#pragma unroll
  for (int t2 = 0; t2 < 2; ++t2) {
    int nt = wv * 2 + t2;
    float s0 = 0, s1 = 0, s2 = 0, s3 = 0;
#pragma unroll
    for (int w = 0; w < 4; ++w) {
      s0 += red[w][l][nt * 4 + 0];
      s1 += red[w][l][nt * 4 + 1];
      s2 += red[w][l][nt * 4 + 2];
      s3 += red[w][l][nt * 4 + 3];
    }
    if (nt < 4) {
      float bb = b1[nt * 16 + m];
      ldsH[q * 4 + 0][nt * 16 + m] = s0 + bb;
      ldsH[q * 4 + 1][nt * 16 + m] = s1 + bb;
      ldsH[q * 4 + 2][nt * 16 + m] = s2 + bb;
      ldsH[q * 4 + 3][nt * 16 + m] = s3 + bb;
    } else {
      int cc = (nt - 4) * 16 + m;
      ldsX[q * 4 + 0][cc] = f2b(s0);
      ldsX[q * 4 + 1][cc] = f2b(s1);
      ldsX[q * 4 + 2][cc] = f2b(s2);
      ldsX[q * 4 + 3][cc] = f2b(s3);
    }
  }
  __syncthreads();
  int t = threadIdx.x;
  {
    int row = t >> 4, c4 = (t & 15) * 4;
    float4 v = *reinterpret_cast<const float4*>(&ldsH[row][c4]);
    *reinterpret_cast<float4*>(&h[(size_t)(n0 + row) * 64 + c4]) = v;
  }
  if (t < 128) {
    int row = t >> 3, c8 = (t & 7) * 8;
    uint4 v = *reinterpret_cast<const uint4*>(&ldsX[row][c8]);
    *reinterpret_cast<uint4*>(&xw_bf[(size_t)(n0 + row) * 64 + c8]) = v;
  }
}

// ---------------- histograms ----------------
__global__ void k_hists(const int* ei, const int* etype, int* hist1, int* hist2) {
  __shared__ int lh[RR];
  if (threadIdx.x < RR) lh[threadIdx.x] = 0;
  __syncthreads();
  for (int e = blockIdx.x * 256 + threadIdx.x; e < NE; e += gridDim.x * 256) {
    int t = etype[e];
    atomicAdd(&lh[t], 1);
    atomicAdd(&hist2[ei[NE + e] * RR + t], 1);
  }
  __syncthreads();
  if (threadIdx.x < RR) atomicAdd(&hist1[threadIdx.x], lh[threadIdx.x]);
}

__global__ void k_scan1(const int* hist1, int* offs, int* ctr1) {
  if (threadIdx.x == 0) {
    int s = 0;
    for (int r = 0; r < RR; ++r) { offs[r] = s; ctr1[r] = s; s += hist1[r]; }
    offs[RR] = s;
  }
}

__global__ void k_perm1(const int* etype, int* ctr1, int* perm1) {
  __shared__ int lcnt[RR], lbase[RR];
  if (threadIdx.x < RR) lcnt[threadIdx.x] = 0;
  __syncthreads();
  int e = blockIdx.x * 256 + threadIdx.x;
  int t = 0, rank = 0;
  bool valid = e < NE;
  if (valid) { t = etype[e]; rank = atomicAdd(&lcnt[t], 1); }
  __syncthreads();
  if (threadIdx.x < RR) {
    int n = lcnt[threadIdx.x];
    lbase[threadIdx.x] = n ? atomicAdd(&ctr1[threadIdx.x], n) : 0;
  }
  __syncthreads();
  if (valid) perm1[lbase[t] + rank] = e;
}

// ---------------- hierarchical scan of hist2 ----------------
__device__ inline int block_scan_incl(int v, int* ps, int t) {
  ps[t] = v;
  __syncthreads();
  for (int off = 1; off < 256; off <<= 1) {
    int u = (t >= off) ? ps[t - off] : 0;
    __syncthreads();
    ps[t] += u;
    __syncthreads();
  }
  return ps[t];
}

__global__ void k_scanA(const int* hist2, int* bsum) {
  __shared__ int red[256];
  int t = threadIdx.x;
  red[t] = hist2[blockIdx.x * 256 + t];
  __syncthreads();
  for (int s = 128; s; s >>= 1) {
    if (t < s) red[t] += red[t + s];
    __syncthreads();
  }
  if (t == 0) bsum[blockIdx.x] = red[0];
}

__global__ void k_scanB(int* bsum) {
  int t = threadIdx.x;
  int loc[25];
  int s = 0;
  if (t < 250) {
    for (int i = 0; i < 25; ++i) { loc[i] = bsum[t * 25 + i]; s += loc[i]; }
  }
  __shared__ int ps[256];
  int incl = block_scan_incl(s, ps, t);
  int base = incl - s;
  if (t < 250) {
    int run = base;
    for (int i = 0; i < 25; ++i) { int tmp = loc[i]; bsum[t * 25 + i] = run; run += tmp; }
  }
}

__global__ void k_scanC(const int* hist2, const int* bsum, int* rowptr2, int* ctr2) {
  int t = threadIdx.x;
  int gid = blockIdx.x * 256 + t;
  int v = hist2[gid];
  __shared__ int ps[256];
  int incl = block_scan_incl(v, ps, t);
  int ex = bsum[blockIdx.x] + incl - v;
  rowptr2[gid] = ex;
  ctr2[gid] = ex;
}

// ---------------- dst-sort scatter ----------------
__global__ void k_perm2(const int* perm1, const int* ei, const int* etype, const float* enorm,
                        int* ctr2, int* pos2, int* es, float* en) {
  int p = blockIdx.x * 256 + threadIdx.x;
  if (p >= NE) return;
  int e = perm1[p];
  int key = ei[NE + e] * RR + etype[e];
  int pos = atomicAdd(&ctr2[key], 1);
  pos2[p] = pos;
  es[pos] = ei[e];
  en[pos] = enorm[e];
}

// ---------------- GraphConv segment-sum ----------------
__global__ __launch_bounds__(256) void k_gconv_seg(const int* rowptr2, const int* es,
    const float* en, const unsigned short* xw_bf, const float* h, unsigned short* h_bf) {
  int wv = threadIdx.x >> 6, j = threadIdx.x & 63;
  int dst = blockIdx.x * 4 + wv;
  int lo = rowptr2[dst * RR];
  int hi = (dst == NN - 1) ? NE : rowptr2[(dst + 1) * RR];
  float acc = h[(size_t)dst * 64 + j];
  for (int base = lo; base < hi; base += 64) {
    int n = min(64, hi - base);
    int sv = 0;
    float nv = 0.0f;
    if (j < n) { sv = es[base + j]; nv = en[base + j]; }
    for (int k = 0; k < n; ++k) {
      int s = __shfl(sv, k);
      float w = __shfl(nv, k);
      acc += b2f(xw_bf[(size_t)s * 64 + j]) * w;
    }
  }
  h_bf[(size_t)dst * 64 + j] = f2b(acc);
}

// ---------------- out = h_bf @ w2t + b2  (MFMA) ----------------
__global__ __launch_bounds__(256) void k_root2_mfma(const unsigned short* h_bf,
    const unsigned short* w2t, const float* b2, float* out) {
  int wv = threadIdx.x >> 6, l = threadIdx.x & 63, m = l & 15, q = l >> 4;
  int g = blockIdx.x * 4 + wv;
  if (g >= NGROUP) return;
  int n0 = g * 16;
  f32x4 acc[4];
#pragma unroll
  for (int nt = 0; nt < 4; ++nt) acc[nt] = (f32x4){0, 0, 0, 0};
#pragma unroll
  for (int s = 0; s < 2; ++s) {
    bf16x8 a = *reinterpret_cast<const bf16x8*>(h_bf + (size_t)(n0 + m) * 64 + s * 32 + q * 8);
#pragma unroll
    for (int nt = 0; nt < 4; ++nt) {
      bf16x8 b = *reinterpret_cast<const bf16x8*>(w2t + (nt * 16 + m) * 64 + s * 32 + q * 8);
      acc[nt] = __builtin_amdgcn_mfma_f32_16x16x32_bf16(a, b, acc[nt], 0, 0, 0);
    }
  }
  float b2v[4];
#pragma unroll
  for (int nt = 0; nt < 4; ++nt) b2v[nt] = b2[nt * 16 + m];
#pragma unroll
  for (int i = 0; i < 4; ++i) {
    size_t row = n0 + q * 4 + i;
#pragma unroll
    for (int nt = 0; nt < 4; ++nt)
      out[row * 64 + nt * 16 + m] = acc[nt][i] + b2v[nt];
  }
}

// ---------------- RGCN via MFMA; y rows written at dst-ordered slots ----------------
__global__ __launch_bounds__(256) void k_rgcn_y(const int* perm1, const int* ei,
    const int* offs, const int* pos2, const unsigned short* h_bf, const unsigned short* Wt,
    const int* hist2, unsigned short* y_bf) {
  int r = blockIdx.x;
  int lo = offs[r], hi = offs[r + 1];
  int cnt = hi - lo;
  int wv = threadIdx.x >> 6;
  int l = threadIdx.x & 63;
  int m = l & 15, q = l >> 4;
  int ngroups = (cnt + 15) / 16;
  const unsigned short* Wr = Wt + (r << 12);
  bf16x8 bfr[2][4];
#pragma unroll
  for (int s = 0; s < 2; ++s)
#pragma unroll
    for (int nt = 0; nt < 4; ++nt)
      bfr[s][nt] = *reinterpret_cast<const bf16x8*>(Wr + (nt * 16 + m) * 64 + s * 32 + q * 8);

  for (int g = blockIdx.y * 4 + wv; g < ngroups; g += gridDim.y * 4) {
    int base = lo + g * 16;
    int ne = min(16, hi - base);
    int p = base + ((m < ne) ? m : 0);
    int ed = perm1[p];
    int src = ei[ed];
    int dst = ei[NE + ed];
    int pos = pos2[p];
    float inv = 1.0f / (float)max(hist2[dst * RR + r], 1);
    f32x4 acc[4];
#pragma unroll
    for (int nt = 0; nt < 4; ++nt) acc[nt] = (f32x4){0, 0, 0, 0};
    const unsigned short* hrow = h_bf + (size_t)src * 64 + q * 8;
#pragma unroll
    for (int s = 0; s < 2; ++s) {
      bf16x8 afr = *reinterpret_cast<const bf16x8*>(hrow + s * 32);
#pragma unroll
      for (int nt = 0; nt < 4; ++nt)
        acc[nt] = __builtin_amdgcn_mfma_f32_16x16x32_bf16(afr, bfr[s][nt], acc[nt], 0, 0, 0);
    }
#pragma unroll
    for (int i = 0; i < 4; ++i) {
      int row = q * 4 + i;
      float ir = __shfl(inv, row);
      int pr = __shfl(pos, row);
      if (row < ne) {
#pragma unroll
        for (int nt = 0; nt < 4; ++nt)
          y_bf[(size_t)pr * 64 + nt * 16 + m] = f2b(acc[nt][i] * ir);
      }
    }
  }
}

// ---------------- per-dst y-row streaming sum ----------------
__global__ __launch_bounds__(256) void k_ysum(const int* rowptr2, const unsigned short* y_bf,
                                              float* out) {
  int wv = threadIdx.x >> 6, j = threadIdx.x & 63;
  int dst = blockIdx.x * 4 + wv;
  int lo = rowptr2[dst * RR];
  int hi = (dst == NN - 1) ? NE : rowptr2[(dst + 1) * RR];
  float acc = out[(size_t)dst * 64 + j];
  for (int k = lo; k < hi; ++k)
    acc += b2f(y_bf[(size_t)k * 64 + j]);
  out[(size_t)dst * 64 + j] = acc;
}

// ---------------- graph bounds ----------------
__global__ void k_bounds(const int* seq, int* bounds) {
  __shared__ int s[GG];
  for (int i = threadIdx.x; i < GG; i += 256) s[i] = seq[i];
  __syncthreads();
  if (threadIdx.x == 0) {
    int acc = 0;
    for (int g = 0; g < GG; ++g) { acc += s[g]; bounds[g] = acc; }
  }
}

// ---------------- fused pool + MLP head + log_softmax (256 thr, float4, unroll-4) ----------------
__global__ __launch_bounds__(256) void k_head(const float* x, const float* outn,
    const int* bounds, const float* lin_w, const float* lin_b,
    const float* fc_w, const float* fc_b, float* dout) {
  __shared__ float4 psum[5][48], pmax[5][48];   // 5 node-chunks x 48 col-quads
  __shared__ float gsum[192], gmax[192];
  __shared__ float part[4][64];
  __shared__ float hid[HD], lg[CC], mred[2];
  int g = blockIdx.x, t = threadIdx.x;
  int lo = (g == 0) ? 0 : bounds[g - 1];
  int hi = bounds[g];
  int nn = hi - lo;
  if (t < 240) {
    int c4 = t % 48, ch = t / 48;
    int a = lo + (nn * ch) / 5, b = lo + (nn * (ch + 1)) / 5;
    float4 s = {0, 0, 0, 0};
    float4 mx = {-3.4e38f, -3.4e38f, -3.4e38f, -3.4e38f};
    const float* bp;
    int stride;
    if (c4 < 32) { bp = x + (size_t)a * FD + c4 * 4; stride = FD; }
    else         { bp = outn + (size_t)a * 64 + (c4 - 32) * 4; stride = 64; }
    int n = a;
    for (; n + 4 <= b; n += 4) {   // 4-deep unroll: 4 outstanding float4 loads
      float4 v0 = *reinterpret_cast<const float4*>(bp);
      float4 v1 = *reinterpret_cast<const float4*>(bp + stride);
      float4 v2 = *reinterpret_cast<const float4*>(bp + 2 * stride);
      float4 v3 = *reinterpret_cast<const float4*>(bp + 3 * stride);
      bp += 4 * stride;
      s.x += v0.x + v1.x + v2.x + v3.x;
      s.y += v0.y + v1.y + v2.y + v3.y;
      s.z += v0.z + v1.z + v2.z + v3.z;
      s.w += v0.w + v1.w + v2.w + v3.w;
      mx.x = fmaxf(fmaxf(fmaxf(mx.x, v0.x), fmaxf(v1.x, v2.x)), v3.x);
      mx.y = fmaxf(fmaxf(fmaxf(mx.y, v0.y), fmaxf(v1.y, v2.y)), v3.y);
      mx.z = fmaxf(fmaxf(fmaxf(mx.z, v0.z), fmaxf(v1.z, v2.z)), v3.z);
      mx.w = fmaxf(fmaxf(fmaxf(mx.w, v0.w), fmaxf(v1.w, v2.w)), v3.w);
    }
    for (; n < b; ++n) {
      float4 v = *reinterpret_cast<const float4*>(bp);
      bp += stride;
      s.x += v.x; s.y += v.y; s.z += v.z; s.w += v.w;
      mx.x = fmaxf(mx.x, v.x); mx.y = fmaxf(mx.y, v.y);
      mx.z = fmaxf(mx.z, v.z); mx.w = fmaxf(mx.w, v.w);
    }
    psum[ch][c4] = s;
    pmax[ch][c4] = mx;
  }
  __syncthreads();
  if (t < 48) {
    float4 s = psum[0][t], m = pmax[0][t];
#pragma unroll
    for (int ch = 1; ch < 5; ++ch) {
      float4 ps = psum[ch][t], pm = pmax[ch][t];
      s.x += ps.x; s.y += ps.y; s.z += ps.z; s.w += ps.w;
      m.x = fmaxf(m.x, pm.x); m.y = fmaxf(m.y, pm.y);
      m.z = fmaxf(m.z, pm.z); m.w = fmaxf(m.w, pm.w);
    }
    gsum[t * 4 + 0] = s.x; gsum[t * 4 + 1] = s.y;
    gsum[t * 4 + 2] = s.z; gsum[t * 4 + 3] = s.w;
    gmax[t * 4 + 0] = m.x; gmax[t * 4 + 1] = m.y;
    gmax[t * 4 + 2] = m.z; gmax[t * 4 + 3] = m.w;
  }
  __syncthreads();
  {  // hidden matvec: 4-way K-split over 384
    int o = t & 63, pp = t >> 6;
    float a = 0.0f;
    int k0 = pp * 96;
    for (int k = k0; k < k0 + 96; ++k) {
      float gv = (k < 192) ? gsum[k] : gmax[k - 192];
      a += gv * lin_w[k * 64 + o];
    }
    part[pp][o] = a;
  }
  __syncthreads();
  if (t < HD) {
    float a = lin_b[t] + part[0][t] + part[1][t] + part[2][t] + part[3][t];
    hid[t] = fmaxf(a, 0.0f);
  }
  __syncthreads();
  if (t < CC) {
    float a = fc_b[t];
    for (int k = 0; k < HD; ++k) a += hid[k] * fc_w[k * CC + t];
    lg[t] = a;
  }
  __syncthreads();
  if (t == 0) {
    float mm = lg[0];
#pragma unroll
    for (int i = 1; i < CC; ++i) mm = fmaxf(mm, lg[i]);
    float se = 0.0f;
#pragma unroll
    for (int i = 0; i < CC; ++i) se += __expf(lg[i] - mm);
    mred[0] = mm;
    mred[1] = __logf(se);
  }
  __syncthreads();
  if (t < CC) dout[g * CC + t] = lg[t] - mred[0] - mred[1];
}

extern "C" void kernel_launch(void* const* d_in, const int* in_sizes, int n_in,
                              void* d_out, int out_size, void* d_ws, size_t ws_size,
                              hipStream_t stream) {
  const float* x     = (const float*)d_in[0];
  const int* ei      = (const int*)d_in[1];
  const float* enorm = (const float*)d_in[2];
  const int* etype   = (const int*)d_in[3];
  const int* seq     = (const int*)d_in[4];
  const float* w1_rel  = (const float*)d_in[6];
  const float* w1_root = (const float*)d_in[7];
  const float* b1      = (const float*)d_in[8];
  const float* bases   = (const float*)d_in[9];
  const float* comp    = (const float*)d_in[10];
  const float* w2      = (const float*)d_in[11];
  const float* b2      = (const float*)d_in[12];
  const float* lin_w   = (const float*)d_in[13];
  const float* lin_b   = (const float*)d_in[14];
  const float* fc_w    = (const float*)d_in[15];
  const float* fc_b    = (const float*)d_in[16];
  float* dout = (float*)d_out;

  char* p = (char*)d_ws;
  float* h    = (float*)p;  p += (size_t)NN * 64 * 4;
  unsigned short* xw_bf = (unsigned short*)p; p += (size_t)NN * 64 * 2;
  float* out  = (float*)p;  p += (size_t)NN * 64 * 4;
  unsigned short* y_bf = (unsigned short*)p; p += (size_t)NE * 64 * 2;
  unsigned short* h_bf = (unsigned short*)p; p += (size_t)NN * 64 * 2;
  unsigned short* Wt   = (unsigned short*)p; p += (size_t)RR * 4096 * 2;
  unsigned short* wcat = (unsigned short*)p; p += (size_t)128 * 128 * 2;
  unsigned short* w2t  = (unsigned short*)p; p += (size_t)64 * 64 * 2;
  int* perm1   = (int*)p; p += (size_t)NE * 4;
  int* pos2    = (int*)p; p += (size_t)NE * 4;
  int* es      = (int*)p; p += (size_t)NE * 4;
  float* en    = (float*)p; p += (size_t)NE * 4;
  int* hist2   = (int*)p; p += (size_t)NN * RR * 4;
  int* rowptr2 = (int*)p; p += (size_t)NN * RR * 4;
  int* bsum    = (int*)p; p += (size_t)NGROUP * 4;
  int* hist1   = (int*)p; p += 64;
  int* ctr1    = (int*)p; p += 64;
  int* offs    = (int*)p; p += 68;
  int* bounds  = (int*)p; p += (size_t)GG * 4;
  int* ctr2    = (int*)out;  // safe: out first written by k_root2_mfma (after k_perm2)

  hipMemsetAsync(hist2, 0, (size_t)NN * RR * 4, stream);
  hipMemsetAsync(hist1, 0, 128, stream);

  hipLaunchKernelGGL(k_basis, dim3(256), dim3(256), 0, stream, comp, bases, Wt);
  hipLaunchKernelGGL(k_wcvt, dim3(80), dim3(256), 0, stream, w1_root, w1_rel, w2, wcat, w2t);
  hipLaunchKernelGGL(k_proj_mfma, dim3(NGROUP), dim3(256), 0, stream, x, wcat, b1, h, xw_bf);
  hipLaunchKernelGGL(k_hists, dim3(512), dim3(256), 0, stream, ei, etype, hist1, hist2);
  hipLaunchKernelGGL(k_scan1, dim3(1), dim3(64), 0, stream, hist1, offs, ctr1);
  hipLaunchKernelGGL(k_perm1, dim3((NE + 255) / 256), dim3(256), 0, stream, etype, ctr1, perm1);
  hipLaunchKernelGGL(k_scanA, dim3(NGROUP), dim3(256), 0, stream, hist2, bsum);
  hipLaunchKernelGGL(k_scanB, dim3(1), dim3(256), 0, stream, bsum);
  hipLaunchKernelGGL(k_scanC, dim3(NGROUP), dim3(256), 0, stream, hist2, bsum, rowptr2, ctr2);
  hipLaunchKernelGGL(k_perm2, dim3((NE + 255) / 256), dim3(256), 0, stream,
                     perm1, ei, etype, enorm, ctr2, pos2, es, en);
  hipLaunchKernelGGL(k_gconv_seg, dim3(NN / 4), dim3(256), 0, stream,
                     rowptr2, es, en, xw_bf, h, h_bf);
  hipLaunchKernelGGL(k_root2_mfma, dim3((NGROUP + 3) / 4), dim3(256), 0, stream,
                     h_bf, w2t, b2, out);
  hipLaunchKernelGGL(k_rgcn_y, dim3(RR, 128), dim3(256), 0, stream,
                     perm1, ei, offs, pos2, h_bf, Wt, hist2, y_bf);
  hipLaunchKernelGGL(k_ysum, dim3(NN / 4), dim3(256), 0, stream, rowptr2, y_bf, out);
  hipLaunchKernelGGL(k_bounds, dim3(1), dim3(256), 0, stream, seq, bounds);
  hipLaunchKernelGGL(k_head, dim3(GG), dim3(256), 0, stream, x, out, bounds,
                     lin_w, lin_b, fc_w, fc_b, dout);
}

// Round 7
// 391.469 us; speedup vs baseline: 1.5257x; 1.0733x over previous
//
#include <hip/hip_runtime.h>
#include <hip/hip_bf16.h>

#define NN 100000   // nodes
#define NE 500000   // edges
#define FD 128      // input features
#define HD 64       // hidden
#define RR 16       // relations
#define NBASE 30    // bases
#define GG 1000     // graphs
#define CC 10       // classes
#define NGROUP 6250 // NN/16

typedef __attribute__((ext_vector_type(8))) short bf16x8;
typedef __attribute__((ext_vector_type(4))) float f32x4;

__device__ inline unsigned short f2b(float x) {
  __hip_bfloat16 b = __float2bfloat16(x);
  return *reinterpret_cast<unsigned short*>(&b);
}
__device__ inline float b2f(unsigned short u) {
  return __uint_as_float(((unsigned)u) << 16);
}

// ---------------- Wt[r][n][k] = sum_b comp[r,b]*bases[b][k][n] (bf16, B-layout) ----------------
__global__ void k_basis(const float* comp, const float* bases, unsigned short* Wt) {
  int idx = blockIdx.x * 256 + threadIdx.x;  // r*4096 + k*64 + n
  int r = idx >> 12, kj = idx & 4095;
  int k = kj >> 6, n = kj & 63;
  float acc = 0.0f;
  for (int b = 0; b < NBASE; ++b)
    acc += comp[r * NBASE + b] * bases[b * 4096 + kj];
  Wt[(r << 12) + n * 64 + k] = f2b(acc);
}

// ---------------- weight conversions ----------------
__global__ void k_wcvt(const float* w_root, const float* w_rel, const float* w2,
                       unsigned short* wcat, unsigned short* w2t) {
  int idx = blockIdx.x * 256 + threadIdx.x;
  if (idx < 16384) {
    int n = idx >> 7, k = idx & 127;
    float v = (n < 64) ? w_root[k * 64 + n] : w_rel[k * 64 + (n - 64)];
    wcat[n * 128 + k] = f2b(v);
  } else if (idx < 16384 + 4096) {
    int i2 = idx - 16384;
    int n = i2 >> 6, k = i2 & 63;
    w2t[n * 64 + k] = f2b(w2[k * 64 + n]);
  }
}

// ---------------- hroot_bf = bf16(x@w_root + b1) ; xw_bf = bf16(x@w_rel)  (MFMA, K-split) ----------------
__global__ __launch_bounds__(256) void k_proj_mfma(const float* x, const unsigned short* wcat,
                                                   const float* b1, unsigned short* hroot_bf,
                                                   unsigned short* xw_bf) {
  __shared__ float red[4][64][33];
  __shared__ float ldsH[16][68];
  __shared__ unsigned short ldsX[16][72];
  int wv = threadIdx.x >> 6, l = threadIdx.x & 63, m = l & 15, q = l >> 4;
  int n0 = blockIdx.x * 16;
  const float* xr = x + (size_t)(n0 + m) * FD + wv * 32 + q * 8;
  float4 xa = *reinterpret_cast<const float4*>(xr);
  float4 xb = *reinterpret_cast<const float4*>(xr + 4);
  bf16x8 a;
  a[0] = (short)f2b(xa.x); a[1] = (short)f2b(xa.y);
  a[2] = (short)f2b(xa.z); a[3] = (short)f2b(xa.w);
  a[4] = (short)f2b(xb.x); a[5] = (short)f2b(xb.y);
  a[6] = (short)f2b(xb.z); a[7] = (short)f2b(xb.w);
  f32x4 zero = {0.0f, 0.0f, 0.0f, 0.0f};
#pragma unroll
  for (int nt = 0; nt < 8; ++nt) {
    bf16x8 b = *reinterpret_cast<const bf16x8*>(wcat + (nt * 16 + m) * 128 + wv * 32 + q * 8);
    f32x4 acc = __builtin_amdgcn_mfma_f32_16x16x32_bf16(a, b, zero, 0, 0, 0);
#pragma unroll
    for (int i = 0; i < 4; ++i) red[wv][l][nt * 4 + i] = acc[i];
  }
  __syncthreads();
#pragma unroll
  for (int t2 = 0; t2 < 2; ++t2) {
    int nt = wv * 2 + t2;
    float s0 = 0, s1 = 0, s2 = 0, s3 = 0;
#pragma unroll
    for (int w = 0; w < 4; ++w) {
      s0 += red[w][l][nt * 4 + 0];
      s1 += red[w][l][nt * 4 + 1];
      s2 += red[w][l][nt * 4 + 2];
      s3 += red[w][l][nt * 4 + 3];
    }
    if (nt < 4) {
      float bb = b1[nt * 16 + m];
      ldsH[q * 4 + 0][nt * 16 + m] = s0 + bb;
      ldsH[q * 4 + 1][nt * 16 + m] = s1 + bb;
      ldsH[q * 4 + 2][nt * 16 + m] = s2 + bb;
      ldsH[q * 4 + 3][nt * 16 + m] = s3 + bb;
    } else {
      int cc = (nt - 4) * 16 + m;
      ldsX[q * 4 + 0][cc] = f2b(s0);
      ldsX[q * 4 + 1][cc] = f2b(s1);
      ldsX[q * 4 + 2][cc] = f2b(s2);
      ldsX[q * 4 + 3][cc] = f2b(s3);
    }
  }
  __syncthreads();
  int t = threadIdx.x;
  {  // hroot_bf: 16 rows x 128B, 256 threads x 8B
    int row = t >> 4, c4 = (t & 15) * 4;
    ushort4 o;
    o.x = f2b(ldsH[row][c4 + 0]);
    o.y = f2b(ldsH[row][c4 + 1]);
    o.z = f2b(ldsH[row][c4 + 2]);
    o.w = f2b(ldsH[row][c4 + 3]);
    *reinterpret_cast<ushort4*>(&hroot_bf[(size_t)(n0 + row) * 64 + c4]) = o;
  }
  if (t < 128) {  // xw_bf: 16 rows x 128B, 128 threads x 16B
    int row = t >> 3, c8 = (t & 7) * 8;
    uint4 v = *reinterpret_cast<const uint4*>(&ldsX[row][c8]);
    *reinterpret_cast<uint4*>(&xw_bf[(size_t)(n0 + row) * 64 + c8]) = v;
  }
}

// ---------------- histograms ----------------
__global__ void k_hists(const int* ei, const int* etype, int* hist1, int* hist2) {
  __shared__ int lh[RR];
  if (threadIdx.x < RR) lh[threadIdx.x] = 0;
  __syncthreads();
  for (int e = blockIdx.x * 256 + threadIdx.x; e < NE; e += gridDim.x * 256) {
    int t = etype[e];
    atomicAdd(&lh[t], 1);
    atomicAdd(&hist2[ei[NE + e] * RR + t], 1);
  }
  __syncthreads();
  if (threadIdx.x < RR) atomicAdd(&hist1[threadIdx.x], lh[threadIdx.x]);
}

__global__ void k_scan1(const int* hist1, int* offs, int* ctr1) {
  if (threadIdx.x == 0) {
    int s = 0;
    for (int r = 0; r < RR; ++r) { offs[r] = s; ctr1[r] = s; s += hist1[r]; }
    offs[RR] = s;
  }
}

__global__ void k_perm1(const int* etype, int* ctr1, int* perm1) {
  __shared__ int lcnt[RR], lbase[RR];
  if (threadIdx.x < RR) lcnt[threadIdx.x] = 0;
  __syncthreads();
  int e = blockIdx.x * 256 + threadIdx.x;
  int t = 0, rank = 0;
  bool valid = e < NE;
  if (valid) { t = etype[e]; rank = atomicAdd(&lcnt[t], 1); }
  __syncthreads();
  if (threadIdx.x < RR) {
    int n = lcnt[threadIdx.x];
    lbase[threadIdx.x] = n ? atomicAdd(&ctr1[threadIdx.x], n) : 0;
  }
  __syncthreads();
  if (valid) perm1[lbase[t] + rank] = e;
}

// ---------------- hierarchical scan of hist2 ----------------
__device__ inline int block_scan_incl(int v, int* ps, int t) {
  ps[t] = v;
  __syncthreads();
  for (int off = 1; off < 256; off <<= 1) {
    int u = (t >= off) ? ps[t - off] : 0;
    __syncthreads();
    ps[t] += u;
    __syncthreads();
  }
  return ps[t];
}

__global__ void k_scanA(const int* hist2, int* bsum) {
  __shared__ int red[256];
  int t = threadIdx.x;
  red[t] = hist2[blockIdx.x * 256 + t];
  __syncthreads();
  for (int s = 128; s; s >>= 1) {
    if (t < s) red[t] += red[t + s];
    __syncthreads();
  }
  if (t == 0) bsum[blockIdx.x] = red[0];
}

__global__ void k_scanB(int* bsum) {
  int t = threadIdx.x;
  int loc[25];
  int s = 0;
  if (t < 250) {
    for (int i = 0; i < 25; ++i) { loc[i] = bsum[t * 25 + i]; s += loc[i]; }
  }
  __shared__ int ps[256];
  int incl = block_scan_incl(s, ps, t);
  int base = incl - s;
  if (t < 250) {
    int run = base;
    for (int i = 0; i < 25; ++i) { int tmp = loc[i]; bsum[t * 25 + i] = run; run += tmp; }
  }
}

__global__ void k_scanC(const int* hist2, const int* bsum, int* rowptr2, int* ctr2) {
  int t = threadIdx.x;
  int gid = blockIdx.x * 256 + t;
  int v = hist2[gid];
  __shared__ int ps[256];
  int incl = block_scan_incl(v, ps, t);
  int ex = bsum[blockIdx.x] + incl - v;
  rowptr2[gid] = ex;
  ctr2[gid] = ex;
}

// ---------------- dst-sort scatter ----------------
__global__ void k_perm2(const int* perm1, const int* ei, const int* etype, const float* enorm,
                        int* ctr2, int* pos2, int* es, float* en) {
  int p = blockIdx.x * 256 + threadIdx.x;
  if (p >= NE) return;
  int e = perm1[p];
  int key = ei[NE + e] * RR + etype[e];
  int pos = atomicAdd(&ctr2[key], 1);
  pos2[p] = pos;
  es[pos] = ei[e];
  en[pos] = enorm[e];
}

// ---------------- GraphConv segment-sum: 4 edges/iter, uint2 loads ----------------
__global__ __launch_bounds__(256) void k_gconv_seg(const int* rowptr2, const int* es,
    const float* en, const unsigned short* xw_bf, const unsigned short* hroot_bf,
    unsigned short* h_bf) {
  int wv = threadIdx.x >> 6, l = threadIdx.x & 63;
  int c4 = l & 15, eq = l >> 4;
  int dst = blockIdx.x * 4 + wv;
  int lo = rowptr2[dst * RR];
  int hi = (dst == NN - 1) ? NE : rowptr2[(dst + 1) * RR];
  float4 acc = {0.0f, 0.0f, 0.0f, 0.0f};
  for (int base0 = lo; base0 < hi; base0 += 64) {
    int n = min(64, hi - base0);
    int sv = 0;
    float nv = 0.0f;
    if (l < n) { sv = es[base0 + l]; nv = en[base0 + l]; }
    int k4max = (n + 3) >> 2;
    for (int k4 = 0; k4 < k4max; ++k4) {
      int eid = k4 * 4 + eq;
      int s = __shfl(sv, eid);
      float w = __shfl(nv, eid);
      if (eid < n) {
        uint2 v = *reinterpret_cast<const uint2*>(xw_bf + (size_t)s * 64 + c4 * 4);
        acc.x += b2f((unsigned short)(v.x & 0xffffu)) * w;
        acc.y += b2f((unsigned short)(v.x >> 16)) * w;
        acc.z += b2f((unsigned short)(v.y & 0xffffu)) * w;
        acc.w += b2f((unsigned short)(v.y >> 16)) * w;
      }
    }
  }
  // combine 4 edge-slot partials
  acc.x += __shfl_xor(acc.x, 16); acc.y += __shfl_xor(acc.y, 16);
  acc.z += __shfl_xor(acc.z, 16); acc.w += __shfl_xor(acc.w, 16);
  acc.x += __shfl_xor(acc.x, 32); acc.y += __shfl_xor(acc.y, 32);
  acc.z += __shfl_xor(acc.z, 32); acc.w += __shfl_xor(acc.w, 32);
  if (l < 16) {
    uint2 hb = *reinterpret_cast<const uint2*>(hroot_bf + (size_t)dst * 64 + l * 4);
    acc.x += b2f((unsigned short)(hb.x & 0xffffu));
    acc.y += b2f((unsigned short)(hb.x >> 16));
    acc.z += b2f((unsigned short)(hb.y & 0xffffu));
    acc.w += b2f((unsigned short)(hb.y >> 16));
    ushort4 o;
    o.x = f2b(acc.x); o.y = f2b(acc.y); o.z = f2b(acc.z); o.w = f2b(acc.w);
    *reinterpret_cast<ushort4*>(h_bf + (size_t)dst * 64 + l * 4) = o;
  }
}

// ---------------- out = h_bf @ w2t + b2  (MFMA) ----------------
__global__ __launch_bounds__(256) void k_root2_mfma(const unsigned short* h_bf,
    const unsigned short* w2t, const float* b2, float* out) {
  int wv = threadIdx.x >> 6, l = threadIdx.x & 63, m = l & 15, q = l >> 4;
  int g = blockIdx.x * 4 + wv;
  if (g >= NGROUP) return;
  int n0 = g * 16;
  f32x4 acc[4];
#pragma unroll
  for (int nt = 0; nt < 4; ++nt) acc[nt] = (f32x4){0, 0, 0, 0};
#pragma unroll
  for (int s = 0; s < 2; ++s) {
    bf16x8 a = *reinterpret_cast<const bf16x8*>(h_bf + (size_t)(n0 + m) * 64 + s * 32 + q * 8);
#pragma unroll
    for (int nt = 0; nt < 4; ++nt) {
      bf16x8 b = *reinterpret_cast<const bf16x8*>(w2t + (nt * 16 + m) * 64 + s * 32 + q * 8);
      acc[nt] = __builtin_amdgcn_mfma_f32_16x16x32_bf16(a, b, acc[nt], 0, 0, 0);
    }
  }
  float b2v[4];
#pragma unroll
  for (int nt = 0; nt < 4; ++nt) b2v[nt] = b2[nt * 16 + m];
#pragma unroll
  for (int i = 0; i < 4; ++i) {
    size_t row = n0 + q * 4 + i;
#pragma unroll
    for (int nt = 0; nt < 4; ++nt)
      out[row * 64 + nt * 16 + m] = acc[nt][i] + b2v[nt];
  }
}

// ---------------- RGCN via MFMA; y rows written at dst-ordered slots ----------------
__global__ __launch_bounds__(256) void k_rgcn_y(const int* perm1, const int* ei,
    const int* offs, const int* pos2, const unsigned short* h_bf, const unsigned short* Wt,
    const int* hist2, unsigned short* y_bf) {
  int r = blockIdx.x;
  int lo = offs[r], hi = offs[r + 1];
  int cnt = hi - lo;
  int wv = threadIdx.x >> 6;
  int l = threadIdx.x & 63;
  int m = l & 15, q = l >> 4;
  int ngroups = (cnt + 15) / 16;
  const unsigned short* Wr = Wt + (r << 12);
  bf16x8 bfr[2][4];
#pragma unroll
  for (int s = 0; s < 2; ++s)
#pragma unroll
    for (int nt = 0; nt < 4; ++nt)
      bfr[s][nt] = *reinterpret_cast<const bf16x8*>(Wr + (nt * 16 + m) * 64 + s * 32 + q * 8);

  for (int g = blockIdx.y * 4 + wv; g < ngroups; g += gridDim.y * 4) {
    int base = lo + g * 16;
    int ne = min(16, hi - base);
    int p = base + ((m < ne) ? m : 0);
    int ed = perm1[p];
    int src = ei[ed];
    int dst = ei[NE + ed];
    int pos = pos2[p];
    float inv = 1.0f / (float)max(hist2[dst * RR + r], 1);
    f32x4 acc[4];
#pragma unroll
    for (int nt = 0; nt < 4; ++nt) acc[nt] = (f32x4){0, 0, 0, 0};
    const unsigned short* hrow = h_bf + (size_t)src * 64 + q * 8;
#pragma unroll
    for (int s = 0; s < 2; ++s) {
      bf16x8 afr = *reinterpret_cast<const bf16x8*>(hrow + s * 32);
#pragma unroll
      for (int nt = 0; nt < 4; ++nt)
        acc[nt] = __builtin_amdgcn_mfma_f32_16x16x32_bf16(afr, bfr[s][nt], acc[nt], 0, 0, 0);
    }
#pragma unroll
    for (int i = 0; i < 4; ++i) {
      int row = q * 4 + i;
      float ir = __shfl(inv, row);
      int pr = __shfl(pos, row);
      if (row < ne) {
#pragma unroll
        for (int nt = 0; nt < 4; ++nt)
          y_bf[(size_t)pr * 64 + nt * 16 + m] = f2b(acc[nt][i] * ir);
      }
    }
  }
}

// ---------------- per-dst y-row streaming sum: 4 rows/iter, uint2 loads ----------------
__global__ __launch_bounds__(256) void k_ysum(const int* rowptr2, const unsigned short* y_bf,
                                              float* out) {
  int wv = threadIdx.x >> 6, l = threadIdx.x & 63;
  int c4 = l & 15, eq = l >> 4;
  int dst = blockIdx.x * 4 + wv;
  int lo = rowptr2[dst * RR];
  int hi = (dst == NN - 1) ? NE : rowptr2[(dst + 1) * RR];
  float4 acc = {0.0f, 0.0f, 0.0f, 0.0f};
  for (int row = lo + eq; row < hi; row += 4) {
    uint2 v = *reinterpret_cast<const uint2*>(y_bf + (size_t)row * 64 + c4 * 4);
    acc.x += b2f((unsigned short)(v.x & 0xffffu));
    acc.y += b2f((unsigned short)(v.x >> 16));
    acc.z += b2f((unsigned short)(v.y & 0xffffu));
    acc.w += b2f((unsigned short)(v.y >> 16));
  }
  acc.x += __shfl_xor(acc.x, 16); acc.y += __shfl_xor(acc.y, 16);
  acc.z += __shfl_xor(acc.z, 16); acc.w += __shfl_xor(acc.w, 16);
  acc.x += __shfl_xor(acc.x, 32); acc.y += __shfl_xor(acc.y, 32);
  acc.z += __shfl_xor(acc.z, 32); acc.w += __shfl_xor(acc.w, 32);
  if (l < 16) {
    float4* op = reinterpret_cast<float4*>(out + (size_t)dst * 64 + l * 4);
    float4 o = *op;
    o.x += acc.x; o.y += acc.y; o.z += acc.z; o.w += acc.w;
    *op = o;
  }
}

// ---------------- graph bounds ----------------
__global__ void k_bounds(const int* seq, int* bounds) {
  __shared__ int s[GG];
  for (int i = threadIdx.x; i < GG; i += 256) s[i] = seq[i];
  __syncthreads();
  if (threadIdx.x == 0) {
    int acc = 0;
    for (int g = 0; g < GG; ++g) { acc += s[g]; bounds[g] = acc; }
  }
}

// ---------------- fused pool + MLP head + log_softmax ----------------
__global__ __launch_bounds__(256) void k_head(const float* x, const float* outn,
    const int* bounds, const float* lin_w, const float* lin_b,
    const float* fc_w, const float* fc_b, float* dout) {
  __shared__ float4 psum[5][48], pmax[5][48];
  __shared__ float gsum[192], gmax[192];
  __shared__ float part[4][64];
  __shared__ float hid[HD], lg[CC], mred[2];
  int g = blockIdx.x, t = threadIdx.x;
  int lo = (g == 0) ? 0 : bounds[g - 1];
  int hi = bounds[g];
  int nn = hi - lo;
  if (t < 240) {
    int c4 = t % 48, ch = t / 48;
    int a = lo + (nn * ch) / 5, b = lo + (nn * (ch + 1)) / 5;
    float4 s = {0, 0, 0, 0};
    float4 mx = {-3.4e38f, -3.4e38f, -3.4e38f, -3.4e38f};
    const float* bp;
    int stride;
    if (c4 < 32) { bp = x + (size_t)a * FD + c4 * 4; stride = FD; }
    else         { bp = outn + (size_t)a * 64 + (c4 - 32) * 4; stride = 64; }
    int n = a;
    for (; n + 4 <= b; n += 4) {
      float4 v0 = *reinterpret_cast<const float4*>(bp);
      float4 v1 = *reinterpret_cast<const float4*>(bp + stride);
      float4 v2 = *reinterpret_cast<const float4*>(bp + 2 * stride);
      float4 v3 = *reinterpret_cast<const float4*>(bp + 3 * stride);
      bp += 4 * stride;
      s.x += v0.x + v1.x + v2.x + v3.x;
      s.y += v0.y + v1.y + v2.y + v3.y;
      s.z += v0.z + v1.z + v2.z + v3.z;
      s.w += v0.w + v1.w + v2.w + v3.w;
      mx.x = fmaxf(fmaxf(fmaxf(mx.x, v0.x), fmaxf(v1.x, v2.x)), v3.x);
      mx.y = fmaxf(fmaxf(fmaxf(mx.y, v0.y), fmaxf(v1.y, v2.y)), v3.y);
      mx.z = fmaxf(fmaxf(fmaxf(mx.z, v0.z), fmaxf(v1.z, v2.z)), v3.z);
      mx.w = fmaxf(fmaxf(fmaxf(mx.w, v0.w), fmaxf(v1.w, v2.w)), v3.w);
    }
    for (; n < b; ++n) {
      float4 v = *reinterpret_cast<const float4*>(bp);
      bp += stride;
      s.x += v.x; s.y += v.y; s.z += v.z; s.w += v.w;
      mx.x = fmaxf(mx.x, v.x); mx.y = fmaxf(mx.y, v.y);
      mx.z = fmaxf(mx.z, v.z); mx.w = fmaxf(mx.w, v.w);
    }
    psum[ch][c4] = s;
    pmax[ch][c4] = mx;
  }
  __syncthreads();
  if (t < 48) {
    float4 s = psum[0][t], m = pmax[0][t];
#pragma unroll
    for (int ch = 1; ch < 5; ++ch) {
      float4 ps = psum[ch][t], pm = pmax[ch][t];
      s.x += ps.x; s.y += ps.y; s.z += ps.z; s.w += ps.w;
      m.x = fmaxf(m.x, pm.x); m.y = fmaxf(m.y, pm.y);
      m.z = fmaxf(m.z, pm.z); m.w = fmaxf(m.w, pm.w);
    }
    gsum[t * 4 + 0] = s.x; gsum[t * 4 + 1] = s.y;
    gsum[t * 4 + 2] = s.z; gsum[t * 4 + 3] = s.w;
    gmax[t * 4 + 0] = m.x; gmax[t * 4 + 1] = m.y;
    gmax[t * 4 + 2] = m.z; gmax[t * 4 + 3] = m.w;
  }
  __syncthreads();
  {
    int o = t & 63, pp = t >> 6;
    float a = 0.0f;
    int k0 = pp * 96;
    for (int k = k0; k < k0 + 96; ++k) {
      float gv = (k < 192) ? gsum[k] : gmax[k - 192];
      a += gv * lin_w[k * 64 + o];
    }
    part[pp][o] = a;
  }
  __syncthreads();
  if (t < HD) {
    float a = lin_b[t] + part[0][t] + part[1][t] + part[2][t] + part[3][t];
    hid[t] = fmaxf(a, 0.0f);
  }
  __syncthreads();
  if (t < CC) {
    float a = fc_b[t];
    for (int k = 0; k < HD; ++k) a += hid[k] * fc_w[k * CC + t];
    lg[t] = a;
  }
  __syncthreads();
  if (t == 0) {
    float mm = lg[0];
#pragma unroll
    for (int i = 1; i < CC; ++i) mm = fmaxf(mm, lg[i]);
    float se = 0.0f;
#pragma unroll
    for (int i = 0; i < CC; ++i) se += __expf(lg[i] - mm);
    mred[0] = mm;
    mred[1] = __logf(se);
  }
  __syncthreads();
  if (t < CC) dout[g * CC + t] = lg[t] - mred[0] - mred[1];
}

extern "C" void kernel_launch(void* const* d_in, const int* in_sizes, int n_in,
                              void* d_out, int out_size, void* d_ws, size_t ws_size,
                              hipStream_t stream) {
  const float* x     = (const float*)d_in[0];
  const int* ei      = (const int*)d_in[1];
  const float* enorm = (const float*)d_in[2];
  const int* etype   = (const int*)d_in[3];
  const int* seq     = (const int*)d_in[4];
  const float* w1_rel  = (const float*)d_in[6];
  const float* w1_root = (const float*)d_in[7];
  const float* b1      = (const float*)d_in[8];
  const float* bases   = (const float*)d_in[9];
  const float* comp    = (const float*)d_in[10];
  const float* w2      = (const float*)d_in[11];
  const float* b2      = (const float*)d_in[12];
  const float* lin_w   = (const float*)d_in[13];
  const float* lin_b   = (const float*)d_in[14];
  const float* fc_w    = (const float*)d_in[15];
  const float* fc_b    = (const float*)d_in[16];
  float* dout = (float*)d_out;

  char* p = (char*)d_ws;
  unsigned short* hroot_bf = (unsigned short*)p; p += (size_t)NN * 64 * 2;  // 12.8 MB
  unsigned short* xw_bf    = (unsigned short*)p; p += (size_t)NN * 64 * 2;  // 12.8 MB
  float* out  = (float*)p;  p += (size_t)NN * 64 * 4;                       // 25.6 MB (ctr2 alias)
  unsigned short* y_bf = (unsigned short*)p; p += (size_t)NE * 64 * 2;      // 64 MB
  unsigned short* h_bf = (unsigned short*)p; p += (size_t)NN * 64 * 2;      // 12.8 MB
  unsigned short* Wt   = (unsigned short*)p; p += (size_t)RR * 4096 * 2;
  unsigned short* wcat = (unsigned short*)p; p += (size_t)128 * 128 * 2;
  unsigned short* w2t  = (unsigned short*)p; p += (size_t)64 * 64 * 2;
  int* perm1   = (int*)p; p += (size_t)NE * 4;
  int* pos2    = (int*)p; p += (size_t)NE * 4;
  int* es      = (int*)p; p += (size_t)NE * 4;
  float* en    = (float*)p; p += (size_t)NE * 4;
  int* hist2   = (int*)p; p += (size_t)NN * RR * 4;
  int* rowptr2 = (int*)p; p += (size_t)NN * RR * 4;
  int* bsum    = (int*)p; p += (size_t)NGROUP * 4;
  int* hist1   = (int*)p; p += 64;
  int* ctr1    = (int*)p; p += 64;
  int* offs    = (int*)p; p += 68;
  int* bounds  = (int*)p; p += (size_t)GG * 4;
  int* ctr2    = (int*)out;  // safe: out first written by k_root2_mfma (after k_perm2)

  hipMemsetAsync(hist2, 0, (size_t)NN * RR * 4, stream);
  hipMemsetAsync(hist1, 0, 128, stream);

  hipLaunchKernelGGL(k_basis, dim3(256), dim3(256), 0, stream, comp, bases, Wt);
  hipLaunchKernelGGL(k_wcvt, dim3(80), dim3(256), 0, stream, w1_root, w1_rel, w2, wcat, w2t);
  hipLaunchKernelGGL(k_proj_mfma, dim3(NGROUP), dim3(256), 0, stream, x, wcat, b1,
                     hroot_bf, xw_bf);
  hipLaunchKernelGGL(k_hists, dim3(512), dim3(256), 0, stream, ei, etype, hist1, hist2);
  hipLaunchKernelGGL(k_scan1, dim3(1), dim3(64), 0, stream, hist1, offs, ctr1);
  hipLaunchKernelGGL(k_perm1, dim3((NE + 255) / 256), dim3(256), 0, stream, etype, ctr1, perm1);
  hipLaunchKernelGGL(k_scanA, dim3(NGROUP), dim3(256), 0, stream, hist2, bsum);
  hipLaunchKernelGGL(k_scanB, dim3(1), dim3(256), 0, stream, bsum);
  hipLaunchKernelGGL(k_scanC, dim3(NGROUP), dim3(256), 0, stream, hist2, bsum, rowptr2, ctr2);
  hipLaunchKernelGGL(k_perm2, dim3((NE + 255) / 256), dim3(256), 0, stream,
                     perm1, ei, etype, enorm, ctr2, pos2, es, en);
  hipLaunchKernelGGL(k_gconv_seg, dim3(NN / 4), dim3(256), 0, stream,
                     rowptr2, es, en, xw_bf, hroot_bf, h_bf);
  hipLaunchKernelGGL(k_root2_mfma, dim3((NGROUP + 3) / 4), dim3(256), 0, stream,
                     h_bf, w2t, b2, out);
  hipLaunchKernelGGL(k_rgcn_y, dim3(RR, 128), dim3(256), 0, stream,
                     perm1, ei, offs, pos2, h_bf, Wt, hist2, y_bf);
  hipLaunchKernelGGL(k_ysum, dim3(NN / 4), dim3(256), 0, stream, rowptr2, y_bf, out);
  hipLaunchKernelGGL(k_bounds, dim3(1), dim3(256), 0, stream, seq, bounds);
  hipLaunchKernelGGL(k_head, dim3(GG), dim3(256), 0, stream, x, out, bounds,
                     lin_w, lin_b, fc_w, fc_b, dout);
}

// Round 8
// 384.782 us; speedup vs baseline: 1.5522x; 1.0174x over previous
//
#include <hip/hip_runtime.h>
#include <hip/hip_bf16.h>

#define NN 100000   // nodes
#define NE 500000   // edges
#define FD 128      // input features
#define HD 64       // hidden
#define RR 16       // relations
#define NBASE 30    // bases
#define GG 1000     // graphs
#define CC 10       // classes
#define NGROUP 6250 // NN/16

typedef __attribute__((ext_vector_type(8))) short bf16x8;
typedef __attribute__((ext_vector_type(4))) float f32x4;

__device__ inline unsigned short f2b(float x) {
  __hip_bfloat16 b = __float2bfloat16(x);
  return *reinterpret_cast<unsigned short*>(&b);
}
__device__ inline float b2f(unsigned short u) {
  return __uint_as_float(((unsigned)u) << 16);
}

// ---------------- Wt[r][n][k] = sum_b comp[r,b]*bases[b][k][n] (bf16, B-layout) ----------------
__global__ void k_basis(const float* comp, const float* bases, unsigned short* Wt) {
  int idx = blockIdx.x * 256 + threadIdx.x;  // r*4096 + k*64 + n
  int r = idx >> 12, kj = idx & 4095;
  int k = kj >> 6, n = kj & 63;
  float acc = 0.0f;
  for (int b = 0; b < NBASE; ++b)
    acc += comp[r * NBASE + b] * bases[b * 4096 + kj];
  Wt[(r << 12) + n * 64 + k] = f2b(acc);
}

// ---------------- weight conversions ----------------
__global__ void k_wcvt(const float* w_root, const float* w_rel, const float* w2,
                       unsigned short* wcat, unsigned short* w2t) {
  int idx = blockIdx.x * 256 + threadIdx.x;
  if (idx < 16384) {
    int n = idx >> 7, k = idx & 127;
    float v = (n < 64) ? w_root[k * 64 + n] : w_rel[k * 64 + (n - 64)];
    wcat[n * 128 + k] = f2b(v);
  } else if (idx < 16384 + 4096) {
    int i2 = idx - 16384;
    int n = i2 >> 6, k = i2 & 63;
    w2t[n * 64 + k] = f2b(w2[k * 64 + n]);
  }
}

// ---------------- hroot_bf = bf16(x@w_root + b1) ; xw_bf = bf16(x@w_rel) ----------------
// One wave = 16 nodes, full-K accumulation (32 MFMAs); per-wave LDS repack -> uint4 stores.
__global__ __launch_bounds__(256) void k_proj_mfma(const float* x, const unsigned short* wcat,
                                                   const float* b1, unsigned short* hroot_bf,
                                                   unsigned short* xw_bf) {
  __shared__ unsigned short ldsO[4][16][72];   // per-wave staging, 72: 16B-aligned rows
  int wv = threadIdx.x >> 6, l = threadIdx.x & 63, m = l & 15, q = l >> 4;
  int g = blockIdx.x * 4 + wv;
  bool act = g < NGROUP;
  size_t n0 = (size_t)g * 16;
  f32x4 acc[8];
#pragma unroll
  for (int nt = 0; nt < 8; ++nt) acc[nt] = (f32x4){0, 0, 0, 0};
  if (act) {
#pragma unroll
    for (int s = 0; s < 4; ++s) {
      const float* xr = x + (n0 + m) * FD + s * 32 + q * 8;
      float4 xa = *reinterpret_cast<const float4*>(xr);
      float4 xb = *reinterpret_cast<const float4*>(xr + 4);
      bf16x8 a;
      a[0] = (short)f2b(xa.x); a[1] = (short)f2b(xa.y);
      a[2] = (short)f2b(xa.z); a[3] = (short)f2b(xa.w);
      a[4] = (short)f2b(xb.x); a[5] = (short)f2b(xb.y);
      a[6] = (short)f2b(xb.z); a[7] = (short)f2b(xb.w);
#pragma unroll
      for (int nt = 0; nt < 8; ++nt) {
        bf16x8 b = *reinterpret_cast<const bf16x8*>(wcat + (nt * 16 + m) * 128 + s * 32 + q * 8);
        acc[nt] = __builtin_amdgcn_mfma_f32_16x16x32_bf16(a, b, acc[nt], 0, 0, 0);
      }
    }
  }
  float b1v[4];
#pragma unroll
  for (int nt = 0; nt < 4; ++nt) b1v[nt] = b1[nt * 16 + m];
  // stage + store h (tiles 0..3, +bias), then xw (tiles 4..7)
#pragma unroll
  for (int half = 0; half < 2; ++half) {
#pragma unroll
    for (int nt = 0; nt < 4; ++nt)
#pragma unroll
      for (int i = 0; i < 4; ++i) {
        float v = acc[half * 4 + nt][i] + (half == 0 ? b1v[nt] : 0.0f);
        ldsO[wv][q * 4 + i][nt * 16 + m] = f2b(v);
      }
    __syncthreads();
    unsigned short* dstbuf = half == 0 ? hroot_bf : xw_bf;
#pragma unroll
    for (int h2 = 0; h2 < 2; ++h2) {
      int row = h2 * 8 + (l >> 3), ch = l & 7;
      uint4 v = *reinterpret_cast<const uint4*>(&ldsO[wv][row][ch * 8]);
      if (act)
        *reinterpret_cast<uint4*>(&dstbuf[(n0 + row) * 64 + ch * 8]) = v;
    }
    __syncthreads();
  }
}

// ---------------- histograms ----------------
__global__ void k_hists(const int* ei, const int* etype, int* hist1, int* hist2) {
  __shared__ int lh[RR];
  if (threadIdx.x < RR) lh[threadIdx.x] = 0;
  __syncthreads();
  for (int e = blockIdx.x * 256 + threadIdx.x; e < NE; e += gridDim.x * 256) {
    int t = etype[e];
    atomicAdd(&lh[t], 1);
    atomicAdd(&hist2[ei[NE + e] * RR + t], 1);
  }
  __syncthreads();
  if (threadIdx.x < RR) atomicAdd(&hist1[threadIdx.x], lh[threadIdx.x]);
}

__global__ void k_scan1(const int* hist1, int* offs, int* ctr1) {
  if (threadIdx.x == 0) {
    int s = 0;
    for (int r = 0; r < RR; ++r) { offs[r] = s; ctr1[r] = s; s += hist1[r]; }
    offs[RR] = s;
  }
}

__global__ void k_perm1(const int* etype, int* ctr1, int* perm1) {
  __shared__ int lcnt[RR], lbase[RR];
  if (threadIdx.x < RR) lcnt[threadIdx.x] = 0;
  __syncthreads();
  int e = blockIdx.x * 256 + threadIdx.x;
  int t = 0, rank = 0;
  bool valid = e < NE;
  if (valid) { t = etype[e]; rank = atomicAdd(&lcnt[t], 1); }
  __syncthreads();
  if (threadIdx.x < RR) {
    int n = lcnt[threadIdx.x];
    lbase[threadIdx.x] = n ? atomicAdd(&ctr1[threadIdx.x], n) : 0;
  }
  __syncthreads();
  if (valid) perm1[lbase[t] + rank] = e;
}

// ---------------- hierarchical scan of hist2 ----------------
__device__ inline int block_scan_incl(int v, int* ps, int t) {
  ps[t] = v;
  __syncthreads();
  for (int off = 1; off < 256; off <<= 1) {
    int u = (t >= off) ? ps[t - off] : 0;
    __syncthreads();
    ps[t] += u;
    __syncthreads();
  }
  return ps[t];
}

__global__ void k_scanA(const int* hist2, int* bsum) {
  __shared__ int red[256];
  int t = threadIdx.x;
  red[t] = hist2[blockIdx.x * 256 + t];
  __syncthreads();
  for (int s = 128; s; s >>= 1) {
    if (t < s) red[t] += red[t + s];
    __syncthreads();
  }
  if (t == 0) bsum[blockIdx.x] = red[0];
}

__global__ void k_scanB(int* bsum) {
  int t = threadIdx.x;
  int loc[25];
  int s = 0;
  if (t < 250) {
    for (int i = 0; i < 25; ++i) { loc[i] = bsum[t * 25 + i]; s += loc[i]; }
  }
  __shared__ int ps[256];
  int incl = block_scan_incl(s, ps, t);
  int base = incl - s;
  if (t < 250) {
    int run = base;
    for (int i = 0; i < 25; ++i) { int tmp = loc[i]; bsum[t * 25 + i] = run; run += tmp; }
  }
}

__global__ void k_scanC(const int* hist2, const int* bsum, int* rowptr2, int* ctr2) {
  int t = threadIdx.x;
  int gid = blockIdx.x * 256 + t;
  int v = hist2[gid];
  __shared__ int ps[256];
  int incl = block_scan_incl(v, ps, t);
  int ex = bsum[blockIdx.x] + incl - v;
  rowptr2[gid] = ex;
  ctr2[gid] = ex;
}

// ---------------- dst-sort scatter; also type-ordered src/inv for rgcn ----------------
__global__ void k_perm2(const int* perm1, const int* ei, const int* etype, const float* enorm,
                        const int* hist2, int* ctr2, int* pos2, int* es, float* en,
                        int* ts, float* tinv) {
  int p = blockIdx.x * 256 + threadIdx.x;
  if (p >= NE) return;
  int e = perm1[p];
  int src = ei[e];
  int key = ei[NE + e] * RR + etype[e];
  int pos = atomicAdd(&ctr2[key], 1);
  pos2[p] = pos;
  es[pos] = src;
  en[pos] = enorm[e];
  ts[p] = src;
  tinv[p] = 1.0f / (float)max(hist2[key], 1);
}

// ---------------- GraphConv segment-sum: 4 edges/iter, uint2 loads ----------------
__global__ __launch_bounds__(256) void k_gconv_seg(const int* rowptr2, const int* es,
    const float* en, const unsigned short* xw_bf, const unsigned short* hroot_bf,
    unsigned short* h_bf) {
  int wv = threadIdx.x >> 6, l = threadIdx.x & 63;
  int c4 = l & 15, eq = l >> 4;
  int dst = blockIdx.x * 4 + wv;
  int lo = rowptr2[dst * RR];
  int hi = (dst == NN - 1) ? NE : rowptr2[(dst + 1) * RR];
  float4 acc = {0.0f, 0.0f, 0.0f, 0.0f};
  for (int base0 = lo; base0 < hi; base0 += 64) {
    int n = min(64, hi - base0);
    int sv = 0;
    float nv = 0.0f;
    if (l < n) { sv = es[base0 + l]; nv = en[base0 + l]; }
    int k4max = (n + 3) >> 2;
    for (int k4 = 0; k4 < k4max; ++k4) {
      int eid = k4 * 4 + eq;
      int s = __shfl(sv, eid);
      float w = __shfl(nv, eid);
      if (eid < n) {
        uint2 v = *reinterpret_cast<const uint2*>(xw_bf + (size_t)s * 64 + c4 * 4);
        acc.x += b2f((unsigned short)(v.x & 0xffffu)) * w;
        acc.y += b2f((unsigned short)(v.x >> 16)) * w;
        acc.z += b2f((unsigned short)(v.y & 0xffffu)) * w;
        acc.w += b2f((unsigned short)(v.y >> 16)) * w;
      }
    }
  }
  acc.x += __shfl_xor(acc.x, 16); acc.y += __shfl_xor(acc.y, 16);
  acc.z += __shfl_xor(acc.z, 16); acc.w += __shfl_xor(acc.w, 16);
  acc.x += __shfl_xor(acc.x, 32); acc.y += __shfl_xor(acc.y, 32);
  acc.z += __shfl_xor(acc.z, 32); acc.w += __shfl_xor(acc.w, 32);
  if (l < 16) {
    uint2 hb = *reinterpret_cast<const uint2*>(hroot_bf + (size_t)dst * 64 + l * 4);
    acc.x += b2f((unsigned short)(hb.x & 0xffffu));
    acc.y += b2f((unsigned short)(hb.x >> 16));
    acc.z += b2f((unsigned short)(hb.y & 0xffffu));
    acc.w += b2f((unsigned short)(hb.y >> 16));
    ushort4 o;
    o.x = f2b(acc.x); o.y = f2b(acc.y); o.z = f2b(acc.z); o.w = f2b(acc.w);
    *reinterpret_cast<ushort4*>(h_bf + (size_t)dst * 64 + l * 4) = o;
  }
}

// ---------------- RGCN via MFMA; single-indirection streams; y at dst-ordered slots ----------------
__global__ __launch_bounds__(256) void k_rgcn_y(const int* ts, const float* tinv,
    const int* pos2, const int* offs, const unsigned short* h_bf, const unsigned short* Wt,
    unsigned short* y_bf) {
  int r = blockIdx.x;
  int lo = offs[r], hi = offs[r + 1];
  int cnt = hi - lo;
  int wv = threadIdx.x >> 6;
  int l = threadIdx.x & 63;
  int m = l & 15, q = l >> 4;
  int ngroups = (cnt + 15) / 16;
  const unsigned short* Wr = Wt + (r << 12);
  bf16x8 bfr[2][4];
#pragma unroll
  for (int s = 0; s < 2; ++s)
#pragma unroll
    for (int nt = 0; nt < 4; ++nt)
      bfr[s][nt] = *reinterpret_cast<const bf16x8*>(Wr + (nt * 16 + m) * 64 + s * 32 + q * 8);

  for (int g = blockIdx.y * 4 + wv; g < ngroups; g += gridDim.y * 4) {
    int base = lo + g * 16;
    int ne = min(16, hi - base);
    int p = base + ((m < ne) ? m : 0);
    int src = ts[p];         // coalesced
    int pos = pos2[p];       // coalesced
    float inv = tinv[p];     // coalesced
    f32x4 acc[4];
#pragma unroll
    for (int nt = 0; nt < 4; ++nt) acc[nt] = (f32x4){0, 0, 0, 0};
    const unsigned short* hrow = h_bf + (size_t)src * 64 + q * 8;
#pragma unroll
    for (int s = 0; s < 2; ++s) {
      bf16x8 afr = *reinterpret_cast<const bf16x8*>(hrow + s * 32);
#pragma unroll
      for (int nt = 0; nt < 4; ++nt)
        acc[nt] = __builtin_amdgcn_mfma_f32_16x16x32_bf16(afr, bfr[s][nt], acc[nt], 0, 0, 0);
    }
#pragma unroll
    for (int i = 0; i < 4; ++i) {
      int row = q * 4 + i;
      float ir = __shfl(inv, row);
      int pr = __shfl(pos, row);
      if (row < ne) {
#pragma unroll
        for (int nt = 0; nt < 4; ++nt)
          y_bf[(size_t)pr * 64 + nt * 16 + m] = f2b(acc[nt][i] * ir);
      }
    }
  }
}

// ---------------- fused: out[dst] = h_bf[dst]@w2 + b2 + sum(y rows of dst) ----------------
// Block = 16 dsts. Phase 1: per-wave y-segment sums into LDS (C-layout).
// Phase 2: MFMA h@w2t with accumulator initialized from LDS + b2; single out write.
__global__ __launch_bounds__(256) void k_out(const int* rowptr2, const unsigned short* y_bf,
    const unsigned short* h_bf, const unsigned short* w2t, const float* b2, float* out) {
  __shared__ float ldsC[16][68];
  int wv = threadIdx.x >> 6, l = threadIdx.x & 63;
  int c4 = l & 15, eq = l >> 4;
  size_t d0 = (size_t)blockIdx.x * 16;
  for (int dd = 0; dd < 4; ++dd) {
    int dst = (int)d0 + wv * 4 + dd;
    int lo = rowptr2[dst * RR];
    int hi = (dst == NN - 1) ? NE : rowptr2[(dst + 1) * RR];
    float4 acc = {0.0f, 0.0f, 0.0f, 0.0f};
    for (int row = lo + eq; row < hi; row += 4) {
      uint2 v = *reinterpret_cast<const uint2*>(y_bf + (size_t)row * 64 + c4 * 4);
      acc.x += b2f((unsigned short)(v.x & 0xffffu));
      acc.y += b2f((unsigned short)(v.x >> 16));
      acc.z += b2f((unsigned short)(v.y & 0xffffu));
      acc.w += b2f((unsigned short)(v.y >> 16));
    }
    acc.x += __shfl_xor(acc.x, 16); acc.y += __shfl_xor(acc.y, 16);
    acc.z += __shfl_xor(acc.z, 16); acc.w += __shfl_xor(acc.w, 16);
    acc.x += __shfl_xor(acc.x, 32); acc.y += __shfl_xor(acc.y, 32);
    acc.z += __shfl_xor(acc.z, 32); acc.w += __shfl_xor(acc.w, 32);
    if (l < 16)
      *reinterpret_cast<float4*>(&ldsC[wv * 4 + dd][l * 4]) = acc;
  }
  __syncthreads();
  // phase 2: wave wv owns n-tile nt=wv (cols nt*16..+16)
  int m = l & 15, q = l >> 4, nt = wv;
  float bb = b2[nt * 16 + m];
  f32x4 acc;
#pragma unroll
  for (int i = 0; i < 4; ++i) acc[i] = ldsC[q * 4 + i][nt * 16 + m] + bb;
#pragma unroll
  for (int s = 0; s < 2; ++s) {
    bf16x8 a = *reinterpret_cast<const bf16x8*>(h_bf + (d0 + m) * 64 + s * 32 + q * 8);
    bf16x8 b = *reinterpret_cast<const bf16x8*>(w2t + (nt * 16 + m) * 64 + s * 32 + q * 8);
    acc = __builtin_amdgcn_mfma_f32_16x16x32_bf16(a, b, acc, 0, 0, 0);
  }
#pragma unroll
  for (int i = 0; i < 4; ++i)
    out[(d0 + q * 4 + i) * 64 + nt * 16 + m] = acc[i];
}

// ---------------- graph bounds ----------------
__global__ void k_bounds(const int* seq, int* bounds) {
  __shared__ int s[GG];
  for (int i = threadIdx.x; i < GG; i += 256) s[i] = seq[i];
  __syncthreads();
  if (threadIdx.x == 0) {
    int acc = 0;
    for (int g = 0; g < GG; ++g) { acc += s[g]; bounds[g] = acc; }
  }
}

// ---------------- fused pool + MLP head + log_softmax ----------------
__global__ __launch_bounds__(256) void k_head(const float* x, const float* outn,
    const int* bounds, const float* lin_w, const float* lin_b,
    const float* fc_w, const float* fc_b, float* dout) {
  __shared__ float4 psum[5][48], pmax[5][48];
  __shared__ float gsum[192], gmax[192];
  __shared__ float part[4][64];
  __shared__ float hid[HD], lg[CC], mred[2];
  int g = blockIdx.x, t = threadIdx.x;
  int lo = (g == 0) ? 0 : bounds[g - 1];
  int hi = bounds[g];
  int nn = hi - lo;
  if (t < 240) {
    int c4 = t % 48, ch = t / 48;
    int a = lo + (nn * ch) / 5, b = lo + (nn * (ch + 1)) / 5;
    float4 s = {0, 0, 0, 0};
    float4 mx = {-3.4e38f, -3.4e38f, -3.4e38f, -3.4e38f};
    const float* bp;
    int stride;
    if (c4 < 32) { bp = x + (size_t)a * FD + c4 * 4; stride = FD; }
    else         { bp = outn + (size_t)a * 64 + (c4 - 32) * 4; stride = 64; }
    int n = a;
    for (; n + 4 <= b; n += 4) {
      float4 v0 = *reinterpret_cast<const float4*>(bp);
      float4 v1 = *reinterpret_cast<const float4*>(bp + stride);
      float4 v2 = *reinterpret_cast<const float4*>(bp + 2 * stride);
      float4 v3 = *reinterpret_cast<const float4*>(bp + 3 * stride);
      bp += 4 * stride;
      s.x += v0.x + v1.x + v2.x + v3.x;
      s.y += v0.y + v1.y + v2.y + v3.y;
      s.z += v0.z + v1.z + v2.z + v3.z;
      s.w += v0.w + v1.w + v2.w + v3.w;
      mx.x = fmaxf(fmaxf(fmaxf(mx.x, v0.x), fmaxf(v1.x, v2.x)), v3.x);
      mx.y = fmaxf(fmaxf(fmaxf(mx.y, v0.y), fmaxf(v1.y, v2.y)), v3.y);
      mx.z = fmaxf(fmaxf(fmaxf(mx.z, v0.z), fmaxf(v1.z, v2.z)), v3.z);
      mx.w = fmaxf(fmaxf(fmaxf(mx.w, v0.w), fmaxf(v1.w, v2.w)), v3.w);
    }
    for (; n < b; ++n) {
      float4 v = *reinterpret_cast<const float4*>(bp);
      bp += stride;
      s.x += v.x; s.y += v.y; s.z += v.z; s.w += v.w;
      mx.x = fmaxf(mx.x, v.x); mx.y = fmaxf(mx.y, v.y);
      mx.z = fmaxf(mx.z, v.z); mx.w = fmaxf(mx.w, v.w);
    }
    psum[ch][c4] = s;
    pmax[ch][c4] = mx;
  }
  __syncthreads();
  if (t < 48) {
    float4 s = psum[0][t], m = pmax[0][t];
#pragma unroll
    for (int ch = 1; ch < 5; ++ch) {
      float4 ps = psum[ch][t], pm = pmax[ch][t];
      s.x += ps.x; s.y += ps.y; s.z += ps.z; s.w += ps.w;
      m.x = fmaxf(m.x, pm.x); m.y = fmaxf(m.y, pm.y);
      m.z = fmaxf(m.z, pm.z); m.w = fmaxf(m.w, pm.w);
    }
    gsum[t * 4 + 0] = s.x; gsum[t * 4 + 1] = s.y;
    gsum[t * 4 + 2] = s.z; gsum[t * 4 + 3] = s.w;
    gmax[t * 4 + 0] = m.x; gmax[t * 4 + 1] = m.y;
    gmax[t * 4 + 2] = m.z; gmax[t * 4 + 3] = m.w;
  }
  __syncthreads();
  {
    int o = t & 63, pp = t >> 6;
    float a = 0.0f;
    int k0 = pp * 96;
    for (int k = k0; k < k0 + 96; ++k) {
      float gv = (k < 192) ? gsum[k] : gmax[k - 192];
      a += gv * lin_w[k * 64 + o];
    }
    part[pp][o] = a;
  }
  __syncthreads();
  if (t < HD) {
    float a = lin_b[t] + part[0][t] + part[1][t] + part[2][t] + part[3][t];
    hid[t] = fmaxf(a, 0.0f);
  }
  __syncthreads();
  if (t < CC) {
    float a = fc_b[t];
    for (int k = 0; k < HD; ++k) a += hid[k] * fc_w[k * CC + t];
    lg[t] = a;
  }
  __syncthreads();
  if (t == 0) {
    float mm = lg[0];
#pragma unroll
    for (int i = 1; i < CC; ++i) mm = fmaxf(mm, lg[i]);
    float se = 0.0f;
#pragma unroll
    for (int i = 0; i < CC; ++i) se += __expf(lg[i] - mm);
    mred[0] = mm;
    mred[1] = __logf(se);
  }
  __syncthreads();
  if (t < CC) dout[g * CC + t] = lg[t] - mred[0] - mred[1];
}

extern "C" void kernel_launch(void* const* d_in, const int* in_sizes, int n_in,
                              void* d_out, int out_size, void* d_ws, size_t ws_size,
                              hipStream_t stream) {
  const float* x     = (const float*)d_in[0];
  const int* ei      = (const int*)d_in[1];
  const float* enorm = (const float*)d_in[2];
  const int* etype   = (const int*)d_in[3];
  const int* seq     = (const int*)d_in[4];
  const float* w1_rel  = (const float*)d_in[6];
  const float* w1_root = (const float*)d_in[7];
  const float* b1      = (const float*)d_in[8];
  const float* bases   = (const float*)d_in[9];
  const float* comp    = (const float*)d_in[10];
  const float* w2      = (const float*)d_in[11];
  const float* b2      = (const float*)d_in[12];
  const float* lin_w   = (const float*)d_in[13];
  const float* lin_b   = (const float*)d_in[14];
  const float* fc_w    = (const float*)d_in[15];
  const float* fc_b    = (const float*)d_in[16];
  float* dout = (float*)d_out;

  char* p = (char*)d_ws;
  unsigned short* hroot_bf = (unsigned short*)p; p += (size_t)NN * 64 * 2;  // 12.8 MB
  unsigned short* xw_bf    = (unsigned short*)p; p += (size_t)NN * 64 * 2;  // 12.8 MB
  float* out  = (float*)p;  p += (size_t)NN * 64 * 4;                       // 25.6 MB (ctr2 alias)
  unsigned short* y_bf = (unsigned short*)p; p += (size_t)NE * 64 * 2;      // 64 MB
  unsigned short* h_bf = (unsigned short*)p; p += (size_t)NN * 64 * 2;      // 12.8 MB
  unsigned short* Wt   = (unsigned short*)p; p += (size_t)RR * 4096 * 2;
  unsigned short* wcat = (unsigned short*)p; p += (size_t)128 * 128 * 2;
  unsigned short* w2t  = (unsigned short*)p; p += (size_t)64 * 64 * 2;
  int* perm1   = (int*)p; p += (size_t)NE * 4;
  int* pos2    = (int*)p; p += (size_t)NE * 4;
  int* es      = (int*)p; p += (size_t)NE * 4;
  float* en    = (float*)p; p += (size_t)NE * 4;
  int* ts      = (int*)p; p += (size_t)NE * 4;
  float* tinv  = (float*)p; p += (size_t)NE * 4;
  int* hist2   = (int*)p; p += (size_t)NN * RR * 4;
  int* rowptr2 = (int*)p; p += (size_t)NN * RR * 4;
  int* bsum    = (int*)p; p += (size_t)NGROUP * 4;
  int* hist1   = (int*)p; p += 64;
  int* ctr1    = (int*)p; p += 64;
  int* offs    = (int*)p; p += 68;
  int* bounds  = (int*)p; p += (size_t)GG * 4;
  int* ctr2    = (int*)out;  // safe: out first written by k_out (after k_perm2)

  hipMemsetAsync(hist2, 0, (size_t)NN * RR * 4, stream);
  hipMemsetAsync(hist1, 0, 128, stream);

  hipLaunchKernelGGL(k_basis, dim3(256), dim3(256), 0, stream, comp, bases, Wt);
  hipLaunchKernelGGL(k_wcvt, dim3(80), dim3(256), 0, stream, w1_root, w1_rel, w2, wcat, w2t);
  hipLaunchKernelGGL(k_proj_mfma, dim3((NGROUP + 3) / 4), dim3(256), 0, stream, x, wcat, b1,
                     hroot_bf, xw_bf);
  hipLaunchKernelGGL(k_hists, dim3(512), dim3(256), 0, stream, ei, etype, hist1, hist2);
  hipLaunchKernelGGL(k_scan1, dim3(1), dim3(64), 0, stream, hist1, offs, ctr1);
  hipLaunchKernelGGL(k_perm1, dim3((NE + 255) / 256), dim3(256), 0, stream, etype, ctr1, perm1);
  hipLaunchKernelGGL(k_scanA, dim3(NGROUP), dim3(256), 0, stream, hist2, bsum);
  hipLaunchKernelGGL(k_scanB, dim3(1), dim3(256), 0, stream, bsum);
  hipLaunchKernelGGL(k_scanC, dim3(NGROUP), dim3(256), 0, stream, hist2, bsum, rowptr2, ctr2);
  hipLaunchKernelGGL(k_perm2, dim3((NE + 255) / 256), dim3(256), 0, stream,
                     perm1, ei, etype, enorm, hist2, ctr2, pos2, es, en, ts, tinv);
  hipLaunchKernelGGL(k_gconv_seg, dim3(NN / 4), dim3(256), 0, stream,
                     rowptr2, es, en, xw_bf, hroot_bf, h_bf);
  hipLaunchKernelGGL(k_rgcn_y, dim3(RR, 128), dim3(256), 0, stream,
                     ts, tinv, pos2, offs, h_bf, Wt, y_bf);
  hipLaunchKernelGGL(k_out, dim3(NN / 16), dim3(256), 0, stream,
                     rowptr2, y_bf, h_bf, w2t, b2, out);
  hipLaunchKernelGGL(k_bounds, dim3(1), dim3(256), 0, stream, seq, bounds);
  hipLaunchKernelGGL(k_head, dim3(GG), dim3(256), 0, stream, x, out, bounds,
                     lin_w, lin_b, fc_w, fc_b, dout);
}

// Round 9
// 378.993 us; speedup vs baseline: 1.5759x; 1.0153x over previous
//
#include <hip/hip_runtime.h>
#include <hip/hip_bf16.h>

#define NN 100000   // nodes
#define NE 500000   // edges
#define FD 128      // input features
#define HD 64       // hidden
#define RR 16       // relations
#define NBASE 30    // bases
#define GG 1000     // graphs
#define CC 10       // classes
#define NGROUP 6250 // NN/16

// All per-node 64-vectors (hroot_bf, xw_bf, h_bf, y_bf) are stored in
// sigma-order: stored[(c&15)*4 + (c>>4)] = true[c]. This is the MFMA C-layout
// interleave, so C-fragments store as one uint2 per lane per row.
// Wt and w2t have their contraction (k) dim sigma-permuted to match.
// out and d_out are in TRUE layout.

typedef __attribute__((ext_vector_type(8))) short bf16x8;
typedef __attribute__((ext_vector_type(4))) float f32x4;

__device__ inline unsigned short f2b(float x) {
  __hip_bfloat16 b = __float2bfloat16(x);
  return *reinterpret_cast<unsigned short*>(&b);
}
__device__ inline float b2f(unsigned short u) {
  return __uint_as_float(((unsigned)u) << 16);
}
__device__ inline unsigned pk2(float a, float b) {
  return (unsigned)f2b(a) | ((unsigned)f2b(b) << 16);
}

// ---------------- Wt[r][n][sig(k)] = sum_b comp[r,b]*bases[b][k][n] (bf16) ----------------
__global__ void k_basis(const float* comp, const float* bases, unsigned short* Wt) {
  int idx = blockIdx.x * 256 + threadIdx.x;  // r*4096 + k*64 + n
  int r = idx >> 12, kj = idx & 4095;
  int k = kj >> 6, n = kj & 63;
  float acc = 0.0f;
  for (int b = 0; b < NBASE; ++b)
    acc += comp[r * NBASE + b] * bases[b * 4096 + kj];
  int sk = (k & 15) * 4 + (k >> 4);
  Wt[(r << 12) + n * 64 + sk] = f2b(acc);
}

// ---------------- wcat[n][k] (true k); w2t[n][sig(k)] ----------------
__global__ void k_wcvt(const float* w_root, const float* w_rel, const float* w2,
                       unsigned short* wcat, unsigned short* w2t) {
  int idx = blockIdx.x * 256 + threadIdx.x;
  if (idx < 16384) {
    int n = idx >> 7, k = idx & 127;
    float v = (n < 64) ? w_root[k * 64 + n] : w_rel[k * 64 + (n - 64)];
    wcat[n * 128 + k] = f2b(v);
  } else if (idx < 16384 + 4096) {
    int i2 = idx - 16384;
    int n = i2 >> 6, k = i2 & 63;
    int sk = (k & 15) * 4 + (k >> 4);
    w2t[n * 64 + sk] = f2b(w2[k * 64 + n]);
  }
}

// ---------------- hroot_bf / xw_bf (sigma layout), register->global, no LDS ----------------
__global__ __launch_bounds__(256) void k_proj_mfma(const float* x, const unsigned short* wcat,
                                                   const float* b1, unsigned short* hroot_bf,
                                                   unsigned short* xw_bf) {
  int wv = threadIdx.x >> 6, l = threadIdx.x & 63, m = l & 15, q = l >> 4;
  int g = blockIdx.x * 4 + wv;
  if (g >= NGROUP) return;
  size_t n0 = (size_t)g * 16;
  f32x4 acc[8];
#pragma unroll
  for (int nt = 0; nt < 8; ++nt) acc[nt] = (f32x4){0, 0, 0, 0};
#pragma unroll
  for (int s = 0; s < 4; ++s) {
    const float* xr = x + (n0 + m) * FD + s * 32 + q * 8;
    float4 xa = *reinterpret_cast<const float4*>(xr);
    float4 xb = *reinterpret_cast<const float4*>(xr + 4);
    bf16x8 a;
    a[0] = (short)f2b(xa.x); a[1] = (short)f2b(xa.y);
    a[2] = (short)f2b(xa.z); a[3] = (short)f2b(xa.w);
    a[4] = (short)f2b(xb.x); a[5] = (short)f2b(xb.y);
    a[6] = (short)f2b(xb.z); a[7] = (short)f2b(xb.w);
#pragma unroll
    for (int nt = 0; nt < 8; ++nt) {
      bf16x8 b = *reinterpret_cast<const bf16x8*>(wcat + (nt * 16 + m) * 128 + s * 32 + q * 8);
      acc[nt] = __builtin_amdgcn_mfma_f32_16x16x32_bf16(a, b, acc[nt], 0, 0, 0);
    }
  }
  float b1v[4];
#pragma unroll
  for (int nt = 0; nt < 4; ++nt) b1v[nt] = b1[nt * 16 + m];
#pragma unroll
  for (int i = 0; i < 4; ++i) {
    size_t row = (n0 + q * 4 + i) * 64 + m * 4;  // sigma: stored = m*4 + nt
    uint2 hv, xv;
    hv.x = pk2(acc[0][i] + b1v[0], acc[1][i] + b1v[1]);
    hv.y = pk2(acc[2][i] + b1v[2], acc[3][i] + b1v[3]);
    xv.x = pk2(acc[4][i], acc[5][i]);
    xv.y = pk2(acc[6][i], acc[7][i]);
    *reinterpret_cast<uint2*>(hroot_bf + row) = hv;
    *reinterpret_cast<uint2*>(xw_bf + row) = xv;
  }
}

// ---------------- histograms ----------------
__global__ void k_hists(const int* ei, const int* etype, int* hist1, int* hist2) {
  __shared__ int lh[RR];
  if (threadIdx.x < RR) lh[threadIdx.x] = 0;
  __syncthreads();
  for (int e = blockIdx.x * 256 + threadIdx.x; e < NE; e += gridDim.x * 256) {
    int t = etype[e];
    atomicAdd(&lh[t], 1);
    atomicAdd(&hist2[ei[NE + e] * RR + t], 1);
  }
  __syncthreads();
  if (threadIdx.x < RR) atomicAdd(&hist1[threadIdx.x], lh[threadIdx.x]);
}

__global__ void k_scan1(const int* hist1, int* offs, int* ctr1) {
  if (threadIdx.x == 0) {
    int s = 0;
    for (int r = 0; r < RR; ++r) { offs[r] = s; ctr1[r] = s; s += hist1[r]; }
    offs[RR] = s;
  }
}

// ---------------- hierarchical scan of hist2 ----------------
__device__ inline int block_scan_incl(int v, int* ps, int t) {
  ps[t] = v;
  __syncthreads();
  for (int off = 1; off < 256; off <<= 1) {
    int u = (t >= off) ? ps[t - off] : 0;
    __syncthreads();
    ps[t] += u;
    __syncthreads();
  }
  return ps[t];
}

__global__ void k_scanA(const int* hist2, int* bsum) {
  __shared__ int red[256];
  int t = threadIdx.x;
  red[t] = hist2[blockIdx.x * 256 + t];
  __syncthreads();
  for (int s = 128; s; s >>= 1) {
    if (t < s) red[t] += red[t + s];
    __syncthreads();
  }
  if (t == 0) bsum[blockIdx.x] = red[0];
}

__global__ void k_scanB(int* bsum) {
  int t = threadIdx.x;
  int loc[25];
  int s = 0;
  if (t < 250) {
    for (int i = 0; i < 25; ++i) { loc[i] = bsum[t * 25 + i]; s += loc[i]; }
  }
  __shared__ int ps[256];
  int incl = block_scan_incl(s, ps, t);
  int base = incl - s;
  if (t < 250) {
    int run = base;
    for (int i = 0; i < 25; ++i) { int tmp = loc[i]; bsum[t * 25 + i] = run; run += tmp; }
  }
}

__global__ void k_scanC(const int* hist2, const int* bsum, int* rowptr2, int* ctr2) {
  int t = threadIdx.x;
  int gid = blockIdx.x * 256 + t;
  int v = hist2[gid];
  __shared__ int ps[256];
  int incl = block_scan_incl(v, ps, t);
  int ex = bsum[blockIdx.x] + incl - v;
  rowptr2[gid] = ex;
  ctr2[gid] = ex;
}

// ---------------- fused sort: one pass over original edges (coalesced reads) ----------------
// tse[p] = {src, inv_bits, pos, 0} at type-order slot p; esen[pos] = {src, norm} at dst slot.
__global__ void k_sort(const int* ei, const int* etype, const float* enorm,
                       const int* hist2, int* ctr1, int* ctr2, uint4* tse, uint2* esen) {
  __shared__ int lcnt[RR], lbase[RR];
  if (threadIdx.x < RR) lcnt[threadIdx.x] = 0;
  __syncthreads();
  int e = blockIdx.x * 256 + threadIdx.x;
  int t = 0, rank = 0;
  bool valid = e < NE;
  if (valid) { t = etype[e]; rank = atomicAdd(&lcnt[t], 1); }
  __syncthreads();
  if (threadIdx.x < RR) {
    int n = lcnt[threadIdx.x];
    lbase[threadIdx.x] = n ? atomicAdd(&ctr1[threadIdx.x], n) : 0;
  }
  __syncthreads();
  if (valid) {
    int p = lbase[t] + rank;
    int src = ei[e];
    int key = ei[NE + e] * RR + t;
    int pos = atomicAdd(&ctr2[key], 1);
    float nrm = enorm[e];
    float inv = 1.0f / (float)max(hist2[key], 1);
    esen[pos] = make_uint2((unsigned)src, __float_as_uint(nrm));
    tse[p] = make_uint4((unsigned)src, __float_as_uint(inv), (unsigned)pos, 0u);
  }
}

// ---------------- GraphConv segment-sum: 4 edges/iter, uint2 loads (sigma space) ----------------
__global__ __launch_bounds__(256) void k_gconv_seg(const int* rowptr2, const uint2* esen,
    const unsigned short* xw_bf, const unsigned short* hroot_bf, unsigned short* h_bf) {
  int wv = threadIdx.x >> 6, l = threadIdx.x & 63;
  int c4 = l & 15, eq = l >> 4;
  int dst = blockIdx.x * 4 + wv;
  int lo = rowptr2[dst * RR];
  int hi = (dst == NN - 1) ? NE : rowptr2[(dst + 1) * RR];
  float4 acc = {0.0f, 0.0f, 0.0f, 0.0f};
  for (int base0 = lo; base0 < hi; base0 += 64) {
    int n = min(64, hi - base0);
    int sv = 0;
    float nv = 0.0f;
    if (l < n) {
      uint2 se = esen[base0 + l];
      sv = (int)se.x;
      nv = __uint_as_float(se.y);
    }
    int k4max = (n + 3) >> 2;
    for (int k4 = 0; k4 < k4max; ++k4) {
      int eid = k4 * 4 + eq;
      int s = __shfl(sv, eid);
      float w = __shfl(nv, eid);
      if (eid < n) {
        uint2 v = *reinterpret_cast<const uint2*>(xw_bf + (size_t)s * 64 + c4 * 4);
        acc.x += b2f((unsigned short)(v.x & 0xffffu)) * w;
        acc.y += b2f((unsigned short)(v.x >> 16)) * w;
        acc.z += b2f((unsigned short)(v.y & 0xffffu)) * w;
        acc.w += b2f((unsigned short)(v.y >> 16)) * w;
      }
    }
  }
  acc.x += __shfl_xor(acc.x, 16); acc.y += __shfl_xor(acc.y, 16);
  acc.z += __shfl_xor(acc.z, 16); acc.w += __shfl_xor(acc.w, 16);
  acc.x += __shfl_xor(acc.x, 32); acc.y += __shfl_xor(acc.y, 32);
  acc.z += __shfl_xor(acc.z, 32); acc.w += __shfl_xor(acc.w, 32);
  if (l < 16) {
    uint2 hb = *reinterpret_cast<const uint2*>(hroot_bf + (size_t)dst * 64 + l * 4);
    acc.x += b2f((unsigned short)(hb.x & 0xffffu));
    acc.y += b2f((unsigned short)(hb.x >> 16));
    acc.z += b2f((unsigned short)(hb.y & 0xffffu));
    acc.w += b2f((unsigned short)(hb.y >> 16));
    uint2 o;
    o.x = pk2(acc.x, acc.y);
    o.y = pk2(acc.z, acc.w);
    *reinterpret_cast<uint2*>(h_bf + (size_t)dst * 64 + l * 4) = o;
  }
}

// ---------------- RGCN via MFMA; y rows at dst-ordered slots, sigma uint2 stores ----------------
__global__ __launch_bounds__(256) void k_rgcn_y(const uint4* tse, const int* offs,
    const unsigned short* h_bf, const unsigned short* Wt, unsigned short* y_bf) {
  int r = blockIdx.x;
  int lo = offs[r], hi = offs[r + 1];
  int cnt = hi - lo;
  int wv = threadIdx.x >> 6;
  int l = threadIdx.x & 63;
  int m = l & 15, q = l >> 4;
  int ngroups = (cnt + 15) / 16;
  const unsigned short* Wr = Wt + (r << 12);
  bf16x8 bfr[2][4];
#pragma unroll
  for (int s = 0; s < 2; ++s)
#pragma unroll
    for (int nt = 0; nt < 4; ++nt)
      bfr[s][nt] = *reinterpret_cast<const bf16x8*>(Wr + (nt * 16 + m) * 64 + s * 32 + q * 8);

  for (int g = blockIdx.y * 4 + wv; g < ngroups; g += gridDim.y * 4) {
    int base = lo + g * 16;
    int ne = min(16, hi - base);
    int p = base + ((m < ne) ? m : 0);
    uint4 t4 = tse[p];
    int src = (int)t4.x;
    float inv = __uint_as_float(t4.y);
    int pos = (int)t4.z;
    f32x4 acc[4];
#pragma unroll
    for (int nt = 0; nt < 4; ++nt) acc[nt] = (f32x4){0, 0, 0, 0};
    const unsigned short* hrow = h_bf + (size_t)src * 64 + q * 8;
#pragma unroll
    for (int s = 0; s < 2; ++s) {
      bf16x8 afr = *reinterpret_cast<const bf16x8*>(hrow + s * 32);
#pragma unroll
      for (int nt = 0; nt < 4; ++nt)
        acc[nt] = __builtin_amdgcn_mfma_f32_16x16x32_bf16(afr, bfr[s][nt], acc[nt], 0, 0, 0);
    }
#pragma unroll
    for (int i = 0; i < 4; ++i) {
      int row = q * 4 + i;
      float ir = __shfl(inv, row);
      int pr = __shfl(pos, row);
      if (row < ne) {
        uint2 o;
        o.x = pk2(acc[0][i] * ir, acc[1][i] * ir);
        o.y = pk2(acc[2][i] * ir, acc[3][i] * ir);
        *reinterpret_cast<uint2*>(y_bf + (size_t)pr * 64 + m * 4) = o;
      }
    }
  }
}

// ---------------- fused: out[dst] = h_bf[dst]@w2 + b2 + sum(y rows of dst) ----------------
__global__ __launch_bounds__(256) void k_out(const int* rowptr2, const unsigned short* y_bf,
    const unsigned short* h_bf, const unsigned short* w2t, const float* b2, float* out) {
  __shared__ float ldsC[16][68];   // [dst-in-block][sigma col]
  int wv = threadIdx.x >> 6, l = threadIdx.x & 63;
  int c4 = l & 15, eq = l >> 4;
  size_t d0 = (size_t)blockIdx.x * 16;
  for (int dd = 0; dd < 4; ++dd) {
    int dst = (int)d0 + wv * 4 + dd;
    int lo = rowptr2[dst * RR];
    int hi = (dst == NN - 1) ? NE : rowptr2[(dst + 1) * RR];
    float4 acc = {0.0f, 0.0f, 0.0f, 0.0f};
    for (int row = lo + eq; row < hi; row += 4) {
      uint2 v = *reinterpret_cast<const uint2*>(y_bf + (size_t)row * 64 + c4 * 4);
      acc.x += b2f((unsigned short)(v.x & 0xffffu));
      acc.y += b2f((unsigned short)(v.x >> 16));
      acc.z += b2f((unsigned short)(v.y & 0xffffu));
      acc.w += b2f((unsigned short)(v.y >> 16));
    }
    acc.x += __shfl_xor(acc.x, 16); acc.y += __shfl_xor(acc.y, 16);
    acc.z += __shfl_xor(acc.z, 16); acc.w += __shfl_xor(acc.w, 16);
    acc.x += __shfl_xor(acc.x, 32); acc.y += __shfl_xor(acc.y, 32);
    acc.z += __shfl_xor(acc.z, 32); acc.w += __shfl_xor(acc.w, 32);
    if (l < 16)
      *reinterpret_cast<float4*>(&ldsC[wv * 4 + dd][l * 4]) = acc;
  }
  __syncthreads();
  // phase 2: wave wv owns true cols wv*16 + m; y-sum for that col is at sigma m*4+wv
  int m = l & 15, q = l >> 4, nt = wv;
  float bb = b2[nt * 16 + m];
  f32x4 acc;
#pragma unroll
  for (int i = 0; i < 4; ++i) acc[i] = ldsC[q * 4 + i][m * 4 + nt] + bb;
#pragma unroll
  for (int s = 0; s < 2; ++s) {
    bf16x8 a = *reinterpret_cast<const bf16x8*>(h_bf + (d0 + m) * 64 + s * 32 + q * 8);
    bf16x8 b = *reinterpret_cast<const bf16x8*>(w2t + (nt * 16 + m) * 64 + s * 32 + q * 8);
    acc = __builtin_amdgcn_mfma_f32_16x16x32_bf16(a, b, acc, 0, 0, 0);
  }
#pragma unroll
  for (int i = 0; i < 4; ++i)
    out[(d0 + q * 4 + i) * 64 + nt * 16 + m] = acc[i];   // TRUE layout
}

// ---------------- graph bounds ----------------
__global__ void k_bounds(const int* seq, int* bounds) {
  __shared__ int s[GG];
  for (int i = threadIdx.x; i < GG; i += 256) s[i] = seq[i];
  __syncthreads();
  if (threadIdx.x == 0) {
    int acc = 0;
    for (int g = 0; g < GG; ++g) { acc += s[g]; bounds[g] = acc; }
  }
}

// ---------------- fused pool + MLP head + log_softmax ----------------
__global__ __launch_bounds__(256) void k_head(const float* x, const float* outn,
    const int* bounds, const float* lin_w, const float* lin_b,
    const float* fc_w, const float* fc_b, float* dout) {
  __shared__ float4 psum[5][48], pmax[5][48];
  __shared__ float gsum[192], gmax[192];
  __shared__ float part[4][64];
  __shared__ float hid[HD], lg[CC], mred[2];
  int g = blockIdx.x, t = threadIdx.x;
  int lo = (g == 0) ? 0 : bounds[g - 1];
  int hi = bounds[g];
  int nn = hi - lo;
  if (t < 240) {
    int c4 = t % 48, ch = t / 48;
    int a = lo + (nn * ch) / 5, b = lo + (nn * (ch + 1)) / 5;
    float4 s = {0, 0, 0, 0};
    float4 mx = {-3.4e38f, -3.4e38f, -3.4e38f, -3.4e38f};
    const float* bp;
    int stride;
    if (c4 < 32) { bp = x + (size_t)a * FD + c4 * 4; stride = FD; }
    else         { bp = outn + (size_t)a * 64 + (c4 - 32) * 4; stride = 64; }
    int n = a;
    for (; n + 4 <= b; n += 4) {
      float4 v0 = *reinterpret_cast<const float4*>(bp);
      float4 v1 = *reinterpret_cast<const float4*>(bp + stride);
      float4 v2 = *reinterpret_cast<const float4*>(bp + 2 * stride);
      float4 v3 = *reinterpret_cast<const float4*>(bp + 3 * stride);
      bp += 4 * stride;
      s.x += v0.x + v1.x + v2.x + v3.x;
      s.y += v0.y + v1.y + v2.y + v3.y;
      s.z += v0.z + v1.z + v2.z + v3.z;
      s.w += v0.w + v1.w + v2.w + v3.w;
      mx.x = fmaxf(fmaxf(fmaxf(mx.x, v0.x), fmaxf(v1.x, v2.x)), v3.x);
      mx.y = fmaxf(fmaxf(fmaxf(mx.y, v0.y), fmaxf(v1.y, v2.y)), v3.y);
      mx.z = fmaxf(fmaxf(fmaxf(mx.z, v0.z), fmaxf(v1.z, v2.z)), v3.z);
      mx.w = fmaxf(fmaxf(fmaxf(mx.w, v0.w), fmaxf(v1.w, v2.w)), v3.w);
    }
    for (; n < b; ++n) {
      float4 v = *reinterpret_cast<const float4*>(bp);
      bp += stride;
      s.x += v.x; s.y += v.y; s.z += v.z; s.w += v.w;
      mx.x = fmaxf(mx.x, v.x); mx.y = fmaxf(mx.y, v.y);
      mx.z = fmaxf(mx.z, v.z); mx.w = fmaxf(mx.w, v.w);
    }
    psum[ch][c4] = s;
    pmax[ch][c4] = mx;
  }
  __syncthreads();
  if (t < 48) {
    float4 s = psum[0][t], m = pmax[0][t];
#pragma unroll
    for (int ch = 1; ch < 5; ++ch) {
      float4 ps = psum[ch][t], pm = pmax[ch][t];
      s.x += ps.x; s.y += ps.y; s.z += ps.z; s.w += ps.w;
      m.x = fmaxf(m.x, pm.x); m.y = fmaxf(m.y, pm.y);
      m.z = fmaxf(m.z, pm.z); m.w = fmaxf(m.w, pm.w);
    }
    gsum[t * 4 + 0] = s.x; gsum[t * 4 + 1] = s.y;
    gsum[t * 4 + 2] = s.z; gsum[t * 4 + 3] = s.w;
    gmax[t * 4 + 0] = m.x; gmax[t * 4 + 1] = m.y;
    gmax[t * 4 + 2] = m.z; gmax[t * 4 + 3] = m.w;
  }
  __syncthreads();
  {
    int o = t & 63, pp = t >> 6;
    float a = 0.0f;
    int k0 = pp * 96;
    for (int k = k0; k < k0 + 96; ++k) {
      float gv = (k < 192) ? gsum[k] : gmax[k - 192];
      a += gv * lin_w[k * 64 + o];
    }
    part[pp][o] = a;
  }
  __syncthreads();
  if (t < HD) {
    float a = lin_b[t] + part[0][t] + part[1][t] + part[2][t] + part[3][t];
    hid[t] = fmaxf(a, 0.0f);
  }
  __syncthreads();
  if (t < CC) {
    float a = fc_b[t];
    for (int k = 0; k < HD; ++k) a += hid[k] * fc_w[k * CC + t];
    lg[t] = a;
  }
  __syncthreads();
  if (t == 0) {
    float mm = lg[0];
#pragma unroll
    for (int i = 1; i < CC; ++i) mm = fmaxf(mm, lg[i]);
    float se = 0.0f;
#pragma unroll
    for (int i = 0; i < CC; ++i) se += __expf(lg[i] - mm);
    mred[0] = mm;
    mred[1] = __logf(se);
  }
  __syncthreads();
  if (t < CC) dout[g * CC + t] = lg[t] - mred[0] - mred[1];
}

extern "C" void kernel_launch(void* const* d_in, const int* in_sizes, int n_in,
                              void* d_out, int out_size, void* d_ws, size_t ws_size,
                              hipStream_t stream) {
  const float* x     = (const float*)d_in[0];
  const int* ei      = (const int*)d_in[1];
  const float* enorm = (const float*)d_in[2];
  const int* etype   = (const int*)d_in[3];
  const int* seq     = (const int*)d_in[4];
  const float* w1_rel  = (const float*)d_in[6];
  const float* w1_root = (const float*)d_in[7];
  const float* b1      = (const float*)d_in[8];
  const float* bases   = (const float*)d_in[9];
  const float* comp    = (const float*)d_in[10];
  const float* w2      = (const float*)d_in[11];
  const float* b2      = (const float*)d_in[12];
  const float* lin_w   = (const float*)d_in[13];
  const float* lin_b   = (const float*)d_in[14];
  const float* fc_w    = (const float*)d_in[15];
  const float* fc_b    = (const float*)d_in[16];
  float* dout = (float*)d_out;

  char* p = (char*)d_ws;
  unsigned short* hroot_bf = (unsigned short*)p; p += (size_t)NN * 64 * 2;  // 12.8 MB
  unsigned short* xw_bf    = (unsigned short*)p; p += (size_t)NN * 64 * 2;  // 12.8 MB
  float* out  = (float*)p;  p += (size_t)NN * 64 * 4;                       // 25.6 MB (ctr2 alias)
  unsigned short* y_bf = (unsigned short*)p; p += (size_t)NE * 64 * 2;      // 64 MB
  unsigned short* h_bf = (unsigned short*)p; p += (size_t)NN * 64 * 2;      // 12.8 MB
  unsigned short* Wt   = (unsigned short*)p; p += (size_t)RR * 4096 * 2;
  unsigned short* wcat = (unsigned short*)p; p += (size_t)128 * 128 * 2;
  unsigned short* w2t  = (unsigned short*)p; p += (size_t)64 * 64 * 2;
  uint4* tse   = (uint4*)p; p += (size_t)NE * 16;       // 8 MB
  uint2* esen  = (uint2*)p; p += (size_t)NE * 8;        // 4 MB
  int* hist2   = (int*)p; p += (size_t)NN * RR * 4;     // 6.4 MB
  int* rowptr2 = (int*)p; p += (size_t)NN * RR * 4;     // 6.4 MB
  int* bsum    = (int*)p; p += (size_t)NGROUP * 4;
  int* hist1   = (int*)p; p += 64;
  int* ctr1    = (int*)p; p += 64;
  int* offs    = (int*)p; p += 68;
  int* bounds  = (int*)p; p += (size_t)GG * 4;
  int* ctr2    = (int*)out;  // safe: out first written by k_out (after k_sort)

  hipMemsetAsync(hist2, 0, (size_t)NN * RR * 4, stream);
  hipMemsetAsync(hist1, 0, 128, stream);  // hist1 + ctr1

  hipLaunchKernelGGL(k_basis, dim3(256), dim3(256), 0, stream, comp, bases, Wt);
  hipLaunchKernelGGL(k_wcvt, dim3(80), dim3(256), 0, stream, w1_root, w1_rel, w2, wcat, w2t);
  hipLaunchKernelGGL(k_proj_mfma, dim3((NGROUP + 3) / 4), dim3(256), 0, stream, x, wcat, b1,
                     hroot_bf, xw_bf);
  hipLaunchKernelGGL(k_hists, dim3(512), dim3(256), 0, stream, ei, etype, hist1, hist2);
  hipLaunchKernelGGL(k_scan1, dim3(1), dim3(64), 0, stream, hist1, offs, ctr1);
  hipLaunchKernelGGL(k_scanA, dim3(NGROUP), dim3(256), 0, stream, hist2, bsum);
  hipLaunchKernelGGL(k_scanB, dim3(1), dim3(256), 0, stream, bsum);
  hipLaunchKernelGGL(k_scanC, dim3(NGROUP), dim3(256), 0, stream, hist2, bsum, rowptr2, ctr2);
  hipLaunchKernelGGL(k_sort, dim3((NE + 255) / 256), dim3(256), 0, stream,
                     ei, etype, enorm, hist2, ctr1, ctr2, tse, esen);
  hipLaunchKernelGGL(k_gconv_seg, dim3(NN / 4), dim3(256), 0, stream,
                     rowptr2, esen, xw_bf, hroot_bf, h_bf);
  hipLaunchKernelGGL(k_rgcn_y, dim3(RR, 128), dim3(256), 0, stream,
                     tse, offs, h_bf, Wt, y_bf);
  hipLaunchKernelGGL(k_out, dim3(NN / 16), dim3(256), 0, stream,
                     rowptr2, y_bf, h_bf, w2t, b2, out);
  hipLaunchKernelGGL(k_bounds, dim3(1), dim3(256), 0, stream, seq, bounds);
  hipLaunchKernelGGL(k_head, dim3(GG), dim3(256), 0, stream, x, out, bounds,
                     lin_w, lin_b, fc_w, fc_b, dout);
}

// Round 10
// 371.846 us; speedup vs baseline: 1.6062x; 1.0192x over previous
//
#include <hip/hip_runtime.h>
#include <hip/hip_bf16.h>

#define NN 100000   // nodes
#define NE 500000   // edges
#define FD 128      // input features
#define HD 64       // hidden
#define RR 16       // relations
#define NBASE 30    // bases
#define GG 1000     // graphs
#define CC 10       // classes
#define NGROUP 6250 // NN/16

// Per-node 64-vectors (hroot_bf, xw_bf, h_bf, y_bf) are stored sigma-order:
// stored[(c&15)*4 + (c>>4)] = true[c] (MFMA C-layout interleave). Wt/w2t have
// contraction dim sigma-permuted to match. out/d_out are TRUE layout.

typedef __attribute__((ext_vector_type(8))) short bf16x8;
typedef __attribute__((ext_vector_type(4))) float f32x4;

__device__ inline unsigned short f2b(float x) {
  __hip_bfloat16 b = __float2bfloat16(x);
  return *reinterpret_cast<unsigned short*>(&b);
}
__device__ inline float b2f(unsigned short u) {
  return __uint_as_float(((unsigned)u) << 16);
}
__device__ inline unsigned pk2(float a, float b) {
  return (unsigned)f2b(a) | ((unsigned)f2b(b) << 16);
}

// ---------------- Wt[r][n][sig(k)] = sum_b comp[r,b]*bases[b][k][n] (bf16) ----------------
__global__ void k_basis(const float* comp, const float* bases, unsigned short* Wt) {
  int idx = blockIdx.x * 256 + threadIdx.x;  // r*4096 + k*64 + n
  int r = idx >> 12, kj = idx & 4095;
  int k = kj >> 6, n = kj & 63;
  float acc = 0.0f;
  for (int b = 0; b < NBASE; ++b)
    acc += comp[r * NBASE + b] * bases[b * 4096 + kj];
  int sk = (k & 15) * 4 + (k >> 4);
  Wt[(r << 12) + n * 64 + sk] = f2b(acc);
}

// ---------------- wcat[n][k] (true k); w2t[n][sig(k)] ----------------
__global__ void k_wcvt(const float* w_root, const float* w_rel, const float* w2,
                       unsigned short* wcat, unsigned short* w2t) {
  int idx = blockIdx.x * 256 + threadIdx.x;
  if (idx < 16384) {
    int n = idx >> 7, k = idx & 127;
    float v = (n < 64) ? w_root[k * 64 + n] : w_rel[k * 64 + (n - 64)];
    wcat[n * 128 + k] = f2b(v);
  } else if (idx < 16384 + 4096) {
    int i2 = idx - 16384;
    int n = i2 >> 6, k = i2 & 63;
    int sk = (k & 15) * 4 + (k >> 4);
    w2t[n * 64 + sk] = f2b(w2[k * 64 + n]);
  }
}

// ---------------- hroot_bf / xw_bf (sigma), 2 waves/group, preloaded x ----------------
__global__ __launch_bounds__(256) void k_proj_mfma(const float* x, const unsigned short* wcat,
                                                   const float* b1, unsigned short* hroot_bf,
                                                   unsigned short* xw_bf) {
  int wv = threadIdx.x >> 6, l = threadIdx.x & 63, m = l & 15, q = l >> 4;
  int gid = blockIdx.x * 4 + wv;
  int g = gid >> 1, half = gid & 1;   // half 0 -> h tiles, half 1 -> xw tiles
  if (g >= NGROUP) return;
  size_t n0 = (size_t)g * 16;
  // preload all 8 float4 (one x row, 128 floats / 16 per lane-quad pattern)
  const float* xr = x + (n0 + m) * FD + q * 8;
  float4 xv[8];
#pragma unroll
  for (int s = 0; s < 4; ++s) {
    xv[2 * s] = *reinterpret_cast<const float4*>(xr + s * 32);
    xv[2 * s + 1] = *reinterpret_cast<const float4*>(xr + s * 32 + 4);
  }
  f32x4 acc[4];
#pragma unroll
  for (int nt = 0; nt < 4; ++nt) acc[nt] = (f32x4){0, 0, 0, 0};
#pragma unroll
  for (int s = 0; s < 4; ++s) {
    float4 xa = xv[2 * s], xb = xv[2 * s + 1];
    bf16x8 a;
    a[0] = (short)f2b(xa.x); a[1] = (short)f2b(xa.y);
    a[2] = (short)f2b(xa.z); a[3] = (short)f2b(xa.w);
    a[4] = (short)f2b(xb.x); a[5] = (short)f2b(xb.y);
    a[6] = (short)f2b(xb.z); a[7] = (short)f2b(xb.w);
#pragma unroll
    for (int nt = 0; nt < 4; ++nt) {
      bf16x8 b = *reinterpret_cast<const bf16x8*>(
          wcat + ((half * 4 + nt) * 16 + m) * 128 + s * 32 + q * 8);
      acc[nt] = __builtin_amdgcn_mfma_f32_16x16x32_bf16(a, b, acc[nt], 0, 0, 0);
    }
  }
  float bv[4] = {0, 0, 0, 0};
  if (half == 0) {
#pragma unroll
    for (int nt = 0; nt < 4; ++nt) bv[nt] = b1[nt * 16 + m];
  }
  unsigned short* dbuf = half ? xw_bf : hroot_bf;
#pragma unroll
  for (int i = 0; i < 4; ++i) {
    size_t row = (n0 + q * 4 + i) * 64 + m * 4;  // sigma: stored = m*4 + nt
    uint2 o;
    o.x = pk2(acc[0][i] + bv[0], acc[1][i] + bv[1]);
    o.y = pk2(acc[2][i] + bv[2], acc[3][i] + bv[3]);
    *reinterpret_cast<uint2*>(dbuf + row) = o;
  }
}

// ---------------- histograms ----------------
__global__ void k_hists(const int* ei, const int* etype, int* hist1, int* hist2) {
  __shared__ int lh[RR];
  if (threadIdx.x < RR) lh[threadIdx.x] = 0;
  __syncthreads();
  for (int e = blockIdx.x * 256 + threadIdx.x; e < NE; e += gridDim.x * 256) {
    int t = etype[e];
    atomicAdd(&lh[t], 1);
    atomicAdd(&hist2[ei[NE + e] * RR + t], 1);
  }
  __syncthreads();
  if (threadIdx.x < RR) atomicAdd(&hist1[threadIdx.x], lh[threadIdx.x]);
}

__global__ void k_scan1(const int* hist1, int* offs, int* ctr1) {
  if (threadIdx.x == 0) {
    int s = 0;
    for (int r = 0; r < RR; ++r) { offs[r] = s; ctr1[r] = s; s += hist1[r]; }
    offs[RR] = s;
  }
}

// ---------------- hierarchical scan of hist2 ----------------
__device__ inline int block_scan_incl(int v, int* ps, int t) {
  ps[t] = v;
  __syncthreads();
  for (int off = 1; off < 256; off <<= 1) {
    int u = (t >= off) ? ps[t - off] : 0;
    __syncthreads();
    ps[t] += u;
    __syncthreads();
  }
  return ps[t];
}

__global__ void k_scanA(const int* hist2, int* bsum) {
  __shared__ int red[256];
  int t = threadIdx.x;
  red[t] = hist2[blockIdx.x * 256 + t];
  __syncthreads();
  for (int s = 128; s; s >>= 1) {
    if (t < s) red[t] += red[t + s];
    __syncthreads();
  }
  if (t == 0) bsum[blockIdx.x] = red[0];
}

__global__ void k_scanB(int* bsum) {
  int t = threadIdx.x;
  int loc[25];
  int s = 0;
  if (t < 250) {
    for (int i = 0; i < 25; ++i) { loc[i] = bsum[t * 25 + i]; s += loc[i]; }
  }
  __shared__ int ps[256];
  int incl = block_scan_incl(s, ps, t);
  int base = incl - s;
  if (t < 250) {
    int run = base;
    for (int i = 0; i < 25; ++i) { int tmp = loc[i]; bsum[t * 25 + i] = run; run += tmp; }
  }
}

// ctr2 packed: low 20 bits = running slot (starts at rowptr), bits 20+ = segment count.
__global__ void k_scanC(const int* hist2, const int* bsum, int* rowptr2, int* ctr2) {
  int t = threadIdx.x;
  int gid = blockIdx.x * 256 + t;
  int v = hist2[gid];
  __shared__ int ps[256];
  int incl = block_scan_incl(v, ps, t);
  int ex = bsum[blockIdx.x] + incl - v;
  rowptr2[gid] = ex;
  ctr2[gid] = ex | (v << 20);
}

// ---------------- fused sort: one pass over original edges ----------------
// tse[p] = {src, inv_bits, pos, 0} at type-order slot; esen[pos] = {src, norm} at dst slot.
// One atomic on packed ctr2 yields both the slot and the (dst,r) count.
__global__ void k_sort(const int* ei, const int* etype, const float* enorm,
                       int* ctr1, int* ctr2, uint4* tse, uint2* esen) {
  __shared__ int lcnt[RR], lbase[RR];
  if (threadIdx.x < RR) lcnt[threadIdx.x] = 0;
  __syncthreads();
  int e = blockIdx.x * 256 + threadIdx.x;
  int t = 0, rank = 0;
  bool valid = e < NE;
  if (valid) { t = etype[e]; rank = atomicAdd(&lcnt[t], 1); }
  __syncthreads();
  if (threadIdx.x < RR) {
    int n = lcnt[threadIdx.x];
    lbase[threadIdx.x] = n ? atomicAdd(&ctr1[threadIdx.x], n) : 0;
  }
  __syncthreads();
  if (valid) {
    int p = lbase[t] + rank;
    int src = ei[e];
    int key = ei[NE + e] * RR + t;
    int old = atomicAdd(&ctr2[key], 1);
    int pos = old & 0xFFFFF;
    int cnt = old >> 20;
    float inv = 1.0f / (float)max(cnt, 1);
    float nrm = enorm[e];
    esen[pos] = make_uint2((unsigned)src, __float_as_uint(nrm));
    tse[p] = make_uint4((unsigned)src, __float_as_uint(inv), (unsigned)pos, 0u);
  }
}

// ---------------- GraphConv segment-sum: 4 edges/iter, uint2 loads (sigma space) ----------------
__global__ __launch_bounds__(256) void k_gconv_seg(const int* rowptr2, const uint2* esen,
    const unsigned short* xw_bf, const unsigned short* hroot_bf, unsigned short* h_bf) {
  int wv = threadIdx.x >> 6, l = threadIdx.x & 63;
  int c4 = l & 15, eq = l >> 4;
  int dst = blockIdx.x * 4 + wv;
  int lo = rowptr2[dst * RR];
  int hi = (dst == NN - 1) ? NE : rowptr2[(dst + 1) * RR];
  float4 acc = {0.0f, 0.0f, 0.0f, 0.0f};
  for (int base0 = lo; base0 < hi; base0 += 64) {
    int n = min(64, hi - base0);
    int sv = 0;
    float nv = 0.0f;
    if (l < n) {
      uint2 se = esen[base0 + l];
      sv = (int)se.x;
      nv = __uint_as_float(se.y);
    }
    int k4max = (n + 3) >> 2;
    for (int k4 = 0; k4 < k4max; ++k4) {
      int eid = k4 * 4 + eq;
      int s = __shfl(sv, eid);
      float w = __shfl(nv, eid);
      if (eid < n) {
        uint2 v = *reinterpret_cast<const uint2*>(xw_bf + (size_t)s * 64 + c4 * 4);
        acc.x += b2f((unsigned short)(v.x & 0xffffu)) * w;
        acc.y += b2f((unsigned short)(v.x >> 16)) * w;
        acc.z += b2f((unsigned short)(v.y & 0xffffu)) * w;
        acc.w += b2f((unsigned short)(v.y >> 16)) * w;
      }
    }
  }
  acc.x += __shfl_xor(acc.x, 16); acc.y += __shfl_xor(acc.y, 16);
  acc.z += __shfl_xor(acc.z, 16); acc.w += __shfl_xor(acc.w, 16);
  acc.x += __shfl_xor(acc.x, 32); acc.y += __shfl_xor(acc.y, 32);
  acc.z += __shfl_xor(acc.z, 32); acc.w += __shfl_xor(acc.w, 32);
  if (l < 16) {
    uint2 hb = *reinterpret_cast<const uint2*>(hroot_bf + (size_t)dst * 64 + l * 4);
    acc.x += b2f((unsigned short)(hb.x & 0xffffu));
    acc.y += b2f((unsigned short)(hb.x >> 16));
    acc.z += b2f((unsigned short)(hb.y & 0xffffu));
    acc.w += b2f((unsigned short)(hb.y >> 16));
    uint2 o;
    o.x = pk2(acc.x, acc.y);
    o.y = pk2(acc.z, acc.w);
    *reinterpret_cast<uint2*>(h_bf + (size_t)dst * 64 + l * 4) = o;
  }
}

// ---------------- RGCN via MFMA; y rows at dst-ordered slots, sigma uint2 stores ----------------
__global__ __launch_bounds__(256) void k_rgcn_y(const uint4* tse, const int* offs,
    const unsigned short* h_bf, const unsigned short* Wt, unsigned short* y_bf) {
  int r = blockIdx.x;
  int lo = offs[r], hi = offs[r + 1];
  int cnt = hi - lo;
  int wv = threadIdx.x >> 6;
  int l = threadIdx.x & 63;
  int m = l & 15, q = l >> 4;
  int ngroups = (cnt + 15) / 16;
  const unsigned short* Wr = Wt + (r << 12);
  bf16x8 bfr[2][4];
#pragma unroll
  for (int s = 0; s < 2; ++s)
#pragma unroll
    for (int nt = 0; nt < 4; ++nt)
      bfr[s][nt] = *reinterpret_cast<const bf16x8*>(Wr + (nt * 16 + m) * 64 + s * 32 + q * 8);

  for (int g = blockIdx.y * 4 + wv; g < ngroups; g += gridDim.y * 4) {
    int base = lo + g * 16;
    int ne = min(16, hi - base);
    int p = base + ((m < ne) ? m : 0);
    uint4 t4 = tse[p];
    int src = (int)t4.x;
    float inv = __uint_as_float(t4.y);
    int pos = (int)t4.z;
    f32x4 acc[4];
#pragma unroll
    for (int nt = 0; nt < 4; ++nt) acc[nt] = (f32x4){0, 0, 0, 0};
    const unsigned short* hrow = h_bf + (size_t)src * 64 + q * 8;
#pragma unroll
    for (int s = 0; s < 2; ++s) {
      bf16x8 afr = *reinterpret_cast<const bf16x8*>(hrow + s * 32);
#pragma unroll
      for (int nt = 0; nt < 4; ++nt)
        acc[nt] = __builtin_amdgcn_mfma_f32_16x16x32_bf16(afr, bfr[s][nt], acc[nt], 0, 0, 0);
    }
#pragma unroll
    for (int i = 0; i < 4; ++i) {
      int row = q * 4 + i;
      float ir = __shfl(inv, row);
      int pr = __shfl(pos, row);
      if (row < ne) {
        uint2 o;
        o.x = pk2(acc[0][i] * ir, acc[1][i] * ir);
        o.y = pk2(acc[2][i] * ir, acc[3][i] * ir);
        *reinterpret_cast<uint2*>(y_bf + (size_t)pr * 64 + m * 4) = o;
      }
    }
  }
}

// ---------------- fused: out[dst] = h_bf[dst]@w2 + b2 + sum(y rows of dst) ----------------
__global__ __launch_bounds__(256) void k_out(const int* rowptr2, const unsigned short* y_bf,
    const unsigned short* h_bf, const unsigned short* w2t, const float* b2, float* out) {
  __shared__ float ldsC[16][68];   // [dst-in-block][sigma col]
  int wv = threadIdx.x >> 6, l = threadIdx.x & 63;
  int c4 = l & 15, eq = l >> 4;
  size_t d0 = (size_t)blockIdx.x * 16;
  for (int dd = 0; dd < 4; ++dd) {
    int dst = (int)d0 + wv * 4 + dd;
    int lo = rowptr2[dst * RR];
    int hi = (dst == NN - 1) ? NE : rowptr2[(dst + 1) * RR];
    float4 acc = {0.0f, 0.0f, 0.0f, 0.0f};
    for (int row = lo + eq; row < hi; row += 4) {
      uint2 v = *reinterpret_cast<const uint2*>(y_bf + (size_t)row * 64 + c4 * 4);
      acc.x += b2f((unsigned short)(v.x & 0xffffu));
      acc.y += b2f((unsigned short)(v.x >> 16));
      acc.z += b2f((unsigned short)(v.y & 0xffffu));
      acc.w += b2f((unsigned short)(v.y >> 16));
    }
    acc.x += __shfl_xor(acc.x, 16); acc.y += __shfl_xor(acc.y, 16);
    acc.z += __shfl_xor(acc.z, 16); acc.w += __shfl_xor(acc.w, 16);
    acc.x += __shfl_xor(acc.x, 32); acc.y += __shfl_xor(acc.y, 32);
    acc.z += __shfl_xor(acc.z, 32); acc.w += __shfl_xor(acc.w, 32);
    if (l < 16)
      *reinterpret_cast<float4*>(&ldsC[wv * 4 + dd][l * 4]) = acc;
  }
  __syncthreads();
  // phase 2: wave wv owns true cols wv*16 + m; y-sum for that col is at sigma m*4+wv
  int m = l & 15, q = l >> 4, nt = wv;
  float bb = b2[nt * 16 + m];
  f32x4 acc;
#pragma unroll
  for (int i = 0; i < 4; ++i) acc[i] = ldsC[q * 4 + i][m * 4 + nt] + bb;
#pragma unroll
  for (int s = 0; s < 2; ++s) {
    bf16x8 a = *reinterpret_cast<const bf16x8*>(h_bf + (d0 + m) * 64 + s * 32 + q * 8);
    bf16x8 b = *reinterpret_cast<const bf16x8*>(w2t + (nt * 16 + m) * 64 + s * 32 + q * 8);
    acc = __builtin_amdgcn_mfma_f32_16x16x32_bf16(a, b, acc, 0, 0, 0);
  }
#pragma unroll
  for (int i = 0; i < 4; ++i)
    out[(d0 + q * 4 + i) * 64 + nt * 16 + m] = acc[i];   // TRUE layout
}

// ---------------- graph bounds ----------------
__global__ void k_bounds(const int* seq, int* bounds) {
  __shared__ int s[GG];
  for (int i = threadIdx.x; i < GG; i += 256) s[i] = seq[i];
  __syncthreads();
  if (threadIdx.x == 0) {
    int acc = 0;
    for (int g = 0; g < GG; ++g) { acc += s[g]; bounds[g] = acc; }
  }
}

// ---------------- fused pool + MLP head + log_softmax ----------------
__global__ __launch_bounds__(256) void k_head(const float* x, const float* outn,
    const int* bounds, const float* lin_w, const float* lin_b,
    const float* fc_w, const float* fc_b, float* dout) {
  __shared__ float4 psum[5][48], pmax[5][48];
  __shared__ float gsum[192], gmax[192];
  __shared__ float part[4][64];
  __shared__ float hid[HD], lg[CC], mred[2];
  int g = blockIdx.x, t = threadIdx.x;
  int lo = (g == 0) ? 0 : bounds[g - 1];
  int hi = bounds[g];
  int nn = hi - lo;
  if (t < 240) {
    int c4 = t % 48, ch = t / 48;
    int a = lo + (nn * ch) / 5, b = lo + (nn * (ch + 1)) / 5;
    float4 s = {0, 0, 0, 0};
    float4 mx = {-3.4e38f, -3.4e38f, -3.4e38f, -3.4e38f};
    const float* bp;
    int stride;
    if (c4 < 32) { bp = x + (size_t)a * FD + c4 * 4; stride = FD; }
    else         { bp = outn + (size_t)a * 64 + (c4 - 32) * 4; stride = 64; }
    int n = a;
    for (; n + 4 <= b; n += 4) {
      float4 v0 = *reinterpret_cast<const float4*>(bp);
      float4 v1 = *reinterpret_cast<const float4*>(bp + stride);
      float4 v2 = *reinterpret_cast<const float4*>(bp + 2 * stride);
      float4 v3 = *reinterpret_cast<const float4*>(bp + 3 * stride);
      bp += 4 * stride;
      s.x += v0.x + v1.x + v2.x + v3.x;
      s.y += v0.y + v1.y + v2.y + v3.y;
      s.z += v0.z + v1.z + v2.z + v3.z;
      s.w += v0.w + v1.w + v2.w + v3.w;
      mx.x = fmaxf(fmaxf(fmaxf(mx.x, v0.x), fmaxf(v1.x, v2.x)), v3.x);
      mx.y = fmaxf(fmaxf(fmaxf(mx.y, v0.y), fmaxf(v1.y, v2.y)), v3.y);
      mx.z = fmaxf(fmaxf(fmaxf(mx.z, v0.z), fmaxf(v1.z, v2.z)), v3.z);
      mx.w = fmaxf(fmaxf(fmaxf(mx.w, v0.w), fmaxf(v1.w, v2.w)), v3.w);
    }
    for (; n < b; ++n) {
      float4 v = *reinterpret_cast<const float4*>(bp);
      bp += stride;
      s.x += v.x; s.y += v.y; s.z += v.z; s.w += v.w;
      mx.x = fmaxf(mx.x, v.x); mx.y = fmaxf(mx.y, v.y);
      mx.z = fmaxf(mx.z, v.z); mx.w = fmaxf(mx.w, v.w);
    }
    psum[ch][c4] = s;
    pmax[ch][c4] = mx;
  }
  __syncthreads();
  if (t < 48) {
    float4 s = psum[0][t], m = pmax[0][t];
#pragma unroll
    for (int ch = 1; ch < 5; ++ch) {
      float4 ps = psum[ch][t], pm = pmax[ch][t];
      s.x += ps.x; s.y += ps.y; s.z += ps.z; s.w += ps.w;
      m.x = fmaxf(m.x, pm.x); m.y = fmaxf(m.y, pm.y);
      m.z = fmaxf(m.z, pm.z); m.w = fmaxf(m.w, pm.w);
    }
    gsum[t * 4 + 0] = s.x; gsum[t * 4 + 1] = s.y;
    gsum[t * 4 + 2] = s.z; gsum[t * 4 + 3] = s.w;
    gmax[t * 4 + 0] = m.x; gmax[t * 4 + 1] = m.y;
    gmax[t * 4 + 2] = m.z; gmax[t * 4 + 3] = m.w;
  }
  __syncthreads();
  {
    int o = t & 63, pp = t >> 6;
    float a = 0.0f;
    int k0 = pp * 96;
    for (int k = k0; k < k0 + 96; ++k) {
      float gv = (k < 192) ? gsum[k] : gmax[k - 192];
      a += gv * lin_w[k * 64 + o];
    }
    part[pp][o] = a;
  }
  __syncthreads();
  if (t < HD) {
    float a = lin_b[t] + part[0][t] + part[1][t] + part[2][t] + part[3][t];
    hid[t] = fmaxf(a, 0.0f);
  }
  __syncthreads();
  if (t < CC) {
    float a = fc_b[t];
    for (int k = 0; k < HD; ++k) a += hid[k] * fc_w[k * CC + t];
    lg[t] = a;
  }
  __syncthreads();
  if (t == 0) {
    float mm = lg[0];
#pragma unroll
    for (int i = 1; i < CC; ++i) mm = fmaxf(mm, lg[i]);
    float se = 0.0f;
#pragma unroll
    for (int i = 0; i < CC; ++i) se += __expf(lg[i] - mm);
    mred[0] = mm;
    mred[1] = __logf(se);
  }
  __syncthreads();
  if (t < CC) dout[g * CC + t] = lg[t] - mred[0] - mred[1];
}

extern "C" void kernel_launch(void* const* d_in, const int* in_sizes, int n_in,
                              void* d_out, int out_size, void* d_ws, size_t ws_size,
                              hipStream_t stream) {
  const float* x     = (const float*)d_in[0];
  const int* ei      = (const int*)d_in[1];
  const float* enorm = (const float*)d_in[2];
  const int* etype   = (const int*)d_in[3];
  const int* seq     = (const int*)d_in[4];
  const float* w1_rel  = (const float*)d_in[6];
  const float* w1_root = (const float*)d_in[7];
  const float* b1      = (const float*)d_in[8];
  const float* bases   = (const float*)d_in[9];
  const float* comp    = (const float*)d_in[10];
  const float* w2      = (const float*)d_in[11];
  const float* b2      = (const float*)d_in[12];
  const float* lin_w   = (const float*)d_in[13];
  const float* lin_b   = (const float*)d_in[14];
  const float* fc_w    = (const float*)d_in[15];
  const float* fc_b    = (const float*)d_in[16];
  float* dout = (float*)d_out;

  char* p = (char*)d_ws;
  unsigned short* hroot_bf = (unsigned short*)p; p += (size_t)NN * 64 * 2;  // 12.8 MB
  unsigned short* xw_bf    = (unsigned short*)p; p += (size_t)NN * 64 * 2;  // 12.8 MB
  float* out  = (float*)p;  p += (size_t)NN * 64 * 4;                       // 25.6 MB (ctr2 alias)
  unsigned short* y_bf = (unsigned short*)p; p += (size_t)NE * 64 * 2;      // 64 MB
  unsigned short* h_bf = (unsigned short*)p; p += (size_t)NN * 64 * 2;      // 12.8 MB
  unsigned short* Wt   = (unsigned short*)p; p += (size_t)RR * 4096 * 2;
  unsigned short* wcat = (unsigned short*)p; p += (size_t)128 * 128 * 2;
  unsigned short* w2t  = (unsigned short*)p; p += (size_t)64 * 64 * 2;
  uint4* tse   = (uint4*)p; p += (size_t)NE * 16;       // 8 MB
  uint2* esen  = (uint2*)p; p += (size_t)NE * 8;        // 4 MB
  int* hist2   = (int*)p; p += (size_t)NN * RR * 4;     // 6.4 MB
  int* rowptr2 = (int*)p; p += (size_t)NN * RR * 4;     // 6.4 MB
  int* bsum    = (int*)p; p += (size_t)NGROUP * 4;
  int* hist1   = (int*)p; p += 64;
  int* ctr1    = (int*)p; p += 64;
  int* offs    = (int*)p; p += 68;
  int* bounds  = (int*)p; p += (size_t)GG * 4;
  int* ctr2    = (int*)out;  // safe: out first written by k_out (after k_sort)

  hipMemsetAsync(hist2, 0, (size_t)NN * RR * 4, stream);
  hipMemsetAsync(hist1, 0, 128, stream);  // hist1 + ctr1

  hipLaunchKernelGGL(k_basis, dim3(256), dim3(256), 0, stream, comp, bases, Wt);
  hipLaunchKernelGGL(k_wcvt, dim3(80), dim3(256), 0, stream, w1_root, w1_rel, w2, wcat, w2t);
  hipLaunchKernelGGL(k_proj_mfma, dim3((2 * NGROUP + 3) / 4), dim3(256), 0, stream,
                     x, wcat, b1, hroot_bf, xw_bf);
  hipLaunchKernelGGL(k_hists, dim3(512), dim3(256), 0, stream, ei, etype, hist1, hist2);
  hipLaunchKernelGGL(k_scan1, dim3(1), dim3(64), 0, stream, hist1, offs, ctr1);
  hipLaunchKernelGGL(k_scanA, dim3(NGROUP), dim3(256), 0, stream, hist2, bsum);
  hipLaunchKernelGGL(k_scanB, dim3(1), dim3(256), 0, stream, bsum);
  hipLaunchKernelGGL(k_scanC, dim3(NGROUP), dim3(256), 0, stream, hist2, bsum, rowptr2, ctr2);
  hipLaunchKernelGGL(k_sort, dim3((NE + 255) / 256), dim3(256), 0, stream,
                     ei, etype, enorm, ctr1, ctr2, tse, esen);
  hipLaunchKernelGGL(k_gconv_seg, dim3(NN / 4), dim3(256), 0, stream,
                     rowptr2, esen, xw_bf, hroot_bf, h_bf);
  hipLaunchKernelGGL(k_rgcn_y, dim3(RR, 128), dim3(256), 0, stream,
                     tse, offs, h_bf, Wt, y_bf);
  hipLaunchKernelGGL(k_out, dim3(NN / 16), dim3(256), 0, stream,
                     rowptr2, y_bf, h_bf, w2t, b2, out);
  hipLaunchKernelGGL(k_bounds, dim3(1), dim3(256), 0, stream, seq, bounds);
  hipLaunchKernelGGL(k_head, dim3(GG), dim3(256), 0, stream, x, out, bounds,
                     lin_w, lin_b, fc_w, fc_b, dout);
}

// Round 11
// 357.896 us; speedup vs baseline: 1.6688x; 1.0390x over previous
//
#include <hip/hip_runtime.h>
#include <hip/hip_bf16.h>

#define NN 100000   // nodes
#define NE 500000   // edges
#define FD 128      // input features
#define HD 64       // hidden
#define RR 16       // relations
#define NBASE 30    // bases
#define GG 1000     // graphs
#define CC 10       // classes
#define NGROUP 6250 // NN/16
#define NBLK ((NE + 255) / 256)   // 1954 edge-blocks

// Per-node 64-vectors (hroot_bf, xw_bf, h_bf, y_bf) are stored sigma-order:
// stored[(c&15)*4 + (c>>4)] = true[c] (MFMA C-layout interleave). Wt/w2t have
// contraction dim sigma-permuted to match. out/d_out are TRUE layout.

typedef __attribute__((ext_vector_type(8))) short bf16x8;
typedef __attribute__((ext_vector_type(4))) float f32x4;

__device__ inline unsigned short f2b(float x) {
  __hip_bfloat16 b = __float2bfloat16(x);
  return *reinterpret_cast<unsigned short*>(&b);
}
__device__ inline float b2f(unsigned short u) {
  return __uint_as_float(((unsigned)u) << 16);
}
__device__ inline unsigned pk2(float a, float b) {
  return (unsigned)f2b(a) | ((unsigned)f2b(b) << 16);
}

// ---------------- fused prep: Wt (basis combo, sigma-k) + wcat + w2t ----------------
__global__ void k_prep(const float* comp, const float* bases, const float* w_root,
                       const float* w_rel, const float* w2, unsigned short* Wt,
                       unsigned short* wcat, unsigned short* w2t) {
  int bx = blockIdx.x;
  if (bx < 256) {
    int idx = bx * 256 + threadIdx.x;  // r*4096 + k*64 + n
    int r = idx >> 12, kj = idx & 4095;
    int k = kj >> 6, n = kj & 63;
    float acc = 0.0f;
    for (int b = 0; b < NBASE; ++b)
      acc += comp[r * NBASE + b] * bases[b * 4096 + kj];
    int sk = (k & 15) * 4 + (k >> 4);
    Wt[(r << 12) + n * 64 + sk] = f2b(acc);
  } else {
    int idx = (bx - 256) * 256 + threadIdx.x;
    if (idx < 16384) {
      int n = idx >> 7, k = idx & 127;
      float v = (n < 64) ? w_root[k * 64 + n] : w_rel[k * 64 + (n - 64)];
      wcat[n * 128 + k] = f2b(v);
    } else if (idx < 16384 + 4096) {
      int i2 = idx - 16384;
      int n = i2 >> 6, k = i2 & 63;
      int sk = (k & 15) * 4 + (k >> 4);
      w2t[n * 64 + sk] = f2b(w2[k * 64 + n]);
    }
  }
}

// ---------------- hroot_bf / xw_bf (sigma), 2 waves/group, preloaded x ----------------
__global__ __launch_bounds__(256) void k_proj_mfma(const float* x, const unsigned short* wcat,
                                                   const float* b1, unsigned short* hroot_bf,
                                                   unsigned short* xw_bf) {
  int wv = threadIdx.x >> 6, l = threadIdx.x & 63, m = l & 15, q = l >> 4;
  int gid = blockIdx.x * 4 + wv;
  int g = gid >> 1, half = gid & 1;   // half 0 -> h tiles, half 1 -> xw tiles
  if (g >= NGROUP) return;
  size_t n0 = (size_t)g * 16;
  const float* xr = x + (n0 + m) * FD + q * 8;
  float4 xv[8];
#pragma unroll
  for (int s = 0; s < 4; ++s) {
    xv[2 * s] = *reinterpret_cast<const float4*>(xr + s * 32);
    xv[2 * s + 1] = *reinterpret_cast<const float4*>(xr + s * 32 + 4);
  }
  f32x4 acc[4];
#pragma unroll
  for (int nt = 0; nt < 4; ++nt) acc[nt] = (f32x4){0, 0, 0, 0};
#pragma unroll
  for (int s = 0; s < 4; ++s) {
    float4 xa = xv[2 * s], xb = xv[2 * s + 1];
    bf16x8 a;
    a[0] = (short)f2b(xa.x); a[1] = (short)f2b(xa.y);
    a[2] = (short)f2b(xa.z); a[3] = (short)f2b(xa.w);
    a[4] = (short)f2b(xb.x); a[5] = (short)f2b(xb.y);
    a[6] = (short)f2b(xb.z); a[7] = (short)f2b(xb.w);
#pragma unroll
    for (int nt = 0; nt < 4; ++nt) {
      bf16x8 b = *reinterpret_cast<const bf16x8*>(
          wcat + ((half * 4 + nt) * 16 + m) * 128 + s * 32 + q * 8);
      acc[nt] = __builtin_amdgcn_mfma_f32_16x16x32_bf16(a, b, acc[nt], 0, 0, 0);
    }
  }
  float bv[4] = {0, 0, 0, 0};
  if (half == 0) {
#pragma unroll
    for (int nt = 0; nt < 4; ++nt) bv[nt] = b1[nt * 16 + m];
  }
  unsigned short* dbuf = half ? xw_bf : hroot_bf;
#pragma unroll
  for (int i = 0; i < 4; ++i) {
    size_t row = (n0 + q * 4 + i) * 64 + m * 4;  // sigma: stored = m*4 + nt
    uint2 o;
    o.x = pk2(acc[0][i] + bv[0], acc[1][i] + bv[1]);
    o.y = pk2(acc[2][i] + bv[2], acc[3][i] + bv[3]);
    *reinterpret_cast<uint2*>(dbuf + row) = o;
  }
}

// ---------------- histograms: per-block type counts bch + hist2[dst*16+type] ----------------
__global__ void k_hists(const int* ei, const int* etype, int* bch, int* hist2) {
  __shared__ int lh[RR];
  if (threadIdx.x < RR) lh[threadIdx.x] = 0;
  __syncthreads();
  int e = blockIdx.x * 256 + threadIdx.x;
  if (e < NE) {
    int t = etype[e];
    atomicAdd(&lh[t], 1);
    atomicAdd(&hist2[ei[NE + e] * RR + t], 1);
  }
  __syncthreads();
  if (threadIdx.x < RR) bch[blockIdx.x * RR + threadIdx.x] = lh[threadIdx.x];
}

// ---------------- hierarchical scan of hist2 ----------------
__device__ inline int block_scan_incl(int v, int* ps, int t) {
  ps[t] = v;
  __syncthreads();
  for (int off = 1; off < 256; off <<= 1) {
    int u = (t >= off) ? ps[t - off] : 0;
    __syncthreads();
    ps[t] += u;
    __syncthreads();
  }
  return ps[t];
}

__global__ void k_scanA(const int* hist2, int* bsum) {
  __shared__ int red[256];
  int t = threadIdx.x;
  red[t] = hist2[blockIdx.x * 256 + t];
  __syncthreads();
  for (int s = 128; s; s >>= 1) {
    if (t < s) red[t] += red[t + s];
    __syncthreads();
  }
  if (t == 0) bsum[blockIdx.x] = red[0];
}

__global__ void k_scanB(int* bsum) {
  int t = threadIdx.x;
  int loc[25];
  int s = 0;
  if (t < 250) {
    for (int i = 0; i < 25; ++i) { loc[i] = bsum[t * 25 + i]; s += loc[i]; }
  }
  __shared__ int ps[256];
  int incl = block_scan_incl(s, ps, t);
  int base = incl - s;
  if (t < 250) {
    int run = base;
    for (int i = 0; i < 25; ++i) { int tmp = loc[i]; bsum[t * 25 + i] = run; run += tmp; }
  }
}

// ctr2 packed: low 20 bits = running slot (starts at rowptr), bits 20+ = segment count.
__global__ void k_scanC(const int* hist2, const int* bsum, int* rowptr2, int* ctr2) {
  int t = threadIdx.x;
  int gid = blockIdx.x * 256 + t;
  int v = hist2[gid];
  __shared__ int ps[256];
  int incl = block_scan_incl(v, ps, t);
  int ex = bsum[blockIdx.x] + incl - v;
  rowptr2[gid] = ex;
  ctr2[gid] = ex | (v << 20);
}

// ---------------- bscan: bbase[b][t] per-block type bases; offs; bounds ----------------
__global__ void k_bscan(const int* bch, const int* seq, int* bbase, int* offs, int* bounds) {
  __shared__ int part[16][17], chunkbase[16][17];
  __shared__ int colbase[16];
  __shared__ int ps[256];
  int t = threadIdx.x;
  int ty = t & 15, ck = t >> 4;
  const int CH = (NBLK + 15) / 16;
  int b0 = ck * CH, b1 = min(b0 + CH, NBLK);
  int s = 0;
  for (int b = b0; b < b1; ++b) s += bch[b * 16 + ty];
  part[ck][ty] = s;
  __syncthreads();
  if (t < 16) {
    int run = 0;
    for (int c = 0; c < 16; ++c) { chunkbase[c][t] = run; run += part[c][t]; }
    colbase[t] = run;  // column total
  }
  __syncthreads();
  if (t == 0) {
    int run = 0;
    for (int r = 0; r < RR; ++r) { int v = colbase[r]; offs[r] = run; colbase[r] = run; run += v; }
    offs[RR] = run;
  }
  __syncthreads();
  {
    int run = colbase[ty] + chunkbase[ck][ty];
    for (int b = b0; b < b1; ++b) {
      int v = bch[b * 16 + ty];
      bbase[b * 16 + ty] = run;
      run += v;
    }
  }
  // bounds: inclusive cumsum of seq (1000), 250 threads x 4
  int loc[4];
  int ss = 0;
  if (t < 250) {
    for (int i = 0; i < 4; ++i) { loc[i] = seq[t * 4 + i]; ss += loc[i]; }
  }
  int incl = block_scan_incl(ss, ps, t);
  int base = incl - ss;
  if (t < 250) {
    int run = base;
    for (int i = 0; i < 4; ++i) { run += loc[i]; bounds[t * 4 + i] = run; }
  }
}

// ---------------- sort: no hot atomics, no post-rank barrier ----------------
// tse[p] = {src, inv_bits, pos, 0} at type-order slot; esen[pos] = {src, norm} at dst slot.
__global__ void k_sort(const int* ei, const int* etype, const float* enorm,
                       const int* bbase, int* ctr2, uint4* tse, uint2* esen) {
  __shared__ int lcnt[RR];
  if (threadIdx.x < RR) lcnt[threadIdx.x] = 0;
  __syncthreads();
  int e = blockIdx.x * 256 + threadIdx.x;
  if (e >= NE) return;
  int t = etype[e];
  int rank = atomicAdd(&lcnt[t], 1);          // LDS, block-local
  int p = bbase[blockIdx.x * RR + t] + rank;  // deterministic base (cached read)
  int src = ei[e];
  int key = ei[NE + e] * RR + t;
  int old = atomicAdd(&ctr2[key], 1);         // random, low-contention
  int pos = old & 0xFFFFF;
  int cnt = old >> 20;
  float inv = 1.0f / (float)max(cnt, 1);
  esen[pos] = make_uint2((unsigned)src, __float_as_uint(enorm[e]));
  tse[p] = make_uint4((unsigned)src, __float_as_uint(inv), (unsigned)pos, 0u);
}

// ---------------- GraphConv segment-sum: 4 edges/iter, uint2 loads (sigma space) ----------------
__global__ __launch_bounds__(256) void k_gconv_seg(const int* rowptr2, const uint2* esen,
    const unsigned short* xw_bf, const unsigned short* hroot_bf, unsigned short* h_bf) {
  int wv = threadIdx.x >> 6, l = threadIdx.x & 63;
  int c4 = l & 15, eq = l >> 4;
  int dst = blockIdx.x * 4 + wv;
  int lo = rowptr2[dst * RR];
  int hi = (dst == NN - 1) ? NE : rowptr2[(dst + 1) * RR];
  float4 acc = {0.0f, 0.0f, 0.0f, 0.0f};
  for (int base0 = lo; base0 < hi; base0 += 64) {
    int n = min(64, hi - base0);
    int sv = 0;
    float nv = 0.0f;
    if (l < n) {
      uint2 se = esen[base0 + l];
      sv = (int)se.x;
      nv = __uint_as_float(se.y);
    }
    int k4max = (n + 3) >> 2;
    for (int k4 = 0; k4 < k4max; ++k4) {
      int eid = k4 * 4 + eq;
      int s = __shfl(sv, eid);
      float w = __shfl(nv, eid);
      if (eid < n) {
        uint2 v = *reinterpret_cast<const uint2*>(xw_bf + (size_t)s * 64 + c4 * 4);
        acc.x += b2f((unsigned short)(v.x & 0xffffu)) * w;
        acc.y += b2f((unsigned short)(v.x >> 16)) * w;
        acc.z += b2f((unsigned short)(v.y & 0xffffu)) * w;
        acc.w += b2f((unsigned short)(v.y >> 16)) * w;
      }
    }
  }
  acc.x += __shfl_xor(acc.x, 16); acc.y += __shfl_xor(acc.y, 16);
  acc.z += __shfl_xor(acc.z, 16); acc.w += __shfl_xor(acc.w, 16);
  acc.x += __shfl_xor(acc.x, 32); acc.y += __shfl_xor(acc.y, 32);
  acc.z += __shfl_xor(acc.z, 32); acc.w += __shfl_xor(acc.w, 32);
  if (l < 16) {
    uint2 hb = *reinterpret_cast<const uint2*>(hroot_bf + (size_t)dst * 64 + l * 4);
    acc.x += b2f((unsigned short)(hb.x & 0xffffu));
    acc.y += b2f((unsigned short)(hb.x >> 16));
    acc.z += b2f((unsigned short)(hb.y & 0xffffu));
    acc.w += b2f((unsigned short)(hb.y >> 16));
    uint2 o;
    o.x = pk2(acc.x, acc.y);
    o.y = pk2(acc.z, acc.w);
    *reinterpret_cast<uint2*>(h_bf + (size_t)dst * 64 + l * 4) = o;
  }
}

// ---------------- RGCN via MFMA; y rows at dst-ordered slots, sigma uint2 stores ----------------
__global__ __launch_bounds__(256) void k_rgcn_y(const uint4* tse, const int* offs,
    const unsigned short* h_bf, const unsigned short* Wt, unsigned short* y_bf) {
  int r = blockIdx.x;
  int lo = offs[r], hi = offs[r + 1];
  int cnt = hi - lo;
  int wv = threadIdx.x >> 6;
  int l = threadIdx.x & 63;
  int m = l & 15, q = l >> 4;
  int ngroups = (cnt + 15) / 16;
  const unsigned short* Wr = Wt + (r << 12);
  bf16x8 bfr[2][4];
#pragma unroll
  for (int s = 0; s < 2; ++s)
#pragma unroll
    for (int nt = 0; nt < 4; ++nt)
      bfr[s][nt] = *reinterpret_cast<const bf16x8*>(Wr + (nt * 16 + m) * 64 + s * 32 + q * 8);

  for (int g = blockIdx.y * 4 + wv; g < ngroups; g += gridDim.y * 4) {
    int base = lo + g * 16;
    int ne = min(16, hi - base);
    int p = base + ((m < ne) ? m : 0);
    uint4 t4 = tse[p];
    int src = (int)t4.x;
    float inv = __uint_as_float(t4.y);
    int pos = (int)t4.z;
    f32x4 acc[4];
#pragma unroll
    for (int nt = 0; nt < 4; ++nt) acc[nt] = (f32x4){0, 0, 0, 0};
    const unsigned short* hrow = h_bf + (size_t)src * 64 + q * 8;
#pragma unroll
    for (int s = 0; s < 2; ++s) {
      bf16x8 afr = *reinterpret_cast<const bf16x8*>(hrow + s * 32);
#pragma unroll
      for (int nt = 0; nt < 4; ++nt)
        acc[nt] = __builtin_amdgcn_mfma_f32_16x16x32_bf16(afr, bfr[s][nt], acc[nt], 0, 0, 0);
    }
#pragma unroll
    for (int i = 0; i < 4; ++i) {
      int row = q * 4 + i;
      float ir = __shfl(inv, row);
      int pr = __shfl(pos, row);
      if (row < ne) {
        uint2 o;
        o.x = pk2(acc[0][i] * ir, acc[1][i] * ir);
        o.y = pk2(acc[2][i] * ir, acc[3][i] * ir);
        *reinterpret_cast<uint2*>(y_bf + (size_t)pr * 64 + m * 4) = o;
      }
    }
  }
}

// ---------------- fused: out[dst] = h_bf[dst]@w2 + b2 + sum(y rows of dst) ----------------
__global__ __launch_bounds__(256) void k_out(const int* rowptr2, const unsigned short* y_bf,
    const unsigned short* h_bf, const unsigned short* w2t, const float* b2, float* out) {
  __shared__ float ldsC[16][68];   // [dst-in-block][sigma col]
  int wv = threadIdx.x >> 6, l = threadIdx.x & 63;
  int c4 = l & 15, eq = l >> 4;
  size_t d0 = (size_t)blockIdx.x * 16;
  for (int dd = 0; dd < 4; ++dd) {
    int dst = (int)d0 + wv * 4 + dd;
    int lo = rowptr2[dst * RR];
    int hi = (dst == NN - 1) ? NE : rowptr2[(dst + 1) * RR];
    float4 acc = {0.0f, 0.0f, 0.0f, 0.0f};
    for (int row = lo + eq; row < hi; row += 4) {
      uint2 v = *reinterpret_cast<const uint2*>(y_bf + (size_t)row * 64 + c4 * 4);
      acc.x += b2f((unsigned short)(v.x & 0xffffu));
      acc.y += b2f((unsigned short)(v.x >> 16));
      acc.z += b2f((unsigned short)(v.y & 0xffffu));
      acc.w += b2f((unsigned short)(v.y >> 16));
    }
    acc.x += __shfl_xor(acc.x, 16); acc.y += __shfl_xor(acc.y, 16);
    acc.z += __shfl_xor(acc.z, 16); acc.w += __shfl_xor(acc.w, 16);
    acc.x += __shfl_xor(acc.x, 32); acc.y += __shfl_xor(acc.y, 32);
    acc.z += __shfl_xor(acc.z, 32); acc.w += __shfl_xor(acc.w, 32);
    if (l < 16)
      *reinterpret_cast<float4*>(&ldsC[wv * 4 + dd][l * 4]) = acc;
  }
  __syncthreads();
  // phase 2: wave wv owns true cols wv*16 + m; y-sum for that col is at sigma m*4+wv
  int m = l & 15, q = l >> 4, nt = wv;
  float bb = b2[nt * 16 + m];
  f32x4 acc;
#pragma unroll
  for (int i = 0; i < 4; ++i) acc[i] = ldsC[q * 4 + i][m * 4 + nt] + bb;
#pragma unroll
  for (int s = 0; s < 2; ++s) {
    bf16x8 a = *reinterpret_cast<const bf16x8*>(h_bf + (d0 + m) * 64 + s * 32 + q * 8);
    bf16x8 b = *reinterpret_cast<const bf16x8*>(w2t + (nt * 16 + m) * 64 + s * 32 + q * 8);
    acc = __builtin_amdgcn_mfma_f32_16x16x32_bf16(a, b, acc, 0, 0, 0);
  }
#pragma unroll
  for (int i = 0; i < 4; ++i)
    out[(d0 + q * 4 + i) * 64 + nt * 16 + m] = acc[i];   // TRUE layout
}

// ---------------- fused pool + MLP head + log_softmax ----------------
__global__ __launch_bounds__(256) void k_head(const float* x, const float* outn,
    const int* bounds, const float* lin_w, const float* lin_b,
    const float* fc_w, const float* fc_b, float* dout) {
  __shared__ float4 psum[5][48], pmax[5][48];
  __shared__ float gsum[192], gmax[192];
  __shared__ float part[4][64];
  __shared__ float hid[HD], lg[CC], mred[2];
  int g = blockIdx.x, t = threadIdx.x;
  int lo = (g == 0) ? 0 : bounds[g - 1];
  int hi = bounds[g];
  int nn = hi - lo;
  if (t < 240) {
    int c4 = t % 48, ch = t / 48;
    int a = lo + (nn * ch) / 5, b = lo + (nn * (ch + 1)) / 5;
    float4 s = {0, 0, 0, 0};
    float4 mx = {-3.4e38f, -3.4e38f, -3.4e38f, -3.4e38f};
    const float* bp;
    int stride;
    if (c4 < 32) { bp = x + (size_t)a * FD + c4 * 4; stride = FD; }
    else         { bp = outn + (size_t)a * 64 + (c4 - 32) * 4; stride = 64; }
    int n = a;
    for (; n + 4 <= b; n += 4) {
      float4 v0 = *reinterpret_cast<const float4*>(bp);
      float4 v1 = *reinterpret_cast<const float4*>(bp + stride);
      float4 v2 = *reinterpret_cast<const float4*>(bp + 2 * stride);
      float4 v3 = *reinterpret_cast<const float4*>(bp + 3 * stride);
      bp += 4 * stride;
      s.x += v0.x + v1.x + v2.x + v3.x;
      s.y += v0.y + v1.y + v2.y + v3.y;
      s.z += v0.z + v1.z + v2.z + v3.z;
      s.w += v0.w + v1.w + v2.w + v3.w;
      mx.x = fmaxf(fmaxf(fmaxf(mx.x, v0.x), fmaxf(v1.x, v2.x)), v3.x);
      mx.y = fmaxf(fmaxf(fmaxf(mx.y, v0.y), fmaxf(v1.y, v2.y)), v3.y);
      mx.z = fmaxf(fmaxf(fmaxf(mx.z, v0.z), fmaxf(v1.z, v2.z)), v3.z);
      mx.w = fmaxf(fmaxf(fmaxf(mx.w, v0.w), fmaxf(v1.w, v2.w)), v3.w);
    }
    for (; n < b; ++n) {
      float4 v = *reinterpret_cast<const float4*>(bp);
      bp += stride;
      s.x += v.x; s.y += v.y; s.z += v.z; s.w += v.w;
      mx.x = fmaxf(mx.x, v.x); mx.y = fmaxf(mx.y, v.y);
      mx.z = fmaxf(mx.z, v.z); mx.w = fmaxf(mx.w, v.w);
    }
    psum[ch][c4] = s;
    pmax[ch][c4] = mx;
  }
  __syncthreads();
  if (t < 48) {
    float4 s = psum[0][t], m = pmax[0][t];
#pragma unroll
    for (int ch = 1; ch < 5; ++ch) {
      float4 ps = psum[ch][t], pm = pmax[ch][t];
      s.x += ps.x; s.y += ps.y; s.z += ps.z; s.w += ps.w;
      m.x = fmaxf(m.x, pm.x); m.y = fmaxf(m.y, pm.y);
      m.z = fmaxf(m.z, pm.z); m.w = fmaxf(m.w, pm.w);
    }
    gsum[t * 4 + 0] = s.x; gsum[t * 4 + 1] = s.y;
    gsum[t * 4 + 2] = s.z; gsum[t * 4 + 3] = s.w;
    gmax[t * 4 + 0] = m.x; gmax[t * 4 + 1] = m.y;
    gmax[t * 4 + 2] = m.z; gmax[t * 4 + 3] = m.w;
  }
  __syncthreads();
  {
    int o = t & 63, pp = t >> 6;
    float a = 0.0f;
    int k0 = pp * 96;
    for (int k = k0; k < k0 + 96; ++k) {
      float gv = (k < 192) ? gsum[k] : gmax[k - 192];
      a += gv * lin_w[k * 64 + o];
    }
    part[pp][o] = a;
  }
  __syncthreads();
  if (t < HD) {
    float a = lin_b[t] + part[0][t] + part[1][t] + part[2][t] + part[3][t];
    hid[t] = fmaxf(a, 0.0f);
  }
  __syncthreads();
  if (t < CC) {
    float a = fc_b[t];
    for (int k = 0; k < HD; ++k) a += hid[k] * fc_w[k * CC + t];
    lg[t] = a;
  }
  __syncthreads();
  if (t == 0) {
    float mm = lg[0];
#pragma unroll
    for (int i = 1; i < CC; ++i) mm = fmaxf(mm, lg[i]);
    float se = 0.0f;
#pragma unroll
    for (int i = 0; i < CC; ++i) se += __expf(lg[i] - mm);
    mred[0] = mm;
    mred[1] = __logf(se);
  }
  __syncthreads();
  if (t < CC) dout[g * CC + t] = lg[t] - mred[0] - mred[1];
}

extern "C" void kernel_launch(void* const* d_in, const int* in_sizes, int n_in,
                              void* d_out, int out_size, void* d_ws, size_t ws_size,
                              hipStream_t stream) {
  const float* x     = (const float*)d_in[0];
  const int* ei      = (const int*)d_in[1];
  const float* enorm = (const float*)d_in[2];
  const int* etype   = (const int*)d_in[3];
  const int* seq     = (const int*)d_in[4];
  const float* w1_rel  = (const float*)d_in[6];
  const float* w1_root = (const float*)d_in[7];
  const float* b1      = (const float*)d_in[8];
  const float* bases   = (const float*)d_in[9];
  const float* comp    = (const float*)d_in[10];
  const float* w2      = (const float*)d_in[11];
  const float* b2      = (const float*)d_in[12];
  const float* lin_w   = (const float*)d_in[13];
  const float* lin_b   = (const float*)d_in[14];
  const float* fc_w    = (const float*)d_in[15];
  const float* fc_b    = (const float*)d_in[16];
  float* dout = (float*)d_out;

  char* p = (char*)d_ws;
  unsigned short* hroot_bf = (unsigned short*)p; p += (size_t)NN * 64 * 2;  // 12.8 MB
  unsigned short* xw_bf    = (unsigned short*)p; p += (size_t)NN * 64 * 2;  // 12.8 MB
  float* out  = (float*)p;  p += (size_t)NN * 64 * 4;                       // 25.6 MB (ctr2 alias)
  unsigned short* y_bf = (unsigned short*)p; p += (size_t)NE * 64 * 2;      // 64 MB
  unsigned short* h_bf = (unsigned short*)p; p += (size_t)NN * 64 * 2;      // 12.8 MB
  unsigned short* Wt   = (unsigned short*)p; p += (size_t)RR * 4096 * 2;
  unsigned short* wcat = (unsigned short*)p; p += (size_t)128 * 128 * 2;
  unsigned short* w2t  = (unsigned short*)p; p += (size_t)64 * 64 * 2;
  uint4* tse   = (uint4*)p; p += (size_t)NE * 16;       // 8 MB
  uint2* esen  = (uint2*)p; p += (size_t)NE * 8;        // 4 MB
  int* hist2   = (int*)p; p += (size_t)NN * RR * 4;     // 6.4 MB
  int* rowptr2 = (int*)p; p += (size_t)NN * RR * 4;     // 6.4 MB
  int* bch     = (int*)p; p += (size_t)NBLK * RR * 4;   // 125 KB
  int* bbase   = (int*)p; p += (size_t)NBLK * RR * 4;   // 125 KB
  int* bsum    = (int*)p; p += (size_t)NGROUP * 4;
  int* offs    = (int*)p; p += 68;
  int* bounds  = (int*)p; p += (size_t)GG * 4;
  int* ctr2    = (int*)out;  // safe: out first written by k_out (after k_sort)

  hipMemsetAsync(hist2, 0, (size_t)NN * RR * 4, stream);

  hipLaunchKernelGGL(k_prep, dim3(256 + 80), dim3(256), 0, stream,
                     comp, bases, w1_root, w1_rel, w2, Wt, wcat, w2t);
  hipLaunchKernelGGL(k_proj_mfma, dim3((2 * NGROUP + 3) / 4), dim3(256), 0, stream,
                     x, wcat, b1, hroot_bf, xw_bf);
  hipLaunchKernelGGL(k_hists, dim3(NBLK), dim3(256), 0, stream, ei, etype, bch, hist2);
  hipLaunchKernelGGL(k_scanA, dim3(NGROUP), dim3(256), 0, stream, hist2, bsum);
  hipLaunchKernelGGL(k_scanB, dim3(1), dim3(256), 0, stream, bsum);
  hipLaunchKernelGGL(k_scanC, dim3(NGROUP), dim3(256), 0, stream, hist2, bsum, rowptr2, ctr2);
  hipLaunchKernelGGL(k_bscan, dim3(1), dim3(256), 0, stream, bch, seq, bbase, offs, bounds);
  hipLaunchKernelGGL(k_sort, dim3(NBLK), dim3(256), 0, stream,
                     ei, etype, enorm, bbase, ctr2, tse, esen);
  hipLaunchKernelGGL(k_gconv_seg, dim3(NN / 4), dim3(256), 0, stream,
                     rowptr2, esen, xw_bf, hroot_bf, h_bf);
  hipLaunchKernelGGL(k_rgcn_y, dim3(RR, 128), dim3(256), 0, stream,
                     tse, offs, h_bf, Wt, y_bf);
  hipLaunchKernelGGL(k_out, dim3(NN / 16), dim3(256), 0, stream,
                     rowptr2, y_bf, h_bf, w2t, b2, out);
  hipLaunchKernelGGL(k_head, dim3(GG), dim3(256), 0, stream, x, out, bounds,
                     lin_w, lin_b, fc_w, fc_b, dout);
}